// Round 1
// baseline (3510.345 us; speedup 1.0000x reference)
//
#include <hip/hip_runtime.h>
#include <hip/hip_bf16.h>
#include <math.h>

#define Bb 2
#define Tt 512
#define HIDD 1024
#define Hh 16
#define Dd 64
#define Pp 1024
#define Kc 4
#define Ee 8
#define Ii 768
#define ISs 768
#define Ntok (Bb*Tt)   // 1024

__device__ __forceinline__ float sigmoidf_(float x){ return 1.f/(1.f+expf(-x)); }
__device__ __forceinline__ float siluf_(float x){ return x/(1.f+expf(-x)); }

// ---------------- RMS norm over HID=1024, one block per token ----------------
__global__ void rms_kernel(const float* __restrict__ x, const float* __restrict__ w,
                           float* __restrict__ out, float eps) {
  int row = blockIdx.x;
  const float* xr = x + (size_t)row*HIDD;
  float s = 0.f;
  for (int i = threadIdx.x; i < HIDD; i += 256){ float v = xr[i]; s += v*v; }
  #pragma unroll
  for (int off=32; off; off>>=1) s += __shfl_down(s, off, 64);
  __shared__ float red[4];
  if ((threadIdx.x & 63)==0) red[threadIdx.x>>6] = s;
  __syncthreads();
  float tot = red[0]+red[1]+red[2]+red[3];
  float sc = rsqrtf(tot/(float)HIDD + eps);
  for (int i = threadIdx.x; i < HIDD; i += 256) out[(size_t)row*HIDD+i] = xr[i]*sc*w[i];
}

// ---------------- generic fp32 GEMM: C = A(MxK) @ B(KxN) [+ resid] ----------------
__global__ void gemm_f32(const float* __restrict__ A, const float* __restrict__ B,
                         float* __restrict__ C, int M, int N, int K,
                         const float* __restrict__ resid) {
  __shared__ float As[16][64];
  __shared__ float Bs[16][64];
  int row0 = blockIdx.y*64, col0 = blockIdx.x*64;
  int tx = threadIdx.x & 15, ty = threadIdx.x >> 4;
  float acc[4][4] = {};
  for (int k0 = 0; k0 < K; k0 += 16) {
    for (int l = threadIdx.x; l < 64*16; l += 256) {
      int m = l >> 4, kk = l & 15;
      int gm = row0+m, gk = k0+kk;
      As[kk][m] = (gm < M && gk < K) ? A[(size_t)gm*K + gk] : 0.f;
    }
    for (int l = threadIdx.x; l < 16*64; l += 256) {
      int kk = l >> 6, nn = l & 63;
      int gk = k0+kk, gn = col0+nn;
      Bs[kk][nn] = (gk < K && gn < N) ? B[(size_t)gk*N + gn] : 0.f;
    }
    __syncthreads();
    #pragma unroll
    for (int kk = 0; kk < 16; ++kk) {
      float a4[4], b4[4];
      #pragma unroll
      for (int i=0;i<4;i++) a4[i] = As[kk][ty*4+i];
      #pragma unroll
      for (int j=0;j<4;j++) b4[j] = Bs[kk][tx*4+j];
      #pragma unroll
      for (int i=0;i<4;i++)
        #pragma unroll
        for (int j=0;j<4;j++) acc[i][j] += a4[i]*b4[j];
    }
    __syncthreads();
  }
  #pragma unroll
  for (int i=0;i<4;i++){
    int gm = row0 + ty*4 + i; if (gm >= M) continue;
    #pragma unroll
    for (int j=0;j<4;j++){
      int gn = col0 + tx*4 + j; if (gn >= N) continue;
      float v = acc[i][j];
      if (resid) v += resid[(size_t)gm*N + gn];
      C[(size_t)gm*N + gn] = v;
    }
  }
}

// ---------------- causal depthwise conv (K=4) + SiLU ----------------
__global__ void conv_silu_kernel(const float* __restrict__ in, const float* __restrict__ w,
                                 float* __restrict__ out) {
  int idx = blockIdx.x*256 + threadIdx.x;
  if (idx >= Bb*Tt*Pp) return;
  int c = idx & (Pp-1);
  int t = (idx >> 10) & (Tt-1);
  int b = idx >> 19;
  float s = 0.f;
  #pragma unroll
  for (int k=0;k<Kc;k++){
    int tt = t - (Kc-1) + k;
    if (tt >= 0) s += w[c*Kc+k] * in[((size_t)(b*Tt+tt))*Pp + c];
  }
  out[idx] = siluf_(s);
}

// ---------------- per-(b,t,h) L2-style norm over D=64, then scale ----------------
__global__ void l2norm_scale_kernel(float* __restrict__ qk, float mul) {
  int row = blockIdx.x*4 + (threadIdx.x>>6);
  int lane = threadIdx.x & 63;
  size_t idx = (size_t)row*Dd + lane;
  float v = qk[idx];
  float s = v*v;
  #pragma unroll
  for (int off=32; off; off>>=1) s += __shfl_xor(s, off, 64);
  qk[idx] = v * rsqrtf(s/(float)Dd + 1e-6f) * mul;
}

// ---------------- g = exp(-exp(A_log)*softplus(a + dt_bias)) ----------------
__global__ void g_kernel(float* __restrict__ a, const float* __restrict__ A_log,
                         const float* __restrict__ dt_bias) {
  int idx = blockIdx.x*256 + threadIdx.x;
  if (idx >= Ntok*Pp) return;
  int d = idx & 63;
  int hh = (idx >> 6) & 15;
  float v = a[idx] + dt_bias[hh*Dd + d];
  float sp = (v > 20.f) ? v : log1pf(expf(v));
  a[idx] = expf(-expf(A_log[hh]) * sp);
}

__global__ void sigmoid_kernel(float* __restrict__ p, int n) {
  int idx = blockIdx.x*256 + threadIdx.x;
  if (idx < n) p[idx] = sigmoidf_(p[idx]);
}

// ---------------- delta-rule scan: one block (=1 wave) per (b,h), lane owns S[:,v] ----------------
__global__ void scan_kernel(const float* __restrict__ q, const float* __restrict__ k,
                            const float* __restrict__ v, const float* __restrict__ g,
                            const float* __restrict__ beta, float* __restrict__ o) {
  int b = blockIdx.x >> 4;
  int hh = blockIdx.x & 15;
  int lane = threadIdx.x;
  __shared__ float sq[Dd], sk[Dd], sg[Dd];
  float S[Dd];
  #pragma unroll
  for (int i=0;i<Dd;i++) S[i]=0.f;
  for (int t=0;t<Tt;t++){
    size_t base = ((size_t)(b*Tt+t)*Hh + hh)*Dd;
    sq[lane] = q[base+lane];
    sk[lane] = k[base+lane];
    sg[lane] = g[base+lane];
    float vt = v[base+lane];
    float bt = beta[(size_t)(b*Tt+t)*Hh + hh];
    __syncthreads();
    float pred = 0.f;
    #pragma unroll
    for (int kk=0;kk<Dd;kk++){ S[kk] *= sg[kk]; pred += sk[kk]*S[kk]; }
    float upd = (vt - pred)*bt;
    float acc = 0.f;
    #pragma unroll
    for (int kk=0;kk<Dd;kk++){ S[kk] += sk[kk]*upd; acc += sq[kk]*S[kk]; }
    o[base+lane] = acc;
    __syncthreads();
  }
}

// ---------------- output rms(D)*w * sigmoid(gate) ----------------
__global__ void onorm_gate_kernel(float* __restrict__ o, const float* __restrict__ w,
                                  const float* __restrict__ gate) {
  int row = blockIdx.x*4 + (threadIdx.x>>6);
  int lane = threadIdx.x & 63;
  size_t idx = (size_t)row*Dd + lane;
  float v = o[idx];
  float s = v*v;
  #pragma unroll
  for (int off=32; off; off>>=1) s += __shfl_xor(s, off, 64);
  o[idx] = v * rsqrtf(s/(float)Dd + 1e-5f) * w[lane] * sigmoidf_(gate[idx]);
}

// ---------------- router: sigmoid scores, biased top-2, renorm, bucket tokens ----------------
__global__ void router_kernel(const float* __restrict__ scores_raw, const float* __restrict__ gate_b,
                              int* __restrict__ counts, int* __restrict__ tok_list,
                              int* __restrict__ slot_list, float* __restrict__ wt_list) {
  int n = blockIdx.x*256 + threadIdx.x;
  if (n >= Ntok) return;
  float sc[Ee], bi[Ee];
  #pragma unroll
  for (int e=0;e<Ee;e++){ float s = sigmoidf_(scores_raw[n*Ee+e]); sc[e]=s; bi[e]=s+gate_b[e]; }
  int i0=0;
  #pragma unroll
  for (int e=1;e<Ee;e++) if (bi[e] > bi[i0]) i0=e;
  int i1=-1;
  #pragma unroll
  for (int e=0;e<Ee;e++){ if (e==i0) continue; if (i1<0 || bi[e] > bi[i1]) i1=e; }
  float w0=sc[i0], w1=sc[i1];
  float inv = 1.f/(w0+w1+1e-20f);
  w0*=inv; w1*=inv;
  int p0 = atomicAdd(&counts[i0],1);
  tok_list[i0*Ntok+p0]=n; slot_list[i0*Ntok+p0]=0; wt_list[i0*Ntok+p0]=w0;
  int p1 = atomicAdd(&counts[i1],1);
  tok_list[i1*Ntok+p1]=n; slot_list[i1*Ntok+p1]=1; wt_list[i1*Ntok+p1]=w1;
}

__global__ void prefix_kernel(const int* __restrict__ counts, int* __restrict__ prefix) {
  if (threadIdx.x==0 && blockIdx.x==0){ int s=0; for (int e=0;e<Ee;e++){ prefix[e]=s; s+=counts[e]; } }
}

// ---------------- expert stage 1: act = silu(Xe@wg_e) * (Xe@wu_e), gathered rows ----------------
__global__ void expert_gemm1(const float* __restrict__ hn, const int* __restrict__ tok_list,
                             const int* __restrict__ counts, const int* __restrict__ prefix,
                             const float* __restrict__ wg_e, const float* __restrict__ wu_e,
                             float* __restrict__ act) {
  int e = blockIdx.z;
  int cnt = counts[e];
  int row0 = blockIdx.y * 64;
  if (row0 >= cnt) return;
  int col0 = blockIdx.x * 64;
  const float* Bg = wg_e + (size_t)e*HIDD*Ii;
  const float* Bu = wu_e + (size_t)e*HIDD*Ii;
  __shared__ float As[16][64];
  __shared__ float Bs[16][64];
  __shared__ int toks[64];
  if (threadIdx.x < 64){
    int r = row0 + threadIdx.x;
    toks[threadIdx.x] = (r < cnt) ? tok_list[e*Ntok + r] : 0;
  }
  __syncthreads();
  int tx = threadIdx.x & 15, ty = threadIdx.x >> 4;
  float accg[4][4] = {}, accu[4][4] = {};
  for (int k0=0;k0<HIDD;k0+=16){
    for (int l=threadIdx.x; l<64*16; l+=256){
      int m=l>>4, kk=l&15;
      As[kk][m] = hn[(size_t)toks[m]*HIDD + k0+kk];
    }
    for (int l=threadIdx.x; l<16*64; l+=256){
      int kk=l>>6, nn=l&63;
      Bs[kk][nn] = Bg[(size_t)(k0+kk)*Ii + col0+nn];
    }
    __syncthreads();
    #pragma unroll
    for (int kk=0;kk<16;kk++){
      float a4[4], b4[4];
      #pragma unroll
      for (int i=0;i<4;i++) a4[i]=As[kk][ty*4+i];
      #pragma unroll
      for (int j=0;j<4;j++) b4[j]=Bs[kk][tx*4+j];
      #pragma unroll
      for (int i=0;i<4;i++)
        #pragma unroll
        for (int j=0;j<4;j++) accg[i][j] += a4[i]*b4[j];
    }
    __syncthreads();
    for (int l=threadIdx.x; l<16*64; l+=256){
      int kk=l>>6, nn=l&63;
      Bs[kk][nn] = Bu[(size_t)(k0+kk)*Ii + col0+nn];
    }
    __syncthreads();
    #pragma unroll
    for (int kk=0;kk<16;kk++){
      float a4[4], b4[4];
      #pragma unroll
      for (int i=0;i<4;i++) a4[i]=As[kk][ty*4+i];
      #pragma unroll
      for (int j=0;j<4;j++) b4[j]=Bs[kk][tx*4+j];
      #pragma unroll
      for (int i=0;i<4;i++)
        #pragma unroll
        for (int j=0;j<4;j++) accu[i][j] += a4[i]*b4[j];
    }
    __syncthreads();
  }
  #pragma unroll
  for (int i=0;i<4;i++){
    int r = row0 + ty*4 + i; if (r >= cnt) continue;
    #pragma unroll
    for (int j=0;j<4;j++){
      int cc = col0 + tx*4 + j;
      act[(size_t)(prefix[e]+r)*Ii + cc] = siluf_(accg[i][j]) * accu[i][j];
    }
  }
}

// ---------------- expert stage 2: routed[(tok,slot)] = wt * (act_e @ wd_e) ----------------
__global__ void expert_gemm2(const float* __restrict__ act, const int* __restrict__ tok_list,
                             const int* __restrict__ slot_list, const float* __restrict__ wt_list,
                             const int* __restrict__ counts, const int* __restrict__ prefix,
                             const float* __restrict__ wd_e, float* __restrict__ routed) {
  int e = blockIdx.z;
  int cnt = counts[e];
  int row0 = blockIdx.y * 64;
  if (row0 >= cnt) return;
  int col0 = blockIdx.x * 64;
  const float* A = act + (size_t)prefix[e]*Ii;
  const float* Bw = wd_e + (size_t)e*Ii*HIDD;
  __shared__ float As[16][64];
  __shared__ float Bs[16][64];
  int tx = threadIdx.x & 15, ty = threadIdx.x >> 4;
  float acc[4][4] = {};
  for (int k0=0;k0<Ii;k0+=16){
    for (int l=threadIdx.x; l<64*16; l+=256){
      int m=l>>4, kk=l&15;
      As[kk][m] = (row0+m < cnt) ? A[(size_t)(row0+m)*Ii + k0+kk] : 0.f;
    }
    for (int l=threadIdx.x; l<16*64; l+=256){
      int kk=l>>6, nn=l&63;
      Bs[kk][nn] = Bw[(size_t)(k0+kk)*HIDD + col0+nn];
    }
    __syncthreads();
    #pragma unroll
    for (int kk=0;kk<16;kk++){
      float a4[4], b4[4];
      #pragma unroll
      for (int i=0;i<4;i++) a4[i]=As[kk][ty*4+i];
      #pragma unroll
      for (int j=0;j<4;j++) b4[j]=Bs[kk][tx*4+j];
      #pragma unroll
      for (int i=0;i<4;i++)
        #pragma unroll
        for (int j=0;j<4;j++) acc[i][j] += a4[i]*b4[j];
    }
    __syncthreads();
  }
  #pragma unroll
  for (int i=0;i<4;i++){
    int r = row0 + ty*4 + i; if (r >= cnt) continue;
    int tok = tok_list[e*Ntok + r];
    int sl  = slot_list[e*Ntok + r];
    float wt = wt_list[e*Ntok + r];
    #pragma unroll
    for (int j=0;j<4;j++){
      int cc = col0 + tx*4 + j;
      routed[((size_t)tok*2 + sl)*HIDD + cc] = wt * acc[i][j];
    }
  }
}

__global__ void silu_mul_kernel(float* __restrict__ a, const float* __restrict__ b, int n) {
  int idx = blockIdx.x*256 + threadIdx.x;
  if (idx < n) a[idx] = siluf_(a[idx]) * b[idx];
}

__global__ void final_kernel(const float* __restrict__ h, const float* __restrict__ routed,
                             const float* __restrict__ shr, float* __restrict__ out) {
  int idx = blockIdx.x*256 + threadIdx.x;
  if (idx >= Ntok*HIDD) return;
  int n = idx >> 10, c = idx & 1023;
  out[idx] = h[idx] + routed[(size_t)n*2*HIDD + c] + routed[(size_t)n*2*HIDD + HIDD + c] + shr[idx];
}

// ---------------------------------------------------------------------------
extern "C" void kernel_launch(void* const* d_in, const int* in_sizes, int n_in,
                              void* d_out, int out_size, void* d_ws, size_t ws_size,
                              hipStream_t stream) {
  (void)in_sizes; (void)n_in; (void)out_size; (void)ws_size;
  const float* x        = (const float*)d_in[0];
  const float* norm1_w  = (const float*)d_in[1];
  const float* wq       = (const float*)d_in[2];
  const float* wk       = (const float*)d_in[3];
  const float* wv       = (const float*)d_in[4];
  const float* cq       = (const float*)d_in[5];
  const float* ck       = (const float*)d_in[6];
  const float* cv       = (const float*)d_in[7];
  const float* fa       = (const float*)d_in[8];
  const float* fb       = (const float*)d_in[9];
  const float* bp       = (const float*)d_in[10];
  const float* ga       = (const float*)d_in[11];
  const float* gb       = (const float*)d_in[12];
  const float* A_log    = (const float*)d_in[13];
  const float* dt_bias  = (const float*)d_in[14];
  const float* onorm_w  = (const float*)d_in[15];
  const float* wo       = (const float*)d_in[16];
  const float* norm2_w  = (const float*)d_in[17];
  const float* gate_w   = (const float*)d_in[18];
  const float* gate_b   = (const float*)d_in[19];
  const float* wg_e     = (const float*)d_in[20];
  const float* wu_e     = (const float*)d_in[21];
  const float* wd_e     = (const float*)d_in[22];
  const float* wg_s     = (const float*)d_in[23];
  const float* wu_s     = (const float*)d_in[24];
  const float* wd_s     = (const float*)d_in[25];
  float* out = (float*)d_out;

  float* ws = (float*)d_ws;
  size_t off = 0;
  auto alloc = [&](size_t n){ float* p = ws + off; off += n; return p; };
  float* xn      = alloc((size_t)Ntok*HIDD);
  float* qlin    = alloc((size_t)Ntok*Pp);
  float* klin    = alloc((size_t)Ntok*Pp);
  float* vlin    = alloc((size_t)Ntok*Pp);
  float* qc      = alloc((size_t)Ntok*Pp);
  float* kc      = alloc((size_t)Ntok*Pp);
  float* vc      = alloc((size_t)Ntok*Pp);
  float* gbuf    = alloc((size_t)Ntok*Pp);
  float* gatebuf = alloc((size_t)Ntok*Pp);
  float* obuf    = alloc((size_t)Ntok*Pp);
  float* hbuf    = alloc((size_t)Ntok*HIDD);
  float* hn      = alloc((size_t)Ntok*HIDD);
  float* atmp    = alloc((size_t)Ntok*Dd);
  float* betab   = alloc((size_t)Ntok*Hh);
  float* scores  = alloc((size_t)Ntok*Ee);
  float* sg      = alloc((size_t)Ntok*ISs);
  float* su      = alloc((size_t)Ntok*ISs);
  float* shout   = alloc((size_t)Ntok*HIDD);
  float* act     = alloc((size_t)2*Ntok*Ii);
  float* routed  = alloc((size_t)Ntok*2*HIDD);
  float* wt_list = alloc((size_t)Ee*Ntok);
  int* counts    = (int*)alloc(8);
  int* prefix    = (int*)alloc(8);
  int* tok_list  = (int*)alloc((size_t)Ee*Ntok);
  int* slot_list = (int*)alloc((size_t)Ee*Ntok);

  dim3 blk(256);
  auto gemm_grid = [](int M, int N){ return dim3((N+63)/64, (M+63)/64); };

  // ---- attention branch ----
  rms_kernel<<<Ntok, blk, 0, stream>>>(x, norm1_w, xn, 1e-5f);
  gemm_f32<<<gemm_grid(Ntok,Pp), blk, 0, stream>>>(xn, wq, qlin, Ntok, Pp, HIDD, nullptr);
  gemm_f32<<<gemm_grid(Ntok,Pp), blk, 0, stream>>>(xn, wk, klin, Ntok, Pp, HIDD, nullptr);
  gemm_f32<<<gemm_grid(Ntok,Pp), blk, 0, stream>>>(xn, wv, vlin, Ntok, Pp, HIDD, nullptr);
  int nelem = Ntok*Pp;
  conv_silu_kernel<<<(nelem+255)/256, blk, 0, stream>>>(qlin, cq, qc);
  conv_silu_kernel<<<(nelem+255)/256, blk, 0, stream>>>(klin, ck, kc);
  conv_silu_kernel<<<(nelem+255)/256, blk, 0, stream>>>(vlin, cv, vc);
  l2norm_scale_kernel<<<(Ntok*Hh)/4, blk, 0, stream>>>(qc, 1.f/64.f);   // scale^2
  l2norm_scale_kernel<<<(Ntok*Hh)/4, blk, 0, stream>>>(kc, 0.125f);     // scale
  // decay g
  gemm_f32<<<gemm_grid(Ntok,Dd), blk, 0, stream>>>(xn, fa, atmp, Ntok, Dd, HIDD, nullptr);
  gemm_f32<<<gemm_grid(Ntok,Pp), blk, 0, stream>>>(atmp, fb, gbuf, Ntok, Pp, Dd, nullptr);
  g_kernel<<<(nelem+255)/256, blk, 0, stream>>>(gbuf, A_log, dt_bias);
  // beta
  gemm_f32<<<gemm_grid(Ntok,Hh), blk, 0, stream>>>(xn, bp, betab, Ntok, Hh, HIDD, nullptr);
  sigmoid_kernel<<<(Ntok*Hh+255)/256, blk, 0, stream>>>(betab, Ntok*Hh);
  // output gate
  gemm_f32<<<gemm_grid(Ntok,Dd), blk, 0, stream>>>(xn, ga, atmp, Ntok, Dd, HIDD, nullptr);
  gemm_f32<<<gemm_grid(Ntok,Pp), blk, 0, stream>>>(atmp, gb, gatebuf, Ntok, Pp, Dd, nullptr);
  // scan
  scan_kernel<<<Bb*Hh, dim3(64), 0, stream>>>(qc, kc, vc, gbuf, betab, obuf);
  // output norm * sigmoid(gate)
  onorm_gate_kernel<<<(Ntok*Hh)/4, blk, 0, stream>>>(obuf, onorm_w, gatebuf);
  // wo projection + residual
  gemm_f32<<<gemm_grid(Ntok,HIDD), blk, 0, stream>>>(obuf, wo, hbuf, Ntok, HIDD, Pp, x);

  // ---- MoE branch ----
  rms_kernel<<<Ntok, blk, 0, stream>>>(hbuf, norm2_w, hn, 1e-5f);
  gemm_f32<<<gemm_grid(Ntok,Ee), blk, 0, stream>>>(hn, gate_w, scores, Ntok, Ee, HIDD, nullptr);
  hipMemsetAsync(counts, 0, Ee*sizeof(int), stream);
  router_kernel<<<(Ntok+255)/256, blk, 0, stream>>>(scores, gate_b, counts, tok_list, slot_list, wt_list);
  prefix_kernel<<<1, 64, 0, stream>>>(counts, prefix);
  expert_gemm1<<<dim3(Ii/64, Ntok/64, Ee), blk, 0, stream>>>(hn, tok_list, counts, prefix, wg_e, wu_e, act);
  expert_gemm2<<<dim3(HIDD/64, Ntok/64, Ee), blk, 0, stream>>>(act, tok_list, slot_list, wt_list,
                                                               counts, prefix, wd_e, routed);
  // shared expert
  gemm_f32<<<gemm_grid(Ntok,ISs), blk, 0, stream>>>(hn, wg_s, sg, Ntok, ISs, HIDD, nullptr);
  gemm_f32<<<gemm_grid(Ntok,ISs), blk, 0, stream>>>(hn, wu_s, su, Ntok, ISs, HIDD, nullptr);
  silu_mul_kernel<<<(Ntok*ISs+255)/256, blk, 0, stream>>>(sg, su, Ntok*ISs);
  gemm_f32<<<gemm_grid(Ntok,HIDD), blk, 0, stream>>>(sg, wd_s, shout, Ntok, HIDD, ISs, nullptr);

  // ---- combine ----
  final_kernel<<<(Ntok*HIDD+255)/256, blk, 0, stream>>>(hbuf, routed, shout, out);
}

// Round 3
// 855.092 us; speedup vs baseline: 4.1052x; 4.1052x over previous
//
#include <hip/hip_runtime.h>
#include <hip/hip_bf16.h>
#include <math.h>

#define Bb 2
#define Tt 512
#define HIDD 1024
#define Hh 16
#define Dd 64
#define Pp 1024
#define Kc 4
#define Ee 8
#define Ii 768
#define ISs 768
#define Ntok (Bb*Tt)   // 1024
#define NASSIGN (2*Ntok) // 2048 routed assignments
#define NPAD 2112

typedef __attribute__((ext_vector_type(8))) short bf16x8;
typedef __attribute__((ext_vector_type(4))) float floatx4;

__device__ __forceinline__ float sigmoidf_(float x){ return 1.f/(1.f+expf(-x)); }
__device__ __forceinline__ float siluf_(float x){ return x/(1.f+expf(-x)); }
__device__ __forceinline__ float bf2f(__hip_bfloat16 b){ return __bfloat162float(b); }

__device__ __forceinline__ void async16(void* lds, const void* g) {
  __builtin_amdgcn_global_load_lds(
      (const __attribute__((address_space(1))) void*)g,
      (__attribute__((address_space(3))) void*)lds, 16, 0, 0);
}

// ================= RMS norm (fp32 in, bf16 out) =================
__global__ void rms_bf16_kernel(const float* __restrict__ x, const float* __restrict__ w,
                                __hip_bfloat16* __restrict__ out, float eps) {
  int row = blockIdx.x;
  const float* xr = x + (size_t)row*HIDD;
  float s = 0.f;
  for (int i = threadIdx.x; i < HIDD; i += 256){ float v = xr[i]; s += v*v; }
  #pragma unroll
  for (int off=32; off; off>>=1) s += __shfl_down(s, off, 64);
  __shared__ float red[4];
  if ((threadIdx.x & 63)==0) red[threadIdx.x>>6] = s;
  __syncthreads();
  float tot = red[0]+red[1]+red[2]+red[3];
  float sc = rsqrtf(tot/(float)HIDD + eps);
  for (int i = threadIdx.x; i < HIDD; i += 256)
    out[(size_t)row*HIDD+i] = __float2bfloat16(xr[i]*sc*w[i]);
}

// ================= RMS norm (fp32 in, split hi/lo bf16 out) =================
__global__ void rms_split_kernel(const float* __restrict__ x, const float* __restrict__ w,
                                 __hip_bfloat16* __restrict__ hi, __hip_bfloat16* __restrict__ lo,
                                 float eps) {
  int row = blockIdx.x;
  const float* xr = x + (size_t)row*HIDD;
  float s = 0.f;
  for (int i = threadIdx.x; i < HIDD; i += 256){ float v = xr[i]; s += v*v; }
  #pragma unroll
  for (int off=32; off; off>>=1) s += __shfl_down(s, off, 64);
  __shared__ float red[4];
  if ((threadIdx.x & 63)==0) red[threadIdx.x>>6] = s;
  __syncthreads();
  float tot = red[0]+red[1]+red[2]+red[3];
  float sc = rsqrtf(tot/(float)HIDD + eps);
  for (int i = threadIdx.x; i < HIDD; i += 256) {
    float v = xr[i]*sc*w[i];
    __hip_bfloat16 h = __float2bfloat16(v);
    hi[(size_t)row*HIDD+i] = h;
    lo[(size_t)row*HIDD+i] = __float2bfloat16(v - bf2f(h));
  }
}

// ================= transpose + f32->bf16: src[K][N] -> dst[N][K] =================
__global__ void trans_kernel(const float* __restrict__ src, __hip_bfloat16* __restrict__ dst,
                             int K, int N, long sbs, long dbs) {
  src += (size_t)blockIdx.z * sbs; dst += (size_t)blockIdx.z * dbs;
  __shared__ float tile[32][33];
  int n0 = blockIdx.x*32, k0 = blockIdx.y*32;
  int tx = threadIdx.x & 31, ty0 = threadIdx.x >> 5;
  #pragma unroll
  for (int j=0;j<4;j++){ int ty = ty0 + j*8; tile[ty][tx] = src[(size_t)(k0+ty)*N + n0+tx]; }
  __syncthreads();
  #pragma unroll
  for (int j=0;j<4;j++){ int ty = ty0 + j*8; dst[(size_t)(n0+ty)*K + k0+tx] = __float2bfloat16(tile[tx][ty]); }
}

// ================= transpose + split hi/lo: src[K][N] -> hi/lo[N][K] =================
__global__ void trans_split_kernel(const float* __restrict__ src, __hip_bfloat16* __restrict__ hi,
                                   __hip_bfloat16* __restrict__ lo, int K, int N) {
  __shared__ float tile[32][33];
  int n0 = blockIdx.x*32, k0 = blockIdx.y*32;
  int tx = threadIdx.x & 31, ty0 = threadIdx.x >> 5;
  #pragma unroll
  for (int j=0;j<4;j++){ int ty = ty0 + j*8; tile[ty][tx] = src[(size_t)(k0+ty)*N + n0+tx]; }
  __syncthreads();
  #pragma unroll
  for (int j=0;j<4;j++){
    int ty = ty0 + j*8;
    float v = tile[tx][ty];
    __hip_bfloat16 h = __float2bfloat16(v);
    hi[(size_t)(n0+ty)*K + k0+tx] = h;
    lo[(size_t)(n0+ty)*K + k0+tx] = __float2bfloat16(v - bf2f(h));
  }
}

// ================= MFMA GEMM: C = A[M][K](bf16) @ BT[N][K]^T =================
// MODE 0: f32 out. 1: bf16 out. 2: f32 out + resid. 3: expert compact bf16 out.
// 4: expert scatter f32->bf16 routed out with per-row weight.
// ACC: accumulate into existing f32 C (MODE 0/2 only).
__device__ __forceinline__ int lds_off(int row, int slot){
  return row*128 + (((slot ^ row)&7)<<4);
}

template<int MODE, int ACC>
__global__ __launch_bounds__(256)
void gemm_k(const __hip_bfloat16* __restrict__ A, const __hip_bfloat16* __restrict__ BT,
            void* __restrict__ C, int M, int N, int K, const float* __restrict__ resid,
            const int* __restrict__ counts, const int* __restrict__ prefix,
            const int* __restrict__ ctok, const int* __restrict__ cslot,
            const float* __restrict__ cwt) {
  int Me = M;
  int moff = 0;
  if (MODE >= 3) {
    int e = blockIdx.z;
    Me = counts[e]; moff = prefix[e];
    A  += (size_t)moff * K;
    BT += (size_t)e * (size_t)N * K;
  }
  int row0 = blockIdx.y * 64;
  if (row0 >= Me) return;
  int col0 = blockIdx.x * 64;

  __shared__ __attribute__((aligned(16))) short As[64*64];
  __shared__ __attribute__((aligned(16))) short Bs[64*64];
  const int lane = threadIdx.x & 63;
  const int w    = threadIdx.x >> 6;
  const int wr = w >> 1, wc = w & 1;
  const int srow = lane >> 3;                  // row within 8-row staging group
  const int sch  = (lane & 7) ^ (srow & 7);    // pre-swizzled logical 16B chunk
  const int q = lane >> 4, r16 = lane & 15;

  const __hip_bfloat16* Ag = A  + (size_t)row0 * K;
  const __hip_bfloat16* Bg = BT + (size_t)col0 * K;

  floatx4 acc[2][2] = {};

  for (int k0 = 0; k0 < K; k0 += 64) {
    #pragma unroll
    for (int ii = 0; ii < 2; ++ii) {
      const int inst = w + ii*4;
      const int r = inst*8 + srow;
      async16((char*)As + inst*1024, Ag + (size_t)r*K + (size_t)(k0 + sch*8));
      async16((char*)Bs + inst*1024, Bg + (size_t)r*K + (size_t)(k0 + sch*8));
    }
    __syncthreads();
    #pragma unroll
    for (int kk = 0; kk < 2; ++kk) {
      int slot = kk*4 + q;
      bf16x8 a0 = *(const bf16x8*)((const char*)As + lds_off(wr*32 +      r16, slot));
      bf16x8 a1 = *(const bf16x8*)((const char*)As + lds_off(wr*32 + 16 + r16, slot));
      bf16x8 b0 = *(const bf16x8*)((const char*)Bs + lds_off(wc*32 +      r16, slot));
      bf16x8 b1 = *(const bf16x8*)((const char*)Bs + lds_off(wc*32 + 16 + r16, slot));
      acc[0][0] = __builtin_amdgcn_mfma_f32_16x16x32_bf16(a0, b0, acc[0][0], 0, 0, 0);
      acc[0][1] = __builtin_amdgcn_mfma_f32_16x16x32_bf16(a0, b1, acc[0][1], 0, 0, 0);
      acc[1][0] = __builtin_amdgcn_mfma_f32_16x16x32_bf16(a1, b0, acc[1][0], 0, 0, 0);
      acc[1][1] = __builtin_amdgcn_mfma_f32_16x16x32_bf16(a1, b1, acc[1][1], 0, 0, 0);
    }
    __syncthreads();
  }

  #pragma unroll
  for (int mi = 0; mi < 2; ++mi) {
    #pragma unroll
    for (int r = 0; r < 4; ++r) {
      int grow = row0 + wr*32 + mi*16 + q*4 + r;
      if (grow >= Me) continue;
      #pragma unroll
      for (int ni = 0; ni < 2; ++ni) {
        int gcol = col0 + wc*32 + ni*16 + r16;
        float v = acc[mi][ni][r];
        if (MODE == 0) {
          float* Cp = (float*)C + (size_t)grow*N + gcol;
          if (ACC) v += *Cp;
          *Cp = v;
        } else if (MODE == 2) {
          float* Cp = (float*)C + (size_t)grow*N + gcol;
          if (ACC) v += *Cp;
          *Cp = v + resid[(size_t)grow*N + gcol];
        } else if (MODE == 1) {
          ((__hip_bfloat16*)C)[(size_t)grow*N + gcol] = __float2bfloat16(v);
        } else if (MODE == 3) {
          ((__hip_bfloat16*)C)[(size_t)(moff+grow)*N + gcol] = __float2bfloat16(v);
        } else { // 4
          int rc = moff + grow;
          int tok = ctok[rc], sl = cslot[rc];
          ((__hip_bfloat16*)C)[((size_t)tok*2 + sl)*N + gcol] = __float2bfloat16(cwt[rc]*v);
        }
      }
    }
  }
}

// ================= causal depthwise conv (K=4) + SiLU, fused-QKV input =================
__global__ void conv_silu_kernel(const float* __restrict__ in, const float* __restrict__ w,
                                 float* __restrict__ out, int colOff) {
  int idx = blockIdx.x*256 + threadIdx.x;
  if (idx >= Ntok*Pp) return;
  int c = idx & (Pp-1);
  int tok = idx >> 10;
  int t = tok & (Tt-1);
  float s = 0.f;
  #pragma unroll
  for (int k=0;k<Kc;k++){
    int tt = t - (Kc-1) + k;
    if (tt >= 0) s += w[c*Kc+k] * in[(size_t)(tok-(Kc-1)+k)*3072 + colOff + c];
  }
  out[idx] = siluf_(s);
}

// ================= per-(b,t,h) L2 norm over D=64, then scale =================
__global__ void l2norm_scale_kernel(float* __restrict__ qk, float mul) {
  int row = blockIdx.x*4 + (threadIdx.x>>6);
  int lane = threadIdx.x & 63;
  size_t idx = (size_t)row*Dd + lane;
  float v = qk[idx];
  float s = v*v;
  #pragma unroll
  for (int off=32; off; off>>=1) s += __shfl_xor(s, off, 64);
  qk[idx] = v * rsqrtf(s/(float)Dd + 1e-6f) * mul;
}

// ================= g = exp(-exp(A_log)*softplus(a + dt_bias)) =================
__global__ void g_kernel(float* __restrict__ a, const float* __restrict__ A_log,
                         const float* __restrict__ dt_bias) {
  int idx = blockIdx.x*256 + threadIdx.x;
  if (idx >= Ntok*Pp) return;
  int d = idx & 63;
  int hh = (idx >> 6) & 15;
  float v = a[idx] + dt_bias[hh*Dd + d];
  float sp = (v > 20.f) ? v : log1pf(expf(v));
  a[idx] = expf(-expf(A_log[hh]) * sp);
}

// ================= beta = sigmoid(xn @ bp), N=16 =================
__global__ void beta_kernel(const __hip_bfloat16* __restrict__ xn, const float* __restrict__ bp,
                            float* __restrict__ betab) {
  int row = blockIdx.x;
  int t = threadIdx.x;
  int n = t & 15, ch = t >> 4;           // 16 chunks of 64 k
  float s = 0.f;
  for (int k = ch*64; k < ch*64+64; ++k)
    s += bf2f(xn[(size_t)row*HIDD + k]) * bp[k*16 + n];
  __shared__ float red[256];
  red[t] = s; __syncthreads();
  if (t < 16) {
    float tot = 0.f;
    #pragma unroll
    for (int c2 = 0; c2 < 16; ++c2) tot += red[c2*16 + t];
    betab[(size_t)row*16 + t] = sigmoidf_(tot);
  }
}

// ================= router logits in fp32 directly from hbuf (fused rms) =================
__global__ void router_scores_kernel(const float* __restrict__ h, const float* __restrict__ w2,
                                     const float* __restrict__ gw, float* __restrict__ scores) {
  int row = blockIdx.x;
  const float* hr = h + (size_t)row*HIDD;
  float s = 0.f;
  for (int i = threadIdx.x; i < HIDD; i += 256){ float v = hr[i]; s += v*v; }
  #pragma unroll
  for (int off=32; off; off>>=1) s += __shfl_down(s, off, 64);
  __shared__ float red[4];
  if ((threadIdx.x & 63)==0) red[threadIdx.x>>6] = s;
  __syncthreads();
  float sc = rsqrtf((red[0]+red[1]+red[2]+red[3])/(float)HIDD + 1e-5f);
  float acc[Ee] = {};
  for (int i = threadIdx.x; i < HIDD; i += 256){
    float xv = hr[i]*sc*w2[i];
    #pragma unroll
    for (int e=0;e<Ee;e++) acc[e] += xv*gw[i*Ee+e];
  }
  #pragma unroll
  for (int e=0;e<Ee;e++){
    #pragma unroll
    for (int off=32; off; off>>=1) acc[e] += __shfl_down(acc[e], off, 64);
  }
  __shared__ float red2[4][Ee];
  if ((threadIdx.x & 63)==0){
    #pragma unroll
    for (int e=0;e<Ee;e++) red2[threadIdx.x>>6][e] = acc[e];
  }
  __syncthreads();
  if (threadIdx.x < Ee)
    scores[(size_t)row*Ee + threadIdx.x] =
      red2[0][threadIdx.x]+red2[1][threadIdx.x]+red2[2][threadIdx.x]+red2[3][threadIdx.x];
}

// ================= delta-rule scan: 1 wave per (b,h) =================
__global__ void scan_kernel(const float* __restrict__ q, const float* __restrict__ k,
                            const float* __restrict__ v, const float* __restrict__ g,
                            const float* __restrict__ beta, float* __restrict__ o) {
  int b = blockIdx.x >> 4;
  int hh = blockIdx.x & 15;
  int lane = threadIdx.x;
  __shared__ __attribute__((aligned(16))) float sq[2][64], sk[2][64], sg[2][64];
  float S[64];
  #pragma unroll
  for (int i=0;i<64;i++) S[i]=0.f;
  size_t base = ((size_t)(b*Tt)*Hh + hh)*Dd + lane;
  size_t bbase = (size_t)(b*Tt)*Hh + hh;
  float qn = q[base], kn = k[base], gn = g[base], vn = v[base];
  float btn = beta[bbase];
  for (int t=0;t<Tt;t++){
    int pb = t & 1;
    sq[pb][lane]=qn; sk[pb][lane]=kn; sg[pb][lane]=gn;
    float vt = vn, bt = btn;
    if (t < Tt-1) {
      size_t nb = base + (size_t)(t+1)*Pp;
      qn=q[nb]; kn=k[nb]; gn=g[nb]; vn=v[nb];
      btn = beta[bbase + (size_t)(t+1)*Hh];
    }
    const float4* k4p = (const float4*)sk[pb];
    const float4* g4p = (const float4*)sg[pb];
    const float4* q4p = (const float4*)sq[pb];
    float pred = 0.f;
    #pragma unroll
    for (int kq = 0; kq < 16; ++kq) {
      float4 g4 = g4p[kq], k4 = k4p[kq];
      float s0=S[4*kq+0]*g4.x; S[4*kq+0]=s0; pred += k4.x*s0;
      float s1=S[4*kq+1]*g4.y; S[4*kq+1]=s1; pred += k4.y*s1;
      float s2=S[4*kq+2]*g4.z; S[4*kq+2]=s2; pred += k4.z*s2;
      float s3=S[4*kq+3]*g4.w; S[4*kq+3]=s3; pred += k4.w*s3;
    }
    float upd = (vt - pred)*bt;
    float acc = 0.f;
    #pragma unroll
    for (int kq = 0; kq < 16; ++kq) {
      float4 k4 = k4p[kq], q4 = q4p[kq];
      float s0=S[4*kq+0]+k4.x*upd; S[4*kq+0]=s0; acc += q4.x*s0;
      float s1=S[4*kq+1]+k4.y*upd; S[4*kq+1]=s1; acc += q4.y*s1;
      float s2=S[4*kq+2]+k4.z*upd; S[4*kq+2]=s2; acc += q4.z*s2;
      float s3=S[4*kq+3]+k4.w*upd; S[4*kq+3]=s3; acc += q4.w*s3;
    }
    o[base + (size_t)t*Pp] = acc;
  }
}

// ================= o = rms(o)*w*sigmoid(gate) -> split hi/lo bf16 =================
__global__ void onorm_gate_split_kernel(const float* __restrict__ o, const float* __restrict__ w,
                                        const float* __restrict__ gate,
                                        __hip_bfloat16* __restrict__ hi, __hip_bfloat16* __restrict__ lo) {
  int row = blockIdx.x*4 + (threadIdx.x>>6);
  int lane = threadIdx.x & 63;
  size_t idx = (size_t)row*Dd + lane;
  float v = o[idx];
  float s = v*v;
  #pragma unroll
  for (int off=32; off; off>>=1) s += __shfl_xor(s, off, 64);
  float r = v * rsqrtf(s/(float)Dd + 1e-5f) * w[lane] * sigmoidf_(gate[idx]);
  __hip_bfloat16 h = __float2bfloat16(r);
  hi[idx] = h;
  lo[idx] = __float2bfloat16(r - bf2f(h));
}

// ================= router top-2 =================
__global__ void router_kernel(const float* __restrict__ logits, const float* __restrict__ gate_b,
                              int* __restrict__ counts, int* __restrict__ tok_list,
                              int* __restrict__ slot_list, float* __restrict__ wt_list) {
  int n = blockIdx.x*256 + threadIdx.x;
  if (n >= Ntok) return;
  float sc[Ee], bi[Ee];
  #pragma unroll
  for (int e=0;e<Ee;e++){ float s = sigmoidf_(logits[n*Ee+e]); sc[e]=s; bi[e]=s+gate_b[e]; }
  int i0=0;
  #pragma unroll
  for (int e=1;e<Ee;e++) if (bi[e] > bi[i0]) i0=e;
  int i1=-1;
  #pragma unroll
  for (int e=0;e<Ee;e++){ if (e==i0) continue; if (i1<0 || bi[e] > bi[i1]) i1=e; }
  float w0=sc[i0], w1=sc[i1];
  float inv = 1.f/(w0+w1+1e-20f);
  w0*=inv; w1*=inv;
  int p0 = atomicAdd(&counts[i0],1);
  tok_list[i0*Ntok+p0]=n; slot_list[i0*Ntok+p0]=0; wt_list[i0*Ntok+p0]=w0;
  int p1 = atomicAdd(&counts[i1],1);
  tok_list[i1*Ntok+p1]=n; slot_list[i1*Ntok+p1]=1; wt_list[i1*Ntok+p1]=w1;
}

__global__ void prefix_kernel(const int* __restrict__ counts, int* __restrict__ prefix) {
  if (threadIdx.x==0 && blockIdx.x==0){ int s=0; for (int e=0;e<Ee;e++){ prefix[e]=s; s+=counts[e]; } }
}

__global__ void compact_kernel(const int* __restrict__ counts, const int* __restrict__ prefix,
                               const int* __restrict__ tok_list, const int* __restrict__ slot_list,
                               const float* __restrict__ wt_list,
                               int* __restrict__ ctok, int* __restrict__ cslot, float* __restrict__ cwt) {
  int e = blockIdx.x; int c = counts[e], p = prefix[e];
  for (int i = threadIdx.x; i < c; i += 256) {
    ctok[p+i]  = tok_list[e*Ntok+i];
    cslot[p+i] = slot_list[e*Ntok+i];
    cwt[p+i]   = wt_list[e*Ntok+i];
  }
}

__global__ void gather_kernel(const __hip_bfloat16* __restrict__ hn, const int* __restrict__ ctok,
                              __hip_bfloat16* __restrict__ Ae) {
  int r = blockIdx.x;
  int t = threadIdx.x; // 128
  ((int4*)(Ae + (size_t)r*HIDD))[t] = ((const int4*)(hn + (size_t)ctok[r]*HIDD))[t];
}

// ================= GLU: out = silu(gu[:, :768]) * gu[:, 768:] =================
__global__ void glu_kernel(const __hip_bfloat16* __restrict__ gu, __hip_bfloat16* __restrict__ outp,
                           int rows) {
  int idx = blockIdx.x*256 + threadIdx.x;
  if (idx >= rows*Ii) return;
  int r = idx / Ii, c2 = idx - r*Ii;
  float gv = bf2f(gu[(size_t)r*(2*Ii) + c2]);
  float uv = bf2f(gu[(size_t)r*(2*Ii) + Ii + c2]);
  outp[idx] = __float2bfloat16(siluf_(gv)*uv);
}

__global__ void final_kernel(const float* __restrict__ h, const __hip_bfloat16* __restrict__ routed,
                             const float* __restrict__ shr, float* __restrict__ out) {
  int idx = blockIdx.x*256 + threadIdx.x;
  if (idx >= Ntok*HIDD) return;
  int n = idx >> 10, c = idx & 1023;
  out[idx] = h[idx] + bf2f(routed[(size_t)n*2*HIDD + c]) + bf2f(routed[(size_t)n*2*HIDD + HIDD + c]) + shr[idx];
}

// ---------------------------------------------------------------------------
extern "C" void kernel_launch(void* const* d_in, const int* in_sizes, int n_in,
                              void* d_out, int out_size, void* d_ws, size_t ws_size,
                              hipStream_t stream) {
  (void)in_sizes; (void)n_in; (void)out_size; (void)ws_size;
  const float* x        = (const float*)d_in[0];
  const float* norm1_w  = (const float*)d_in[1];
  const float* wq       = (const float*)d_in[2];
  const float* wk       = (const float*)d_in[3];
  const float* wv       = (const float*)d_in[4];
  const float* cq       = (const float*)d_in[5];
  const float* ck       = (const float*)d_in[6];
  const float* cv       = (const float*)d_in[7];
  const float* fa       = (const float*)d_in[8];
  const float* fb       = (const float*)d_in[9];
  const float* bp       = (const float*)d_in[10];
  const float* ga       = (const float*)d_in[11];
  const float* gb       = (const float*)d_in[12];
  const float* A_log    = (const float*)d_in[13];
  const float* dt_bias  = (const float*)d_in[14];
  const float* onorm_w  = (const float*)d_in[15];
  const float* wo       = (const float*)d_in[16];
  const float* norm2_w  = (const float*)d_in[17];
  const float* gate_w   = (const float*)d_in[18];
  const float* gate_b   = (const float*)d_in[19];
  const float* wg_e     = (const float*)d_in[20];
  const float* wu_e     = (const float*)d_in[21];
  const float* wd_e     = (const float*)d_in[22];
  const float* wg_s     = (const float*)d_in[23];
  const float* wu_s     = (const float*)d_in[24];
  const float* wd_s     = (const float*)d_in[25];
  float* out = (float*)d_out;

  char* base = (char*)d_ws;
  size_t off = 0;
  auto alloc = [&](size_t bytes)->char* {
    off = (off + 255) & ~(size_t)255;
    char* p = base + off; off += bytes; return p;
  };
  // persistent
  float* hbuf = (float*)alloc((size_t)Ntok*HIDD*4);
  size_t uStart = (off + 255) & ~(size_t)255;

  // ---- attention view ----
  off = uStart;
  __hip_bfloat16* xn      = (__hip_bfloat16*)alloc((size_t)Ntok*HIDD*2);
  __hip_bfloat16* xn_lo   = (__hip_bfloat16*)alloc((size_t)Ntok*HIDD*2);
  __hip_bfloat16* wqkv_t  = (__hip_bfloat16*)alloc((size_t)3*Pp*HIDD*2);
  __hip_bfloat16* wqkv_lo = (__hip_bfloat16*)alloc((size_t)3*Pp*HIDD*2);
  float*          qkvlin  = (float*)alloc((size_t)Ntok*3*Pp*4);
  float*          qc      = (float*)alloc((size_t)Ntok*Pp*4);
  float*          kc      = (float*)alloc((size_t)Ntok*Pp*4);
  float*          vc      = (float*)alloc((size_t)Ntok*Pp*4);
  float*          gbuf    = (float*)alloc((size_t)Ntok*Pp*4);
  float*          gatebuf = (float*)alloc((size_t)Ntok*Pp*4);
  float*          obuf    = (float*)alloc((size_t)Ntok*Pp*4);
  __hip_bfloat16* atmp    = (__hip_bfloat16*)alloc((size_t)Ntok*Dd*2);
  __hip_bfloat16* atmp2   = (__hip_bfloat16*)alloc((size_t)Ntok*Dd*2);
  float*          betab   = (float*)alloc((size_t)Ntok*Hh*4);
  __hip_bfloat16* obuf_hi = (__hip_bfloat16*)alloc((size_t)Ntok*Pp*2);
  __hip_bfloat16* obuf_lo = (__hip_bfloat16*)alloc((size_t)Ntok*Pp*2);
  __hip_bfloat16* wo_t    = (__hip_bfloat16*)alloc((size_t)HIDD*Pp*2);
  __hip_bfloat16* wo_lo   = (__hip_bfloat16*)alloc((size_t)HIDD*Pp*2);
  __hip_bfloat16* fa_t    = (__hip_bfloat16*)alloc((size_t)Dd*HIDD*2);
  __hip_bfloat16* fb_t    = (__hip_bfloat16*)alloc((size_t)Pp*Dd*2);
  __hip_bfloat16* ga_t    = (__hip_bfloat16*)alloc((size_t)Dd*HIDD*2);
  __hip_bfloat16* gb_t    = (__hip_bfloat16*)alloc((size_t)Pp*Dd*2);

  // ---- moe view (overlaps attention view) ----
  off = uStart;
  __hip_bfloat16* hn      = (__hip_bfloat16*)alloc((size_t)Ntok*HIDD*2);
  float*          scores  = (float*)alloc((size_t)Ntok*Ee*4);
  int*            counts  = (int*)alloc(64);
  int*            prefix  = (int*)alloc(64);
  int*            tok_list  = (int*)alloc((size_t)Ee*Ntok*4);
  int*            slot_list = (int*)alloc((size_t)Ee*Ntok*4);
  float*          wt_list   = (float*)alloc((size_t)Ee*Ntok*4);
  int*            ctok    = (int*)alloc((size_t)NPAD*4);
  int*            cslot   = (int*)alloc((size_t)NPAD*4);
  float*          cwt     = (float*)alloc((size_t)NPAD*4);
  __hip_bfloat16* egu_t   = (__hip_bfloat16*)alloc((size_t)Ee*2*Ii*HIDD*2);
  __hip_bfloat16* sgu_t   = (__hip_bfloat16*)alloc((size_t)2*ISs*HIDD*2);
  __hip_bfloat16* sd_t    = (__hip_bfloat16*)alloc((size_t)HIDD*ISs*2);
  __hip_bfloat16* act     = (__hip_bfloat16*)alloc((size_t)NPAD*Ii*2);
  __hip_bfloat16* sgu_raw = (__hip_bfloat16*)alloc((size_t)Ntok*2*ISs*2);
  __hip_bfloat16* sgb     = (__hip_bfloat16*)alloc((size_t)Ntok*ISs*2);
  __hip_bfloat16* routed  = (__hip_bfloat16*)alloc((size_t)Ntok*2*HIDD*2);
  float*          shout   = (float*)alloc((size_t)Ntok*HIDD*4);
  // X region: Ae+actg, later reused by ed_t
  size_t xStart = (off + 255) & ~(size_t)255;
  off = xStart;
  __hip_bfloat16* Ae      = (__hip_bfloat16*)alloc((size_t)NPAD*HIDD*2);
  __hip_bfloat16* actg    = (__hip_bfloat16*)alloc((size_t)NPAD*2*Ii*2);
  off = xStart;
  __hip_bfloat16* ed_t    = (__hip_bfloat16*)alloc((size_t)Ee*HIDD*Ii*2);

  dim3 blk(256);
  const int nelem = Ntok*Pp;
  #define NO6 nullptr, nullptr, nullptr, nullptr, nullptr, nullptr

  // ================= attention =================
  rms_split_kernel<<<Ntok, blk, 0, stream>>>(x, norm1_w, xn, xn_lo, 1e-5f);
  // weight transposes (split for QKV and wo, plain for the rest)
  trans_split_kernel<<<dim3(32,32,1), blk, 0, stream>>>(wq, wqkv_t, wqkv_lo, HIDD, Pp);
  trans_split_kernel<<<dim3(32,32,1), blk, 0, stream>>>(wk, wqkv_t + (size_t)Pp*HIDD,
                                                        wqkv_lo + (size_t)Pp*HIDD, HIDD, Pp);
  trans_split_kernel<<<dim3(32,32,1), blk, 0, stream>>>(wv, wqkv_t + (size_t)2*Pp*HIDD,
                                                        wqkv_lo + (size_t)2*Pp*HIDD, HIDD, Pp);
  trans_split_kernel<<<dim3(32,32,1), blk, 0, stream>>>(wo, wo_t, wo_lo, Pp, HIDD);
  trans_kernel<<<dim3(2,32,1),  blk, 0, stream>>>(fa, fa_t, HIDD, Dd, 0, 0);
  trans_kernel<<<dim3(32,2,1),  blk, 0, stream>>>(fb, fb_t, Dd, Pp, 0, 0);
  trans_kernel<<<dim3(2,32,1),  blk, 0, stream>>>(ga, ga_t, HIDD, Dd, 0, 0);
  trans_kernel<<<dim3(32,2,1),  blk, 0, stream>>>(gb, gb_t, Dd, Pp, 0, 0);

  // QKV: 3-pass split-bf16 GEMM (~fp32 precision)
  gemm_k<0,0><<<dim3(48,16,1), blk, 0, stream>>>(xn,    wqkv_t,  qkvlin, Ntok, 3*Pp, HIDD, NO6);
  gemm_k<0,1><<<dim3(48,16,1), blk, 0, stream>>>(xn,    wqkv_lo, qkvlin, Ntok, 3*Pp, HIDD, NO6);
  gemm_k<0,1><<<dim3(48,16,1), blk, 0, stream>>>(xn_lo, wqkv_t,  qkvlin, Ntok, 3*Pp, HIDD, NO6);
  conv_silu_kernel<<<(nelem+255)/256, blk, 0, stream>>>(qkvlin, cq, qc, 0);
  conv_silu_kernel<<<(nelem+255)/256, blk, 0, stream>>>(qkvlin, ck, kc, Pp);
  conv_silu_kernel<<<(nelem+255)/256, blk, 0, stream>>>(qkvlin, cv, vc, 2*Pp);
  l2norm_scale_kernel<<<(Ntok*Hh)/4, blk, 0, stream>>>(qc, 1.f/64.f);
  l2norm_scale_kernel<<<(Ntok*Hh)/4, blk, 0, stream>>>(kc, 0.125f);
  gemm_k<1,0><<<dim3(1,16,1), blk, 0, stream>>>(xn, fa_t, atmp, Ntok, Dd, HIDD, NO6);
  gemm_k<0,0><<<dim3(16,16,1), blk, 0, stream>>>(atmp, fb_t, gbuf, Ntok, Pp, Dd, NO6);
  g_kernel<<<(nelem+255)/256, blk, 0, stream>>>(gbuf, A_log, dt_bias);
  beta_kernel<<<Ntok, blk, 0, stream>>>(xn, bp, betab);
  gemm_k<1,0><<<dim3(1,16,1), blk, 0, stream>>>(xn, ga_t, atmp2, Ntok, Dd, HIDD, NO6);
  gemm_k<0,0><<<dim3(16,16,1), blk, 0, stream>>>(atmp2, gb_t, gatebuf, Ntok, Pp, Dd, NO6);
  scan_kernel<<<Bb*Hh, dim3(64), 0, stream>>>(qc, kc, vc, gbuf, betab, obuf);
  onorm_gate_split_kernel<<<(Ntok*Hh)/4, blk, 0, stream>>>(obuf, onorm_w, gatebuf, obuf_hi, obuf_lo);
  // wo: 3-pass split-bf16 GEMM, residual added on last pass
  gemm_k<0,0><<<dim3(16,16,1), blk, 0, stream>>>(obuf_hi, wo_t,  hbuf, Ntok, HIDD, Pp, NO6);
  gemm_k<0,1><<<dim3(16,16,1), blk, 0, stream>>>(obuf_hi, wo_lo, hbuf, Ntok, HIDD, Pp, NO6);
  gemm_k<2,1><<<dim3(16,16,1), blk, 0, stream>>>(obuf_lo, wo_t,  hbuf, Ntok, HIDD, Pp,
                                                 x, nullptr, nullptr, nullptr, nullptr, nullptr);

  // ================= MoE =================
  rms_bf16_kernel<<<Ntok, blk, 0, stream>>>(hbuf, norm2_w, hn, 1e-5f);
  router_scores_kernel<<<Ntok, blk, 0, stream>>>(hbuf, norm2_w, gate_w, scores);
  hipMemsetAsync(counts, 0, Ee*sizeof(int), stream);
  router_kernel<<<(Ntok+255)/256, blk, 0, stream>>>(scores, gate_b, counts, tok_list, slot_list, wt_list);
  prefix_kernel<<<1, 64, 0, stream>>>(counts, prefix);
  compact_kernel<<<Ee, blk, 0, stream>>>(counts, prefix, tok_list, slot_list, wt_list, ctok, cslot, cwt);
  gather_kernel<<<NASSIGN, dim3(128), 0, stream>>>(hn, ctok, Ae);
  // expert up: wg (rows 0..767 of each expert's BT) and wu (rows 768..1535)
  trans_kernel<<<dim3(24,32,Ee), blk, 0, stream>>>(wg_e, egu_t,
      HIDD, Ii, (long)HIDD*Ii, (long)2*Ii*HIDD);
  trans_kernel<<<dim3(24,32,Ee), blk, 0, stream>>>(wu_e, egu_t + (size_t)Ii*HIDD,
      HIDD, Ii, (long)HIDD*Ii, (long)2*Ii*HIDD);
  gemm_k<3,0><<<dim3(24,16,Ee), blk, 0, stream>>>(Ae, egu_t, actg, Ntok, 2*Ii, HIDD,
                                                  nullptr, counts, prefix, nullptr, nullptr, nullptr);
  glu_kernel<<<(NASSIGN*Ii+255)/256, blk, 0, stream>>>(actg, act, NASSIGN);
  // now Ae/actg dead -> transpose wd into the same region
  trans_kernel<<<dim3(32,24,Ee), blk, 0, stream>>>(wd_e, ed_t,
      Ii, HIDD, (long)Ii*HIDD, (long)HIDD*Ii);
  gemm_k<4,0><<<dim3(16,16,Ee), blk, 0, stream>>>(act, ed_t, routed, Ntok, HIDD, Ii,
                                                  nullptr, counts, prefix, ctok, cslot, cwt);
  // shared expert
  trans_kernel<<<dim3(24,32,1), blk, 0, stream>>>(wg_s, sgu_t, HIDD, ISs, 0, 0);
  trans_kernel<<<dim3(24,32,1), blk, 0, stream>>>(wu_s, sgu_t + (size_t)ISs*HIDD, HIDD, ISs, 0, 0);
  trans_kernel<<<dim3(32,24,1), blk, 0, stream>>>(wd_s, sd_t, ISs, HIDD, 0, 0);
  gemm_k<1,0><<<dim3(24,16,1), blk, 0, stream>>>(hn, sgu_t, sgu_raw, Ntok, 2*ISs, HIDD, NO6);
  glu_kernel<<<(Ntok*ISs+255)/256, blk, 0, stream>>>(sgu_raw, sgb, Ntok);
  gemm_k<0,0><<<dim3(16,16,1), blk, 0, stream>>>(sgb, sd_t, shout, Ntok, HIDD, ISs, NO6);

  final_kernel<<<(Ntok*HIDD+255)/256, blk, 0, stream>>>(hbuf, routed, shout, out);
}

// Round 4
// 488.916 us; speedup vs baseline: 7.1799x; 1.7490x over previous
//
#include <hip/hip_runtime.h>
#include <hip/hip_bf16.h>
#include <math.h>

#define Bb 2
#define Tt 512
#define HIDD 1024
#define Hh 16
#define Dd 64
#define Pp 1024
#define Kc 4
#define Ee 8
#define Ii 768
#define ISs 768
#define Ntok (Bb*Tt)   // 1024
#define NASSIGN (2*Ntok) // 2048 routed assignments
#define NPAD 2112
#define CH 16
#define NCH (Tt/CH)

typedef __attribute__((ext_vector_type(8))) short bf16x8;
typedef __attribute__((ext_vector_type(4))) float floatx4;

__device__ __forceinline__ float sigmoidf_(float x){ return 1.f/(1.f+expf(-x)); }
__device__ __forceinline__ float siluf_(float x){ return x/(1.f+expf(-x)); }
__device__ __forceinline__ float bf2f(__hip_bfloat16 b){ return __bfloat162float(b); }

__device__ __forceinline__ void async16(void* lds, const void* g) {
  __builtin_amdgcn_global_load_lds(
      (const __attribute__((address_space(1))) void*)g,
      (__attribute__((address_space(3))) void*)lds, 16, 0, 0);
}

// ================= RMS norm (fp32 in, bf16 out) =================
__global__ void rms_bf16_kernel(const float* __restrict__ x, const float* __restrict__ w,
                                __hip_bfloat16* __restrict__ out, float eps) {
  int row = blockIdx.x;
  const float* xr = x + (size_t)row*HIDD;
  float s = 0.f;
  for (int i = threadIdx.x; i < HIDD; i += 256){ float v = xr[i]; s += v*v; }
  #pragma unroll
  for (int off=32; off; off>>=1) s += __shfl_down(s, off, 64);
  __shared__ float red[4];
  if ((threadIdx.x & 63)==0) red[threadIdx.x>>6] = s;
  __syncthreads();
  float tot = red[0]+red[1]+red[2]+red[3];
  float sc = rsqrtf(tot/(float)HIDD + eps);
  for (int i = threadIdx.x; i < HIDD; i += 256)
    out[(size_t)row*HIDD+i] = __float2bfloat16(xr[i]*sc*w[i]);
}

// ================= RMS norm (fp32 in, split hi/lo bf16 out) =================
__global__ void rms_split_kernel(const float* __restrict__ x, const float* __restrict__ w,
                                 __hip_bfloat16* __restrict__ hi, __hip_bfloat16* __restrict__ lo,
                                 float eps) {
  int row = blockIdx.x;
  const float* xr = x + (size_t)row*HIDD;
  float s = 0.f;
  for (int i = threadIdx.x; i < HIDD; i += 256){ float v = xr[i]; s += v*v; }
  #pragma unroll
  for (int off=32; off; off>>=1) s += __shfl_down(s, off, 64);
  __shared__ float red[4];
  if ((threadIdx.x & 63)==0) red[threadIdx.x>>6] = s;
  __syncthreads();
  float tot = red[0]+red[1]+red[2]+red[3];
  float sc = rsqrtf(tot/(float)HIDD + eps);
  for (int i = threadIdx.x; i < HIDD; i += 256) {
    float v = xr[i]*sc*w[i];
    __hip_bfloat16 h = __float2bfloat16(v);
    hi[(size_t)row*HIDD+i] = h;
    lo[(size_t)row*HIDD+i] = __float2bfloat16(v - bf2f(h));
  }
}

// ================= transpose + f32->bf16: src[K][N] -> dst[N][K] =================
__global__ void trans_kernel(const float* __restrict__ src, __hip_bfloat16* __restrict__ dst,
                             int K, int N, long sbs, long dbs) {
  src += (size_t)blockIdx.z * sbs; dst += (size_t)blockIdx.z * dbs;
  __shared__ float tile[32][33];
  int n0 = blockIdx.x*32, k0 = blockIdx.y*32;
  int tx = threadIdx.x & 31, ty0 = threadIdx.x >> 5;
  #pragma unroll
  for (int j=0;j<4;j++){ int ty = ty0 + j*8; tile[ty][tx] = src[(size_t)(k0+ty)*N + n0+tx]; }
  __syncthreads();
  #pragma unroll
  for (int j=0;j<4;j++){ int ty = ty0 + j*8; dst[(size_t)(n0+ty)*K + k0+tx] = __float2bfloat16(tile[tx][ty]); }
}

// ================= transpose + split hi/lo: src[K][N] -> hi/lo[N][K] =================
__global__ void trans_split_kernel(const float* __restrict__ src, __hip_bfloat16* __restrict__ hi,
                                   __hip_bfloat16* __restrict__ lo, int K, int N) {
  __shared__ float tile[32][33];
  int n0 = blockIdx.x*32, k0 = blockIdx.y*32;
  int tx = threadIdx.x & 31, ty0 = threadIdx.x >> 5;
  #pragma unroll
  for (int j=0;j<4;j++){ int ty = ty0 + j*8; tile[ty][tx] = src[(size_t)(k0+ty)*N + n0+tx]; }
  __syncthreads();
  #pragma unroll
  for (int j=0;j<4;j++){
    int ty = ty0 + j*8;
    float v = tile[tx][ty];
    __hip_bfloat16 h = __float2bfloat16(v);
    hi[(size_t)(n0+ty)*K + k0+tx] = h;
    lo[(size_t)(n0+ty)*K + k0+tx] = __float2bfloat16(v - bf2f(h));
  }
}

// ================= MFMA GEMM: C = A[M][K](bf16) @ BT[N][K]^T =================
// MODE 0: f32 out. 1: bf16 out. 2: f32 out + resid. 3: expert compact bf16 out.
// 4: expert scatter f32->bf16 routed out with per-row weight.
// ACC: accumulate into existing f32 C (MODE 0/2 only).
__device__ __forceinline__ int lds_off(int row, int slot){
  return row*128 + (((slot ^ row)&7)<<4);
}

template<int MODE, int ACC>
__global__ __launch_bounds__(256)
void gemm_k(const __hip_bfloat16* __restrict__ A, const __hip_bfloat16* __restrict__ BT,
            void* __restrict__ C, int M, int N, int K, const float* __restrict__ resid,
            const int* __restrict__ counts, const int* __restrict__ prefix,
            const int* __restrict__ ctok, const int* __restrict__ cslot,
            const float* __restrict__ cwt) {
  int Me = M;
  int moff = 0;
  if (MODE >= 3) {
    int e = blockIdx.z;
    Me = counts[e]; moff = prefix[e];
    A  += (size_t)moff * K;
    BT += (size_t)e * (size_t)N * K;
  }
  int row0 = blockIdx.y * 64;
  if (row0 >= Me) return;
  int col0 = blockIdx.x * 64;

  __shared__ __attribute__((aligned(16))) short As[64*64];
  __shared__ __attribute__((aligned(16))) short Bs[64*64];
  const int lane = threadIdx.x & 63;
  const int w    = threadIdx.x >> 6;
  const int wr = w >> 1, wc = w & 1;
  const int srow = lane >> 3;                  // row within 8-row staging group
  const int sch  = (lane & 7) ^ (srow & 7);    // pre-swizzled logical 16B chunk
  const int q = lane >> 4, r16 = lane & 15;

  const __hip_bfloat16* Ag = A  + (size_t)row0 * K;
  const __hip_bfloat16* Bg = BT + (size_t)col0 * K;

  floatx4 acc[2][2] = {};

  for (int k0 = 0; k0 < K; k0 += 64) {
    #pragma unroll
    for (int ii = 0; ii < 2; ++ii) {
      const int inst = w + ii*4;
      const int r = inst*8 + srow;
      async16((char*)As + inst*1024, Ag + (size_t)r*K + (size_t)(k0 + sch*8));
      async16((char*)Bs + inst*1024, Bg + (size_t)r*K + (size_t)(k0 + sch*8));
    }
    __syncthreads();
    #pragma unroll
    for (int kk = 0; kk < 2; ++kk) {
      int slot = kk*4 + q;
      bf16x8 a0 = *(const bf16x8*)((const char*)As + lds_off(wr*32 +      r16, slot));
      bf16x8 a1 = *(const bf16x8*)((const char*)As + lds_off(wr*32 + 16 + r16, slot));
      bf16x8 b0 = *(const bf16x8*)((const char*)Bs + lds_off(wc*32 +      r16, slot));
      bf16x8 b1 = *(const bf16x8*)((const char*)Bs + lds_off(wc*32 + 16 + r16, slot));
      acc[0][0] = __builtin_amdgcn_mfma_f32_16x16x32_bf16(a0, b0, acc[0][0], 0, 0, 0);
      acc[0][1] = __builtin_amdgcn_mfma_f32_16x16x32_bf16(a0, b1, acc[0][1], 0, 0, 0);
      acc[1][0] = __builtin_amdgcn_mfma_f32_16x16x32_bf16(a1, b0, acc[1][0], 0, 0, 0);
      acc[1][1] = __builtin_amdgcn_mfma_f32_16x16x32_bf16(a1, b1, acc[1][1], 0, 0, 0);
    }
    __syncthreads();
  }

  #pragma unroll
  for (int mi = 0; mi < 2; ++mi) {
    #pragma unroll
    for (int r = 0; r < 4; ++r) {
      int grow = row0 + wr*32 + mi*16 + q*4 + r;
      if (grow >= Me) continue;
      #pragma unroll
      for (int ni = 0; ni < 2; ++ni) {
        int gcol = col0 + wc*32 + ni*16 + r16;
        float v = acc[mi][ni][r];
        if (MODE == 0) {
          float* Cp = (float*)C + (size_t)grow*N + gcol;
          if (ACC) v += *Cp;
          *Cp = v;
        } else if (MODE == 2) {
          float* Cp = (float*)C + (size_t)grow*N + gcol;
          if (ACC) v += *Cp;
          *Cp = v + resid[(size_t)grow*N + gcol];
        } else if (MODE == 1) {
          ((__hip_bfloat16*)C)[(size_t)grow*N + gcol] = __float2bfloat16(v);
        } else if (MODE == 3) {
          ((__hip_bfloat16*)C)[(size_t)(moff+grow)*N + gcol] = __float2bfloat16(v);
        } else { // 4
          int rc = moff + grow;
          int tok = ctok[rc], sl = cslot[rc];
          ((__hip_bfloat16*)C)[((size_t)tok*2 + sl)*N + gcol] = __float2bfloat16(cwt[rc]*v);
        }
      }
    }
  }
}

// ================= causal depthwise conv (K=4) + SiLU, fused-QKV input =================
__global__ void conv_silu_kernel(const float* __restrict__ in, const float* __restrict__ w,
                                 float* __restrict__ out, int colOff) {
  int idx = blockIdx.x*256 + threadIdx.x;
  if (idx >= Ntok*Pp) return;
  int c = idx & (Pp-1);
  int tok = idx >> 10;
  int t = tok & (Tt-1);
  float s = 0.f;
  #pragma unroll
  for (int k=0;k<Kc;k++){
    int tt = t - (Kc-1) + k;
    if (tt >= 0) s += w[c*Kc+k] * in[(size_t)(tok-(Kc-1)+k)*3072 + colOff + c];
  }
  out[idx] = siluf_(s);
}

// ================= per-(b,t,h) L2 norm over D=64, then scale =================
__global__ void l2norm_scale_kernel(float* __restrict__ qk, float mul) {
  int row = blockIdx.x*4 + (threadIdx.x>>6);
  int lane = threadIdx.x & 63;
  size_t idx = (size_t)row*Dd + lane;
  float v = qk[idx];
  float s = v*v;
  #pragma unroll
  for (int off=32; off; off>>=1) s += __shfl_xor(s, off, 64);
  qk[idx] = v * rsqrtf(s/(float)Dd + 1e-6f) * mul;
}

// ================= g = exp(-exp(A_log)*softplus(a + dt_bias)) =================
__global__ void g_kernel(float* __restrict__ a, const float* __restrict__ A_log,
                         const float* __restrict__ dt_bias) {
  int idx = blockIdx.x*256 + threadIdx.x;
  if (idx >= Ntok*Pp) return;
  int d = idx & 63;
  int hh = (idx >> 6) & 15;
  float v = a[idx] + dt_bias[hh*Dd + d];
  float sp = (v > 20.f) ? v : log1pf(expf(v));
  a[idx] = expf(-expf(A_log[hh]) * sp);
}

// ================= beta = sigmoid(xn @ bp), N=16 =================
__global__ void beta_kernel(const __hip_bfloat16* __restrict__ xn, const float* __restrict__ bp,
                            float* __restrict__ betab) {
  int row = blockIdx.x;
  int t = threadIdx.x;
  int n = t & 15, ch = t >> 4;           // 16 chunks of 64 k
  float s = 0.f;
  for (int k = ch*64; k < ch*64+64; ++k)
    s += bf2f(xn[(size_t)row*HIDD + k]) * bp[k*16 + n];
  __shared__ float red[256];
  red[t] = s; __syncthreads();
  if (t < 16) {
    float tot = 0.f;
    #pragma unroll
    for (int c2 = 0; c2 < 16; ++c2) tot += red[c2*16 + t];
    betab[(size_t)row*16 + t] = sigmoidf_(tot);
  }
}

// ================= router logits in fp32 directly from hbuf (fused rms) =================
__global__ void router_scores_kernel(const float* __restrict__ h, const float* __restrict__ w2,
                                     const float* __restrict__ gw, float* __restrict__ scores) {
  int row = blockIdx.x;
  const float* hr = h + (size_t)row*HIDD;
  float s = 0.f;
  for (int i = threadIdx.x; i < HIDD; i += 256){ float v = hr[i]; s += v*v; }
  #pragma unroll
  for (int off=32; off; off>>=1) s += __shfl_down(s, off, 64);
  __shared__ float red[4];
  if ((threadIdx.x & 63)==0) red[threadIdx.x>>6] = s;
  __syncthreads();
  float sc = rsqrtf((red[0]+red[1]+red[2]+red[3])/(float)HIDD + 1e-5f);
  float acc[Ee] = {};
  for (int i = threadIdx.x; i < HIDD; i += 256){
    float xv = hr[i]*sc*w2[i];
    #pragma unroll
    for (int e=0;e<Ee;e++) acc[e] += xv*gw[i*Ee+e];
  }
  #pragma unroll
  for (int e=0;e<Ee;e++){
    #pragma unroll
    for (int off=32; off; off>>=1) acc[e] += __shfl_down(acc[e], off, 64);
  }
  __shared__ float red2[4][Ee];
  if ((threadIdx.x & 63)==0){
    #pragma unroll
    for (int e=0;e<Ee;e++) red2[threadIdx.x>>6][e] = acc[e];
  }
  __syncthreads();
  if (threadIdx.x < Ee)
    scores[(size_t)row*Ee + threadIdx.x] =
      red2[0][threadIdx.x]+red2[1][threadIdx.x]+red2[2][threadIdx.x]+red2[3][threadIdx.x];
}

// ================= delta-rule scan v2: 128 blocks, chunked LDS staging =================
// block = (b, hh, vb): handles v-columns [vb*16, vb*16+16). lane = kq*16+vi.
// Lane holds S[k = kq*16 + j][v0+vi], j in [0,16).
__global__ __launch_bounds__(64)
void scan_kernel(const float* __restrict__ q, const float* __restrict__ k,
                 const float* __restrict__ v, const float* __restrict__ g,
                 const float* __restrict__ beta, float* __restrict__ o) {
  const int vb = blockIdx.x & 3;
  const int hh = (blockIdx.x >> 2) & 15;
  const int b  = blockIdx.x >> 6;
  const int lane = threadIdx.x;
  const int kq = lane >> 4;
  const int vi = lane & 15;
  const int v0 = vb*16;
  const int rb = b*Tt;

  __shared__ __attribute__((aligned(16))) float sq[2][CH][64];
  __shared__ __attribute__((aligned(16))) float sk[2][CH][64];
  __shared__ __attribute__((aligned(16))) float sg[2][CH][64];
  __shared__ __attribute__((aligned(16))) float sv[2][CH][16];
  __shared__ float sb[Tt];

  // stage beta for all 512 steps up front (8 scalar loads/lane)
  #pragma unroll
  for (int i=0;i<Tt/64;i++)
    sb[i*64+lane] = beta[(size_t)(rb + i*64 + lane)*Hh + hh];

  auto stage = [&](int t0, int pb) {
    const int srow = lane >> 4, sch4 = (lane & 15)*4;
    #pragma unroll
    for (int ii=0; ii<4; ++ii) {
      size_t gbase = (size_t)(rb + t0 + ii*4 + srow)*Pp + hh*64;
      async16(&sq[pb][ii*4][0], q + gbase + sch4);
      async16(&sk[pb][ii*4][0], k + gbase + sch4);
      async16(&sg[pb][ii*4][0], g + gbase + sch4);
    }
    size_t gv = (size_t)(rb + t0 + (lane>>2))*Pp + hh*64 + v0 + (lane&3)*4;
    async16(&sv[pb][0][0], v + gv);
  };

  float S[16];
  #pragma unroll
  for (int j=0;j<16;j++) S[j]=0.f;

  stage(0, 0);
  for (int c=0; c<NCH; ++c) {
    int pb = c & 1;
    if (c+1 < NCH) {
      stage((c+1)*CH, pb^1);
      asm volatile("s_waitcnt vmcnt(13)" ::: "memory");   // prev chunk's 13 loads done
    } else {
      asm volatile("s_waitcnt vmcnt(0)" ::: "memory");
    }
    __builtin_amdgcn_sched_barrier(0);
    #pragma unroll
    for (int i=0;i<CH;i++){
      int t = c*CH + i;
      const float4* kp = (const float4*)&sk[pb][i][kq*16];
      const float4* gp = (const float4*)&sg[pb][i][kq*16];
      const float4* qp = (const float4*)&sq[pb][i][kq*16];
      float pr0 = 0.f, pr1 = 0.f;
      #pragma unroll
      for (int jj=0;jj<4;jj++){
        float4 gg = gp[jj]; float4 kk = kp[jj];
        float s0 = S[jj*4+0]*gg.x; S[jj*4+0]=s0;
        float s1 = S[jj*4+1]*gg.y; S[jj*4+1]=s1;
        float s2 = S[jj*4+2]*gg.z; S[jj*4+2]=s2;
        float s3 = S[jj*4+3]*gg.w; S[jj*4+3]=s3;
        pr0 += kk.x*s0; pr1 += kk.y*s1; pr0 += kk.z*s2; pr1 += kk.w*s3;
      }
      float pred = pr0 + pr1;
      pred += __shfl_xor(pred, 16, 64);
      pred += __shfl_xor(pred, 32, 64);
      float upd = (sv[pb][i][vi] - pred) * sb[t];
      float a0 = 0.f, a1 = 0.f;
      #pragma unroll
      for (int jj=0;jj<4;jj++){
        float4 kk = kp[jj]; float4 qq = qp[jj];
        float s0 = S[jj*4+0]+kk.x*upd; S[jj*4+0]=s0;
        float s1 = S[jj*4+1]+kk.y*upd; S[jj*4+1]=s1;
        float s2 = S[jj*4+2]+kk.z*upd; S[jj*4+2]=s2;
        float s3 = S[jj*4+3]+kk.w*upd; S[jj*4+3]=s3;
        a0 += qq.x*s0; a1 += qq.y*s1; a0 += qq.z*s2; a1 += qq.w*s3;
      }
      float acc = a0 + a1;
      acc += __shfl_xor(acc, 16, 64);
      acc += __shfl_xor(acc, 32, 64);
      if (kq == 0) o[(size_t)(rb+t)*Pp + hh*64 + v0 + vi] = acc;
    }
  }
}

// ================= o = rms(o)*w*sigmoid(gate) -> split hi/lo bf16 =================
__global__ void onorm_gate_split_kernel(const float* __restrict__ o, const float* __restrict__ w,
                                        const float* __restrict__ gate,
                                        __hip_bfloat16* __restrict__ hi, __hip_bfloat16* __restrict__ lo) {
  int row = blockIdx.x*4 + (threadIdx.x>>6);
  int lane = threadIdx.x & 63;
  size_t idx = (size_t)row*Dd + lane;
  float v = o[idx];
  float s = v*v;
  #pragma unroll
  for (int off=32; off; off>>=1) s += __shfl_xor(s, off, 64);
  float r = v * rsqrtf(s/(float)Dd + 1e-5f) * w[lane] * sigmoidf_(gate[idx]);
  __hip_bfloat16 h = __float2bfloat16(r);
  hi[idx] = h;
  lo[idx] = __float2bfloat16(r - bf2f(h));
}

// ================= router top-2 =================
__global__ void router_kernel(const float* __restrict__ logits, const float* __restrict__ gate_b,
                              int* __restrict__ counts, int* __restrict__ tok_list,
                              int* __restrict__ slot_list, float* __restrict__ wt_list) {
  int n = blockIdx.x*256 + threadIdx.x;
  if (n >= Ntok) return;
  float sc[Ee], bi[Ee];
  #pragma unroll
  for (int e=0;e<Ee;e++){ float s = sigmoidf_(logits[n*Ee+e]); sc[e]=s; bi[e]=s+gate_b[e]; }
  int i0=0;
  #pragma unroll
  for (int e=1;e<Ee;e++) if (bi[e] > bi[i0]) i0=e;
  int i1=-1;
  #pragma unroll
  for (int e=0;e<Ee;e++){ if (e==i0) continue; if (i1<0 || bi[e] > bi[i1]) i1=e; }
  float w0=sc[i0], w1=sc[i1];
  float inv = 1.f/(w0+w1+1e-20f);
  w0*=inv; w1*=inv;
  int p0 = atomicAdd(&counts[i0],1);
  tok_list[i0*Ntok+p0]=n; slot_list[i0*Ntok+p0]=0; wt_list[i0*Ntok+p0]=w0;
  int p1 = atomicAdd(&counts[i1],1);
  tok_list[i1*Ntok+p1]=n; slot_list[i1*Ntok+p1]=1; wt_list[i1*Ntok+p1]=w1;
}

__global__ void prefix_kernel(const int* __restrict__ counts, int* __restrict__ prefix) {
  if (threadIdx.x==0 && blockIdx.x==0){ int s=0; for (int e=0;e<Ee;e++){ prefix[e]=s; s+=counts[e]; } }
}

__global__ void compact_kernel(const int* __restrict__ counts, const int* __restrict__ prefix,
                               const int* __restrict__ tok_list, const int* __restrict__ slot_list,
                               const float* __restrict__ wt_list,
                               int* __restrict__ ctok, int* __restrict__ cslot, float* __restrict__ cwt) {
  int e = blockIdx.x; int c = counts[e], p = prefix[e];
  for (int i = threadIdx.x; i < c; i += 256) {
    ctok[p+i]  = tok_list[e*Ntok+i];
    cslot[p+i] = slot_list[e*Ntok+i];
    cwt[p+i]   = wt_list[e*Ntok+i];
  }
}

__global__ void gather_kernel(const __hip_bfloat16* __restrict__ hn, const int* __restrict__ ctok,
                              __hip_bfloat16* __restrict__ Ae) {
  int r = blockIdx.x;
  int t = threadIdx.x; // 128
  ((int4*)(Ae + (size_t)r*HIDD))[t] = ((const int4*)(hn + (size_t)ctok[r]*HIDD))[t];
}

// ================= GLU: out = silu(gu[:, :768]) * gu[:, 768:] =================
__global__ void glu_kernel(const __hip_bfloat16* __restrict__ gu, __hip_bfloat16* __restrict__ outp,
                           int rows) {
  int idx = blockIdx.x*256 + threadIdx.x;
  if (idx >= rows*Ii) return;
  int r = idx / Ii, c2 = idx - r*Ii;
  float gv = bf2f(gu[(size_t)r*(2*Ii) + c2]);
  float uv = bf2f(gu[(size_t)r*(2*Ii) + Ii + c2]);
  outp[idx] = __float2bfloat16(siluf_(gv)*uv);
}

__global__ void final_kernel(const float* __restrict__ h, const __hip_bfloat16* __restrict__ routed,
                             const float* __restrict__ shr, float* __restrict__ out) {
  int idx = blockIdx.x*256 + threadIdx.x;
  if (idx >= Ntok*HIDD) return;
  int n = idx >> 10, c = idx & 1023;
  out[idx] = h[idx] + bf2f(routed[(size_t)n*2*HIDD + c]) + bf2f(routed[(size_t)n*2*HIDD + HIDD + c]) + shr[idx];
}

// ---------------------------------------------------------------------------
extern "C" void kernel_launch(void* const* d_in, const int* in_sizes, int n_in,
                              void* d_out, int out_size, void* d_ws, size_t ws_size,
                              hipStream_t stream) {
  (void)in_sizes; (void)n_in; (void)out_size; (void)ws_size;
  const float* x        = (const float*)d_in[0];
  const float* norm1_w  = (const float*)d_in[1];
  const float* wq       = (const float*)d_in[2];
  const float* wk       = (const float*)d_in[3];
  const float* wv       = (const float*)d_in[4];
  const float* cq       = (const float*)d_in[5];
  const float* ck       = (const float*)d_in[6];
  const float* cv       = (const float*)d_in[7];
  const float* fa       = (const float*)d_in[8];
  const float* fb       = (const float*)d_in[9];
  const float* bp       = (const float*)d_in[10];
  const float* ga       = (const float*)d_in[11];
  const float* gb       = (const float*)d_in[12];
  const float* A_log    = (const float*)d_in[13];
  const float* dt_bias  = (const float*)d_in[14];
  const float* onorm_w  = (const float*)d_in[15];
  const float* wo       = (const float*)d_in[16];
  const float* norm2_w  = (const float*)d_in[17];
  const float* gate_w   = (const float*)d_in[18];
  const float* gate_b   = (const float*)d_in[19];
  const float* wg_e     = (const float*)d_in[20];
  const float* wu_e     = (const float*)d_in[21];
  const float* wd_e     = (const float*)d_in[22];
  const float* wg_s     = (const float*)d_in[23];
  const float* wu_s     = (const float*)d_in[24];
  const float* wd_s     = (const float*)d_in[25];
  float* out = (float*)d_out;

  char* base = (char*)d_ws;
  size_t off = 0;
  auto alloc = [&](size_t bytes)->char* {
    off = (off + 255) & ~(size_t)255;
    char* p = base + off; off += bytes; return p;
  };
  // persistent
  float* hbuf = (float*)alloc((size_t)Ntok*HIDD*4);
  size_t uStart = (off + 255) & ~(size_t)255;

  // ---- attention view ----
  off = uStart;
  __hip_bfloat16* xn      = (__hip_bfloat16*)alloc((size_t)Ntok*HIDD*2);
  __hip_bfloat16* xn_lo   = (__hip_bfloat16*)alloc((size_t)Ntok*HIDD*2);
  __hip_bfloat16* wqkv_t  = (__hip_bfloat16*)alloc((size_t)3*Pp*HIDD*2);
  __hip_bfloat16* wqkv_lo = (__hip_bfloat16*)alloc((size_t)3*Pp*HIDD*2);
  float*          qkvlin  = (float*)alloc((size_t)Ntok*3*Pp*4);
  float*          qc      = (float*)alloc((size_t)Ntok*Pp*4);
  float*          kc      = (float*)alloc((size_t)Ntok*Pp*4);
  float*          vc      = (float*)alloc((size_t)Ntok*Pp*4);
  float*          gbuf    = (float*)alloc((size_t)Ntok*Pp*4);
  float*          gatebuf = (float*)alloc((size_t)Ntok*Pp*4);
  float*          obuf    = (float*)alloc((size_t)Ntok*Pp*4);
  __hip_bfloat16* atmp    = (__hip_bfloat16*)alloc((size_t)Ntok*Dd*2);
  __hip_bfloat16* atmp2   = (__hip_bfloat16*)alloc((size_t)Ntok*Dd*2);
  float*          betab   = (float*)alloc((size_t)Ntok*Hh*4);
  __hip_bfloat16* obuf_hi = (__hip_bfloat16*)alloc((size_t)Ntok*Pp*2);
  __hip_bfloat16* obuf_lo = (__hip_bfloat16*)alloc((size_t)Ntok*Pp*2);
  __hip_bfloat16* wo_t    = (__hip_bfloat16*)alloc((size_t)HIDD*Pp*2);
  __hip_bfloat16* wo_lo   = (__hip_bfloat16*)alloc((size_t)HIDD*Pp*2);
  __hip_bfloat16* fa_t    = (__hip_bfloat16*)alloc((size_t)Dd*HIDD*2);
  __hip_bfloat16* fb_t    = (__hip_bfloat16*)alloc((size_t)Pp*Dd*2);
  __hip_bfloat16* ga_t    = (__hip_bfloat16*)alloc((size_t)Dd*HIDD*2);
  __hip_bfloat16* gb_t    = (__hip_bfloat16*)alloc((size_t)Pp*Dd*2);

  // ---- moe view (overlaps attention view) ----
  off = uStart;
  __hip_bfloat16* hn      = (__hip_bfloat16*)alloc((size_t)Ntok*HIDD*2);
  float*          scores  = (float*)alloc((size_t)Ntok*Ee*4);
  int*            counts  = (int*)alloc(64);
  int*            prefix  = (int*)alloc(64);
  int*            tok_list  = (int*)alloc((size_t)Ee*Ntok*4);
  int*            slot_list = (int*)alloc((size_t)Ee*Ntok*4);
  float*          wt_list   = (float*)alloc((size_t)Ee*Ntok*4);
  int*            ctok    = (int*)alloc((size_t)NPAD*4);
  int*            cslot   = (int*)alloc((size_t)NPAD*4);
  float*          cwt     = (float*)alloc((size_t)NPAD*4);
  __hip_bfloat16* egu_t   = (__hip_bfloat16*)alloc((size_t)Ee*2*Ii*HIDD*2);
  __hip_bfloat16* sgu_t   = (__hip_bfloat16*)alloc((size_t)2*ISs*HIDD*2);
  __hip_bfloat16* sd_t    = (__hip_bfloat16*)alloc((size_t)HIDD*ISs*2);
  __hip_bfloat16* act     = (__hip_bfloat16*)alloc((size_t)NPAD*Ii*2);
  __hip_bfloat16* sgu_raw = (__hip_bfloat16*)alloc((size_t)Ntok*2*ISs*2);
  __hip_bfloat16* sgb     = (__hip_bfloat16*)alloc((size_t)Ntok*ISs*2);
  __hip_bfloat16* routed  = (__hip_bfloat16*)alloc((size_t)Ntok*2*HIDD*2);
  float*          shout   = (float*)alloc((size_t)Ntok*HIDD*4);
  // X region: Ae+actg, later reused by ed_t
  size_t xStart = (off + 255) & ~(size_t)255;
  off = xStart;
  __hip_bfloat16* Ae      = (__hip_bfloat16*)alloc((size_t)NPAD*HIDD*2);
  __hip_bfloat16* actg    = (__hip_bfloat16*)alloc((size_t)NPAD*2*Ii*2);
  off = xStart;
  __hip_bfloat16* ed_t    = (__hip_bfloat16*)alloc((size_t)Ee*HIDD*Ii*2);

  dim3 blk(256);
  const int nelem = Ntok*Pp;
  #define NO6 nullptr, nullptr, nullptr, nullptr, nullptr, nullptr

  // ================= attention =================
  rms_split_kernel<<<Ntok, blk, 0, stream>>>(x, norm1_w, xn, xn_lo, 1e-5f);
  // weight transposes (split for QKV and wo, plain for the rest)
  trans_split_kernel<<<dim3(32,32,1), blk, 0, stream>>>(wq, wqkv_t, wqkv_lo, HIDD, Pp);
  trans_split_kernel<<<dim3(32,32,1), blk, 0, stream>>>(wk, wqkv_t + (size_t)Pp*HIDD,
                                                        wqkv_lo + (size_t)Pp*HIDD, HIDD, Pp);
  trans_split_kernel<<<dim3(32,32,1), blk, 0, stream>>>(wv, wqkv_t + (size_t)2*Pp*HIDD,
                                                        wqkv_lo + (size_t)2*Pp*HIDD, HIDD, Pp);
  trans_split_kernel<<<dim3(32,32,1), blk, 0, stream>>>(wo, wo_t, wo_lo, Pp, HIDD);
  trans_kernel<<<dim3(2,32,1),  blk, 0, stream>>>(fa, fa_t, HIDD, Dd, 0, 0);
  trans_kernel<<<dim3(32,2,1),  blk, 0, stream>>>(fb, fb_t, Dd, Pp, 0, 0);
  trans_kernel<<<dim3(2,32,1),  blk, 0, stream>>>(ga, ga_t, HIDD, Dd, 0, 0);
  trans_kernel<<<dim3(32,2,1),  blk, 0, stream>>>(gb, gb_t, Dd, Pp, 0, 0);

  // QKV: 3-pass split-bf16 GEMM (~fp32 precision)
  gemm_k<0,0><<<dim3(48,16,1), blk, 0, stream>>>(xn,    wqkv_t,  qkvlin, Ntok, 3*Pp, HIDD, NO6);
  gemm_k<0,1><<<dim3(48,16,1), blk, 0, stream>>>(xn,    wqkv_lo, qkvlin, Ntok, 3*Pp, HIDD, NO6);
  gemm_k<0,1><<<dim3(48,16,1), blk, 0, stream>>>(xn_lo, wqkv_t,  qkvlin, Ntok, 3*Pp, HIDD, NO6);
  conv_silu_kernel<<<(nelem+255)/256, blk, 0, stream>>>(qkvlin, cq, qc, 0);
  conv_silu_kernel<<<(nelem+255)/256, blk, 0, stream>>>(qkvlin, ck, kc, Pp);
  conv_silu_kernel<<<(nelem+255)/256, blk, 0, stream>>>(qkvlin, cv, vc, 2*Pp);
  l2norm_scale_kernel<<<(Ntok*Hh)/4, blk, 0, stream>>>(qc, 1.f/64.f);
  l2norm_scale_kernel<<<(Ntok*Hh)/4, blk, 0, stream>>>(kc, 0.125f);
  gemm_k<1,0><<<dim3(1,16,1), blk, 0, stream>>>(xn, fa_t, atmp, Ntok, Dd, HIDD, NO6);
  gemm_k<0,0><<<dim3(16,16,1), blk, 0, stream>>>(atmp, fb_t, gbuf, Ntok, Pp, Dd, NO6);
  g_kernel<<<(nelem+255)/256, blk, 0, stream>>>(gbuf, A_log, dt_bias);
  beta_kernel<<<Ntok, blk, 0, stream>>>(xn, bp, betab);
  gemm_k<1,0><<<dim3(1,16,1), blk, 0, stream>>>(xn, ga_t, atmp2, Ntok, Dd, HIDD, NO6);
  gemm_k<0,0><<<dim3(16,16,1), blk, 0, stream>>>(atmp2, gb_t, gatebuf, Ntok, Pp, Dd, NO6);
  scan_kernel<<<Bb*Hh*4, dim3(64), 0, stream>>>(qc, kc, vc, gbuf, betab, obuf);
  onorm_gate_split_kernel<<<(Ntok*Hh)/4, blk, 0, stream>>>(obuf, onorm_w, gatebuf, obuf_hi, obuf_lo);
  // wo: 3-pass split-bf16 GEMM, residual added on last pass
  gemm_k<0,0><<<dim3(16,16,1), blk, 0, stream>>>(obuf_hi, wo_t,  hbuf, Ntok, HIDD, Pp, NO6);
  gemm_k<0,1><<<dim3(16,16,1), blk, 0, stream>>>(obuf_hi, wo_lo, hbuf, Ntok, HIDD, Pp, NO6);
  gemm_k<2,1><<<dim3(16,16,1), blk, 0, stream>>>(obuf_lo, wo_t,  hbuf, Ntok, HIDD, Pp,
                                                 x, nullptr, nullptr, nullptr, nullptr, nullptr);

  // ================= MoE =================
  rms_bf16_kernel<<<Ntok, blk, 0, stream>>>(hbuf, norm2_w, hn, 1e-5f);
  router_scores_kernel<<<Ntok, blk, 0, stream>>>(hbuf, norm2_w, gate_w, scores);
  hipMemsetAsync(counts, 0, Ee*sizeof(int), stream);
  router_kernel<<<(Ntok+255)/256, blk, 0, stream>>>(scores, gate_b, counts, tok_list, slot_list, wt_list);
  prefix_kernel<<<1, 64, 0, stream>>>(counts, prefix);
  compact_kernel<<<Ee, blk, 0, stream>>>(counts, prefix, tok_list, slot_list, wt_list, ctok, cslot, cwt);
  gather_kernel<<<NASSIGN, dim3(128), 0, stream>>>(hn, ctok, Ae);
  // expert up: wg (rows 0..767 of each expert's BT) and wu (rows 768..1535)
  trans_kernel<<<dim3(24,32,Ee), blk, 0, stream>>>(wg_e, egu_t,
      HIDD, Ii, (long)HIDD*Ii, (long)2*Ii*HIDD);
  trans_kernel<<<dim3(24,32,Ee), blk, 0, stream>>>(wu_e, egu_t + (size_t)Ii*HIDD,
      HIDD, Ii, (long)HIDD*Ii, (long)2*Ii*HIDD);
  gemm_k<3,0><<<dim3(24,16,Ee), blk, 0, stream>>>(Ae, egu_t, actg, Ntok, 2*Ii, HIDD,
                                                  nullptr, counts, prefix, nullptr, nullptr, nullptr);
  glu_kernel<<<(NASSIGN*Ii+255)/256, blk, 0, stream>>>(actg, act, NASSIGN);
  // now Ae/actg dead -> transpose wd into the same region
  trans_kernel<<<dim3(32,24,Ee), blk, 0, stream>>>(wd_e, ed_t,
      Ii, HIDD, (long)Ii*HIDD, (long)HIDD*Ii);
  gemm_k<4,0><<<dim3(16,16,Ee), blk, 0, stream>>>(act, ed_t, routed, Ntok, HIDD, Ii,
                                                  nullptr, counts, prefix, ctok, cslot, cwt);
  // shared expert
  trans_kernel<<<dim3(24,32,1), blk, 0, stream>>>(wg_s, sgu_t, HIDD, ISs, 0, 0);
  trans_kernel<<<dim3(24,32,1), blk, 0, stream>>>(wu_s, sgu_t + (size_t)ISs*HIDD, HIDD, ISs, 0, 0);
  trans_kernel<<<dim3(32,24,1), blk, 0, stream>>>(wd_s, sd_t, ISs, HIDD, 0, 0);
  gemm_k<1,0><<<dim3(24,16,1), blk, 0, stream>>>(hn, sgu_t, sgu_raw, Ntok, 2*ISs, HIDD, NO6);
  glu_kernel<<<(Ntok*ISs+255)/256, blk, 0, stream>>>(sgu_raw, sgb, Ntok);
  gemm_k<0,0><<<dim3(16,16,1), blk, 0, stream>>>(sgb, sd_t, shout, Ntok, HIDD, ISs, NO6);

  final_kernel<<<(Ntok*HIDD+255)/256, blk, 0, stream>>>(hbuf, routed, shout, out);
}

// Round 5
// 429.013 us; speedup vs baseline: 8.1824x; 1.1396x over previous
//
#include <hip/hip_runtime.h>
#include <hip/hip_bf16.h>
#include <math.h>

#define Bb 2
#define Tt 512
#define HIDD 1024
#define Hh 16
#define Dd 64
#define Pp 1024
#define Kc 4
#define Ee 8
#define Ii 768
#define ISs 768
#define Ntok (Bb*Tt)   // 1024
#define NASSIGN (2*Ntok) // 2048 routed assignments
#define NPAD 2112
#define CH 16
#define NCH (Tt/CH)

typedef __attribute__((ext_vector_type(8))) short bf16x8;
typedef __attribute__((ext_vector_type(4))) float floatx4;

__device__ __forceinline__ float sigmoidf_(float x){ return 1.f/(1.f+expf(-x)); }
__device__ __forceinline__ float siluf_(float x){ return x/(1.f+expf(-x)); }
__device__ __forceinline__ float bf2f(__hip_bfloat16 b){ return __bfloat162float(b); }

__device__ __forceinline__ void async16(void* lds, const void* g) {
  __builtin_amdgcn_global_load_lds(
      (const __attribute__((address_space(1))) void*)g,
      (__attribute__((address_space(3))) void*)lds, 16, 0, 0);
}

// quad-perm DPP add: x + x[lane ^ (1 or 2)] (VALU pipe, no LDS)
template<int CTRL>
__device__ __forceinline__ float dpp_add(float x){
  int y = __builtin_amdgcn_update_dpp(0, __float_as_int(x), CTRL, 0xF, 0xF, true);
  return x + __int_as_float(y);
}
// xor1 = quad_perm[1,0,3,2] = 0xB1 ; xor2 = quad_perm[2,3,0,1] = 0x4E

// ================= RMS norm (fp32 in, bf16 out) =================
__global__ void rms_bf16_kernel(const float* __restrict__ x, const float* __restrict__ w,
                                __hip_bfloat16* __restrict__ out, float eps) {
  int row = blockIdx.x;
  const float* xr = x + (size_t)row*HIDD;
  float s = 0.f;
  for (int i = threadIdx.x; i < HIDD; i += 256){ float v = xr[i]; s += v*v; }
  #pragma unroll
  for (int off=32; off; off>>=1) s += __shfl_down(s, off, 64);
  __shared__ float red[4];
  if ((threadIdx.x & 63)==0) red[threadIdx.x>>6] = s;
  __syncthreads();
  float tot = red[0]+red[1]+red[2]+red[3];
  float sc = rsqrtf(tot/(float)HIDD + eps);
  for (int i = threadIdx.x; i < HIDD; i += 256)
    out[(size_t)row*HIDD+i] = __float2bfloat16(xr[i]*sc*w[i]);
}

// ================= RMS norm (fp32 in, split hi/lo bf16 out) =================
__global__ void rms_split_kernel(const float* __restrict__ x, const float* __restrict__ w,
                                 __hip_bfloat16* __restrict__ hi, __hip_bfloat16* __restrict__ lo,
                                 float eps) {
  int row = blockIdx.x;
  const float* xr = x + (size_t)row*HIDD;
  float s = 0.f;
  for (int i = threadIdx.x; i < HIDD; i += 256){ float v = xr[i]; s += v*v; }
  #pragma unroll
  for (int off=32; off; off>>=1) s += __shfl_down(s, off, 64);
  __shared__ float red[4];
  if ((threadIdx.x & 63)==0) red[threadIdx.x>>6] = s;
  __syncthreads();
  float tot = red[0]+red[1]+red[2]+red[3];
  float sc = rsqrtf(tot/(float)HIDD + eps);
  for (int i = threadIdx.x; i < HIDD; i += 256) {
    float v = xr[i]*sc*w[i];
    __hip_bfloat16 h = __float2bfloat16(v);
    hi[(size_t)row*HIDD+i] = h;
    lo[(size_t)row*HIDD+i] = __float2bfloat16(v - bf2f(h));
  }
}

// ================= transpose + f32->bf16: src[K][N] -> dst[N][K] =================
__global__ void trans_kernel(const float* __restrict__ src, __hip_bfloat16* __restrict__ dst,
                             int K, int N, long sbs, long dbs) {
  src += (size_t)blockIdx.z * sbs; dst += (size_t)blockIdx.z * dbs;
  __shared__ float tile[32][33];
  int n0 = blockIdx.x*32, k0 = blockIdx.y*32;
  int tx = threadIdx.x & 31, ty0 = threadIdx.x >> 5;
  #pragma unroll
  for (int j=0;j<4;j++){ int ty = ty0 + j*8; tile[ty][tx] = src[(size_t)(k0+ty)*N + n0+tx]; }
  __syncthreads();
  #pragma unroll
  for (int j=0;j<4;j++){ int ty = ty0 + j*8; dst[(size_t)(n0+ty)*K + k0+tx] = __float2bfloat16(tile[tx][ty]); }
}

// ================= transpose + split hi/lo: src[K][N] -> hi/lo[N][K] =================
__global__ void trans_split_kernel(const float* __restrict__ src, __hip_bfloat16* __restrict__ hi,
                                   __hip_bfloat16* __restrict__ lo, int K, int N) {
  __shared__ float tile[32][33];
  int n0 = blockIdx.x*32, k0 = blockIdx.y*32;
  int tx = threadIdx.x & 31, ty0 = threadIdx.x >> 5;
  #pragma unroll
  for (int j=0;j<4;j++){ int ty = ty0 + j*8; tile[ty][tx] = src[(size_t)(k0+ty)*N + n0+tx]; }
  __syncthreads();
  #pragma unroll
  for (int j=0;j<4;j++){
    int ty = ty0 + j*8;
    float v = tile[tx][ty];
    __hip_bfloat16 h = __float2bfloat16(v);
    hi[(size_t)(n0+ty)*K + k0+tx] = h;
    lo[(size_t)(n0+ty)*K + k0+tx] = __float2bfloat16(v - bf2f(h));
  }
}

// ================= MFMA GEMM core =================
__device__ __forceinline__ int lds_off(int row, int slot){
  return row*128 + (((slot ^ row)&7)<<4);
}

// MODE 0: f32 out. 1: bf16 out. 2: f32 out + resid. 3: expert compact bf16 out.
// 4: expert scatter f32->bf16 routed out with per-row weight.
template<int MODE, int ACC>
__global__ __launch_bounds__(256)
void gemm_k(const __hip_bfloat16* __restrict__ A, const __hip_bfloat16* __restrict__ BT,
            void* __restrict__ C, int M, int N, int K, int lda, const float* __restrict__ resid,
            const int* __restrict__ counts, const int* __restrict__ prefix,
            const int* __restrict__ ctok, const int* __restrict__ cslot,
            const float* __restrict__ cwt) {
  int Me = M;
  int moff = 0;
  if (MODE >= 3) {
    int e = blockIdx.z;
    Me = counts[e]; moff = prefix[e];
    A  += (size_t)moff * lda;
    BT += (size_t)e * (size_t)N * K;
  }
  int row0 = blockIdx.y * 64;
  if (row0 >= Me) return;
  int col0 = blockIdx.x * 64;

  __shared__ __attribute__((aligned(16))) short As[64*64];
  __shared__ __attribute__((aligned(16))) short Bs[64*64];
  const int lane = threadIdx.x & 63;
  const int w    = threadIdx.x >> 6;
  const int wr = w >> 1, wc = w & 1;
  const int srow = lane >> 3;
  const int sch  = (lane & 7) ^ (srow & 7);
  const int q = lane >> 4, r16 = lane & 15;

  const __hip_bfloat16* Ag = A  + (size_t)row0 * lda;
  const __hip_bfloat16* Bg = BT + (size_t)col0 * K;

  floatx4 acc[2][2] = {};

  for (int k0 = 0; k0 < K; k0 += 64) {
    #pragma unroll
    for (int ii = 0; ii < 2; ++ii) {
      const int inst = w + ii*4;
      const int r = inst*8 + srow;
      async16((char*)As + inst*1024, Ag + (size_t)r*lda + (size_t)(k0 + sch*8));
      async16((char*)Bs + inst*1024, Bg + (size_t)r*K   + (size_t)(k0 + sch*8));
    }
    __syncthreads();
    #pragma unroll
    for (int kk = 0; kk < 2; ++kk) {
      int slot = kk*4 + q;
      bf16x8 a0 = *(const bf16x8*)((const char*)As + lds_off(wr*32 +      r16, slot));
      bf16x8 a1 = *(const bf16x8*)((const char*)As + lds_off(wr*32 + 16 + r16, slot));
      bf16x8 b0 = *(const bf16x8*)((const char*)Bs + lds_off(wc*32 +      r16, slot));
      bf16x8 b1 = *(const bf16x8*)((const char*)Bs + lds_off(wc*32 + 16 + r16, slot));
      acc[0][0] = __builtin_amdgcn_mfma_f32_16x16x32_bf16(a0, b0, acc[0][0], 0, 0, 0);
      acc[0][1] = __builtin_amdgcn_mfma_f32_16x16x32_bf16(a0, b1, acc[0][1], 0, 0, 0);
      acc[1][0] = __builtin_amdgcn_mfma_f32_16x16x32_bf16(a1, b0, acc[1][0], 0, 0, 0);
      acc[1][1] = __builtin_amdgcn_mfma_f32_16x16x32_bf16(a1, b1, acc[1][1], 0, 0, 0);
    }
    __syncthreads();
  }

  #pragma unroll
  for (int mi = 0; mi < 2; ++mi) {
    #pragma unroll
    for (int r = 0; r < 4; ++r) {
      int grow = row0 + wr*32 + mi*16 + q*4 + r;
      if (grow >= Me) continue;
      #pragma unroll
      for (int ni = 0; ni < 2; ++ni) {
        int gcol = col0 + wc*32 + ni*16 + r16;
        float v = acc[mi][ni][r];
        if (MODE == 0) {
          float* Cp = (float*)C + (size_t)grow*N + gcol;
          if (ACC) v += *Cp;
          *Cp = v;
        } else if (MODE == 2) {
          float* Cp = (float*)C + (size_t)grow*N + gcol;
          if (ACC) v += *Cp;
          *Cp = v + resid[(size_t)grow*N + gcol];
        } else if (MODE == 1) {
          ((__hip_bfloat16*)C)[(size_t)grow*N + gcol] = __float2bfloat16(v);
        } else if (MODE == 3) {
          ((__hip_bfloat16*)C)[(size_t)(moff+grow)*N + gcol] = __float2bfloat16(v);
        } else { // 4
          int rc = moff + grow;
          int tok = ctok[rc], sl = cslot[rc];
          ((__hip_bfloat16*)C)[((size_t)tok*2 + sl)*N + gcol] = __float2bfloat16(cwt[rc]*v);
        }
      }
    }
  }
}

// 3-phase split-bf16 GEMM in one dispatch: C = Ahi·Bhi + Ahi·Blo + Alo·Bhi [+resid]
template<int MODE>  // 0: f32 out, 2: f32 out + resid
__global__ __launch_bounds__(256)
void gemm3_k(const __hip_bfloat16* __restrict__ Ahi, const __hip_bfloat16* __restrict__ Alo,
             const __hip_bfloat16* __restrict__ Bhi, const __hip_bfloat16* __restrict__ Blo,
             float* __restrict__ C, int M, int N, int K, const float* __restrict__ resid) {
  int row0 = blockIdx.y * 64;
  int col0 = blockIdx.x * 64;

  __shared__ __attribute__((aligned(16))) short As[64*64];
  __shared__ __attribute__((aligned(16))) short Bs[64*64];
  const int lane = threadIdx.x & 63;
  const int w    = threadIdx.x >> 6;
  const int wr = w >> 1, wc = w & 1;
  const int srow = lane >> 3;
  const int sch  = (lane & 7) ^ (srow & 7);
  const int q = lane >> 4, r16 = lane & 15;

  floatx4 acc[2][2] = {};

  for (int p = 0; p < 3; ++p) {
    const __hip_bfloat16* Ag = ((p==2)? Alo : Ahi) + (size_t)row0 * K;
    const __hip_bfloat16* Bg = ((p==1)? Blo : Bhi) + (size_t)col0 * K;
    for (int k0 = 0; k0 < K; k0 += 64) {
      #pragma unroll
      for (int ii = 0; ii < 2; ++ii) {
        const int inst = w + ii*4;
        const int r = inst*8 + srow;
        async16((char*)As + inst*1024, Ag + (size_t)r*K + (size_t)(k0 + sch*8));
        async16((char*)Bs + inst*1024, Bg + (size_t)r*K + (size_t)(k0 + sch*8));
      }
      __syncthreads();
      #pragma unroll
      for (int kk = 0; kk < 2; ++kk) {
        int slot = kk*4 + q;
        bf16x8 a0 = *(const bf16x8*)((const char*)As + lds_off(wr*32 +      r16, slot));
        bf16x8 a1 = *(const bf16x8*)((const char*)As + lds_off(wr*32 + 16 + r16, slot));
        bf16x8 b0 = *(const bf16x8*)((const char*)Bs + lds_off(wc*32 +      r16, slot));
        bf16x8 b1 = *(const bf16x8*)((const char*)Bs + lds_off(wc*32 + 16 + r16, slot));
        acc[0][0] = __builtin_amdgcn_mfma_f32_16x16x32_bf16(a0, b0, acc[0][0], 0, 0, 0);
        acc[0][1] = __builtin_amdgcn_mfma_f32_16x16x32_bf16(a0, b1, acc[0][1], 0, 0, 0);
        acc[1][0] = __builtin_amdgcn_mfma_f32_16x16x32_bf16(a1, b0, acc[1][0], 0, 0, 0);
        acc[1][1] = __builtin_amdgcn_mfma_f32_16x16x32_bf16(a1, b1, acc[1][1], 0, 0, 0);
      }
      __syncthreads();
    }
  }

  #pragma unroll
  for (int mi = 0; mi < 2; ++mi) {
    #pragma unroll
    for (int r = 0; r < 4; ++r) {
      int grow = row0 + wr*32 + mi*16 + q*4 + r;
      #pragma unroll
      for (int ni = 0; ni < 2; ++ni) {
        int gcol = col0 + wc*32 + ni*16 + r16;
        float v = acc[mi][ni][r];
        if (MODE == 2) v += resid[(size_t)grow*N + gcol];
        C[(size_t)grow*N + gcol] = v;
      }
    }
  }
}

// ================= fused causal dwconv(K=4) + SiLU + (L2 norm for q/k) =================
// grid (Ntok, 3): z=0 q (scale 1/64 after l2norm), z=1 k (0.125), z=2 v (no norm)
__global__ void conv_norm_kernel(const float* __restrict__ in,
                                 const float* __restrict__ cq, const float* __restrict__ ck,
                                 const float* __restrict__ cv,
                                 float* __restrict__ qc, float* __restrict__ kc,
                                 float* __restrict__ vc) {
  int tok = blockIdx.x;
  int mode = blockIdx.y;
  const float* w = (mode==0) ? cq : (mode==1) ? ck : cv;
  float* outp    = (mode==0) ? qc : (mode==1) ? kc : vc;
  int colOff = mode << 10;
  int t = threadIdx.x;
  int c0 = t*4;
  int tloc = tok & (Tt-1);

  float wv[4][4];
  #pragma unroll
  for (int i=0;i<4;i++){
    float4 w4 = ((const float4*)w)[c0+i];
    wv[i][0]=w4.x; wv[i][1]=w4.y; wv[i][2]=w4.z; wv[i][3]=w4.w;
  }
  float acc[4] = {0.f,0.f,0.f,0.f};
  #pragma unroll
  for (int j=0;j<Kc;j++){
    int tt = tloc - (Kc-1) + j;
    if (tt >= 0){
      float4 xv = *(const float4*)&in[(size_t)(tok-(Kc-1)+j)*3072 + colOff + c0];
      acc[0] += wv[0][j]*xv.x;
      acc[1] += wv[1][j]*xv.y;
      acc[2] += wv[2][j]*xv.z;
      acc[3] += wv[3][j]*xv.w;
    }
  }
  float val[4];
  #pragma unroll
  for (int i=0;i<4;i++) val[i] = siluf_(acc[i]);
  float scale = 1.f;
  if (mode < 2) {
    float ss = val[0]*val[0]+val[1]*val[1]+val[2]*val[2]+val[3]*val[3];
    // head = 64 channels = 16 consecutive lanes
    ss += __shfl_xor(ss, 1, 64);
    ss += __shfl_xor(ss, 2, 64);
    ss += __shfl_xor(ss, 4, 64);
    ss += __shfl_xor(ss, 8, 64);
    scale = rsqrtf(ss/(float)Dd + 1e-6f) * ((mode==0) ? (1.f/64.f) : 0.125f);
  }
  float4 o4 = make_float4(val[0]*scale, val[1]*scale, val[2]*scale, val[3]*scale);
  *(float4*)&outp[(size_t)tok*Pp + c0] = o4;
}

// ================= g = exp(-exp(A_log)*softplus(a + dt_bias)) =================
__global__ void g_kernel(float* __restrict__ a, const float* __restrict__ A_log,
                         const float* __restrict__ dt_bias) {
  int idx = blockIdx.x*256 + threadIdx.x;
  if (idx >= Ntok*Pp) return;
  int d = idx & 63;
  int hh = (idx >> 6) & 15;
  float v = a[idx] + dt_bias[hh*Dd + d];
  float sp = (v > 20.f) ? v : log1pf(expf(v));
  a[idx] = expf(-expf(A_log[hh]) * sp);
}

// ================= beta = sigmoid(xn @ bp), N=16 =================
__global__ void beta_kernel(const __hip_bfloat16* __restrict__ xn, const float* __restrict__ bp,
                            float* __restrict__ betab) {
  int row = blockIdx.x;
  int t = threadIdx.x;
  int n = t & 15, ch = t >> 4;
  float s = 0.f;
  for (int k = ch*64; k < ch*64+64; ++k)
    s += bf2f(xn[(size_t)row*HIDD + k]) * bp[k*16 + n];
  __shared__ float red[256];
  red[t] = s; __syncthreads();
  if (t < 16) {
    float tot = 0.f;
    #pragma unroll
    for (int c2 = 0; c2 < 16; ++c2) tot += red[c2*16 + t];
    betab[(size_t)row*16 + t] = sigmoidf_(tot);
  }
}

// ================= router logits fp32 from hbuf (fused rms) =================
__global__ void router_scores_kernel(const float* __restrict__ h, const float* __restrict__ w2,
                                     const float* __restrict__ gw, float* __restrict__ scores) {
  int row = blockIdx.x;
  const float* hr = h + (size_t)row*HIDD;
  float s = 0.f;
  for (int i = threadIdx.x; i < HIDD; i += 256){ float v = hr[i]; s += v*v; }
  #pragma unroll
  for (int off=32; off; off>>=1) s += __shfl_down(s, off, 64);
  __shared__ float red[4];
  if ((threadIdx.x & 63)==0) red[threadIdx.x>>6] = s;
  __syncthreads();
  float sc = rsqrtf((red[0]+red[1]+red[2]+red[3])/(float)HIDD + 1e-5f);
  float acc[Ee] = {};
  for (int i = threadIdx.x; i < HIDD; i += 256){
    float xv = hr[i]*sc*w2[i];
    #pragma unroll
    for (int e=0;e<Ee;e++) acc[e] += xv*gw[i*Ee+e];
  }
  #pragma unroll
  for (int e=0;e<Ee;e++){
    #pragma unroll
    for (int off=32; off; off>>=1) acc[e] += __shfl_down(acc[e], off, 64);
  }
  __shared__ float red2[4][Ee];
  if ((threadIdx.x & 63)==0){
    #pragma unroll
    for (int e=0;e<Ee;e++) red2[threadIdx.x>>6][e] = acc[e];
  }
  __syncthreads();
  if (threadIdx.x < Ee)
    scores[(size_t)row*Ee + threadIdx.x] =
      red2[0][threadIdx.x]+red2[1][threadIdx.x]+red2[2][threadIdx.x]+red2[3][threadIdx.x];
}

// ================= delta-rule scan v3: DPP quad reductions =================
// block = (b, hh, vb). lane = vi*4 + kq: kq in [0,4) (k-slice), vi in [0,16) (v-col).
__global__ __launch_bounds__(64)
void scan_kernel(const float* __restrict__ q, const float* __restrict__ k,
                 const float* __restrict__ v, const float* __restrict__ g,
                 const float* __restrict__ beta, float* __restrict__ o) {
  const int vb = blockIdx.x & 3;
  const int hh = (blockIdx.x >> 2) & 15;
  const int b  = blockIdx.x >> 6;
  const int lane = threadIdx.x;
  const int kq = lane & 3;
  const int vi = lane >> 2;
  const int v0 = vb*16;
  const int rb = b*Tt;

  __shared__ __attribute__((aligned(16))) float sq[2][CH][64];
  __shared__ __attribute__((aligned(16))) float sk[2][CH][64];
  __shared__ __attribute__((aligned(16))) float sg[2][CH][64];
  __shared__ __attribute__((aligned(16))) float sv[2][CH][16];
  __shared__ float sb[Tt];

  #pragma unroll
  for (int i=0;i<Tt/64;i++)
    sb[i*64+lane] = beta[(size_t)(rb + i*64 + lane)*Hh + hh];

  auto stage = [&](int t0, int pb) {
    const int srow = lane >> 4, sch4 = (lane & 15)*4;
    #pragma unroll
    for (int ii=0; ii<4; ++ii) {
      size_t gbase = (size_t)(rb + t0 + ii*4 + srow)*Pp + hh*64;
      async16(&sq[pb][ii*4][0], q + gbase + sch4);
      async16(&sk[pb][ii*4][0], k + gbase + sch4);
      async16(&sg[pb][ii*4][0], g + gbase + sch4);
    }
    size_t gv = (size_t)(rb + t0 + (lane>>2))*Pp + hh*64 + v0 + (lane&3)*4;
    async16(&sv[pb][0][0], v + gv);
  };

  float S[16];
  #pragma unroll
  for (int j=0;j<16;j++) S[j]=0.f;

  stage(0, 0);
  for (int c=0; c<NCH; ++c) {
    int pb = c & 1;
    if (c+1 < NCH) {
      stage((c+1)*CH, pb^1);
      asm volatile("s_waitcnt vmcnt(13)" ::: "memory");
    } else {
      asm volatile("s_waitcnt vmcnt(0)" ::: "memory");
    }
    __builtin_amdgcn_sched_barrier(0);
    #pragma unroll
    for (int i=0;i<CH;i++){
      int t = c*CH + i;
      const float4* kp = (const float4*)&sk[pb][i][kq*16];
      const float4* gp = (const float4*)&sg[pb][i][kq*16];
      const float4* qp = (const float4*)&sq[pb][i][kq*16];
      float pr0=0.f, pr1=0.f, pr2=0.f, pr3=0.f;
      #pragma unroll
      for (int jj=0;jj<4;jj++){
        float4 gg = gp[jj]; float4 kk = kp[jj];
        float s0 = S[jj*4+0]*gg.x; S[jj*4+0]=s0; pr0 += kk.x*s0;
        float s1 = S[jj*4+1]*gg.y; S[jj*4+1]=s1; pr1 += kk.y*s1;
        float s2 = S[jj*4+2]*gg.z; S[jj*4+2]=s2; pr2 += kk.z*s2;
        float s3 = S[jj*4+3]*gg.w; S[jj*4+3]=s3; pr3 += kk.w*s3;
      }
      float pred = (pr0+pr1)+(pr2+pr3);
      pred = dpp_add<0xB1>(pred);      // + lane^1
      pred = dpp_add<0x4E>(pred);      // + lane^2  -> full 64-k sum in all quad lanes
      float upd = (sv[pb][i][vi] - pred) * sb[t];
      float a0=0.f, a1=0.f, a2=0.f, a3=0.f;
      #pragma unroll
      for (int jj=0;jj<4;jj++){
        float4 kk = kp[jj]; float4 qq = qp[jj];
        float s0 = S[jj*4+0]+kk.x*upd; S[jj*4+0]=s0; a0 += qq.x*s0;
        float s1 = S[jj*4+1]+kk.y*upd; S[jj*4+1]=s1; a1 += qq.y*s1;
        float s2 = S[jj*4+2]+kk.z*upd; S[jj*4+2]=s2; a2 += qq.z*s2;
        float s3 = S[jj*4+3]+kk.w*upd; S[jj*4+3]=s3; a3 += qq.w*s3;
      }
      float acc = (a0+a1)+(a2+a3);
      acc = dpp_add<0xB1>(acc);
      acc = dpp_add<0x4E>(acc);
      if (kq == 0) o[(size_t)(rb+t)*Pp + hh*64 + v0 + vi] = acc;
    }
  }
}

// ================= o = rms(o)*w*sigmoid(gate) -> split hi/lo bf16 =================
__global__ void onorm_gate_split_kernel(const float* __restrict__ o, const float* __restrict__ w,
                                        const float* __restrict__ gate,
                                        __hip_bfloat16* __restrict__ hi, __hip_bfloat16* __restrict__ lo) {
  int row = blockIdx.x*4 + (threadIdx.x>>6);
  int lane = threadIdx.x & 63;
  size_t idx = (size_t)row*Dd + lane;
  float v = o[idx];
  float s = v*v;
  #pragma unroll
  for (int off=32; off; off>>=1) s += __shfl_xor(s, off, 64);
  float r = v * rsqrtf(s/(float)Dd + 1e-5f) * w[lane] * sigmoidf_(gate[idx]);
  __hip_bfloat16 h = __float2bfloat16(r);
  hi[idx] = h;
  lo[idx] = __float2bfloat16(r - bf2f(h));
}

// ================= router top-2 =================
__global__ void router_kernel(const float* __restrict__ logits, const float* __restrict__ gate_b,
                              int* __restrict__ counts, int* __restrict__ tok_list,
                              int* __restrict__ slot_list, float* __restrict__ wt_list) {
  int n = blockIdx.x*256 + threadIdx.x;
  if (n >= Ntok) return;
  float sc[Ee], bi[Ee];
  #pragma unroll
  for (int e=0;e<Ee;e++){ float s = sigmoidf_(logits[n*Ee+e]); sc[e]=s; bi[e]=s+gate_b[e]; }
  int i0=0;
  #pragma unroll
  for (int e=1;e<Ee;e++) if (bi[e] > bi[i0]) i0=e;
  int i1=-1;
  #pragma unroll
  for (int e=0;e<Ee;e++){ if (e==i0) continue; if (i1<0 || bi[e] > bi[i1]) i1=e; }
  float w0=sc[i0], w1=sc[i1];
  float inv = 1.f/(w0+w1+1e-20f);
  w0*=inv; w1*=inv;
  int p0 = atomicAdd(&counts[i0],1);
  tok_list[i0*Ntok+p0]=n; slot_list[i0*Ntok+p0]=0; wt_list[i0*Ntok+p0]=w0;
  int p1 = atomicAdd(&counts[i1],1);
  tok_list[i1*Ntok+p1]=n; slot_list[i1*Ntok+p1]=1; wt_list[i1*Ntok+p1]=w1;
}

__global__ void prefix_kernel(const int* __restrict__ counts, int* __restrict__ prefix) {
  if (threadIdx.x==0 && blockIdx.x==0){ int s=0; for (int e=0;e<Ee;e++){ prefix[e]=s; s+=counts[e]; } }
}

__global__ void compact_kernel(const int* __restrict__ counts, const int* __restrict__ prefix,
                               const int* __restrict__ tok_list, const int* __restrict__ slot_list,
                               const float* __restrict__ wt_list,
                               int* __restrict__ ctok, int* __restrict__ cslot, float* __restrict__ cwt) {
  int e = blockIdx.x; int c = counts[e], p = prefix[e];
  for (int i = threadIdx.x; i < c; i += 256) {
    ctok[p+i]  = tok_list[e*Ntok+i];
    cslot[p+i] = slot_list[e*Ntok+i];
    cwt[p+i]   = wt_list[e*Ntok+i];
  }
}

__global__ void gather_kernel(const __hip_bfloat16* __restrict__ hn, const int* __restrict__ ctok,
                              __hip_bfloat16* __restrict__ Ae) {
  int r = blockIdx.x;
  int t = threadIdx.x; // 128
  ((int4*)(Ae + (size_t)r*HIDD))[t] = ((const int4*)(hn + (size_t)ctok[r]*HIDD))[t];
}

// ================= GLU: out = silu(gu[:, :768]) * gu[:, 768:] =================
__global__ void glu_kernel(const __hip_bfloat16* __restrict__ gu, __hip_bfloat16* __restrict__ outp,
                           int rows) {
  int idx = blockIdx.x*256 + threadIdx.x;
  if (idx >= rows*Ii) return;
  int r = idx / Ii, c2 = idx - r*Ii;
  float gv = bf2f(gu[(size_t)r*(2*Ii) + c2]);
  float uv = bf2f(gu[(size_t)r*(2*Ii) + Ii + c2]);
  outp[idx] = __float2bfloat16(siluf_(gv)*uv);
}

__global__ void final_kernel(const float* __restrict__ h, const __hip_bfloat16* __restrict__ routed,
                             const float* __restrict__ shr, float* __restrict__ out) {
  int idx = blockIdx.x*256 + threadIdx.x;
  if (idx >= Ntok*HIDD) return;
  int n = idx >> 10, c = idx & 1023;
  out[idx] = h[idx] + bf2f(routed[(size_t)n*2*HIDD + c]) + bf2f(routed[(size_t)n*2*HIDD + HIDD + c]) + shr[idx];
}

// ---------------------------------------------------------------------------
extern "C" void kernel_launch(void* const* d_in, const int* in_sizes, int n_in,
                              void* d_out, int out_size, void* d_ws, size_t ws_size,
                              hipStream_t stream) {
  (void)in_sizes; (void)n_in; (void)out_size; (void)ws_size;
  const float* x        = (const float*)d_in[0];
  const float* norm1_w  = (const float*)d_in[1];
  const float* wq       = (const float*)d_in[2];
  const float* wk       = (const float*)d_in[3];
  const float* wv       = (const float*)d_in[4];
  const float* cq       = (const float*)d_in[5];
  const float* ck       = (const float*)d_in[6];
  const float* cv       = (const float*)d_in[7];
  const float* fa       = (const float*)d_in[8];
  const float* fb       = (const float*)d_in[9];
  const float* bp       = (const float*)d_in[10];
  const float* ga       = (const float*)d_in[11];
  const float* gb       = (const float*)d_in[12];
  const float* A_log    = (const float*)d_in[13];
  const float* dt_bias  = (const float*)d_in[14];
  const float* onorm_w  = (const float*)d_in[15];
  const float* wo       = (const float*)d_in[16];
  const float* norm2_w  = (const float*)d_in[17];
  const float* gate_w   = (const float*)d_in[18];
  const float* gate_b   = (const float*)d_in[19];
  const float* wg_e     = (const float*)d_in[20];
  const float* wu_e     = (const float*)d_in[21];
  const float* wd_e     = (const float*)d_in[22];
  const float* wg_s     = (const float*)d_in[23];
  const float* wu_s     = (const float*)d_in[24];
  const float* wd_s     = (const float*)d_in[25];
  float* out = (float*)d_out;

  char* base = (char*)d_ws;
  size_t off = 0;
  auto alloc = [&](size_t bytes)->char* {
    off = (off + 255) & ~(size_t)255;
    char* p = base + off; off += bytes; return p;
  };
  float* hbuf = (float*)alloc((size_t)Ntok*HIDD*4);
  size_t uStart = (off + 255) & ~(size_t)255;

  // ---- attention view ----
  off = uStart;
  __hip_bfloat16* xn      = (__hip_bfloat16*)alloc((size_t)Ntok*HIDD*2);
  __hip_bfloat16* xn_lo   = (__hip_bfloat16*)alloc((size_t)Ntok*HIDD*2);
  __hip_bfloat16* wqkv_t  = (__hip_bfloat16*)alloc((size_t)3*Pp*HIDD*2);
  __hip_bfloat16* wqkv_lo = (__hip_bfloat16*)alloc((size_t)3*Pp*HIDD*2);
  float*          qkvlin  = (float*)alloc((size_t)Ntok*3*Pp*4);
  float*          qc      = (float*)alloc((size_t)Ntok*Pp*4);
  float*          kc      = (float*)alloc((size_t)Ntok*Pp*4);
  float*          vc      = (float*)alloc((size_t)Ntok*Pp*4);
  float*          gbuf    = (float*)alloc((size_t)Ntok*Pp*4);
  float*          gatebuf = (float*)alloc((size_t)Ntok*Pp*4);
  float*          obuf    = (float*)alloc((size_t)Ntok*Pp*4);
  __hip_bfloat16* atmp12  = (__hip_bfloat16*)alloc((size_t)Ntok*2*Dd*2);
  float*          betab   = (float*)alloc((size_t)Ntok*Hh*4);
  __hip_bfloat16* obuf_hi = (__hip_bfloat16*)alloc((size_t)Ntok*Pp*2);
  __hip_bfloat16* obuf_lo = (__hip_bfloat16*)alloc((size_t)Ntok*Pp*2);
  __hip_bfloat16* wo_t    = (__hip_bfloat16*)alloc((size_t)HIDD*Pp*2);
  __hip_bfloat16* wo_lo   = (__hip_bfloat16*)alloc((size_t)HIDD*Pp*2);
  __hip_bfloat16* fg_t    = (__hip_bfloat16*)alloc((size_t)2*Dd*HIDD*2);
  __hip_bfloat16* fb_t    = (__hip_bfloat16*)alloc((size_t)Pp*Dd*2);
  __hip_bfloat16* gb_t    = (__hip_bfloat16*)alloc((size_t)Pp*Dd*2);

  // ---- moe view (overlaps attention view) ----
  off = uStart;
  __hip_bfloat16* hn      = (__hip_bfloat16*)alloc((size_t)Ntok*HIDD*2);
  float*          scores  = (float*)alloc((size_t)Ntok*Ee*4);
  int*            counts  = (int*)alloc(64);
  int*            prefix  = (int*)alloc(64);
  int*            tok_list  = (int*)alloc((size_t)Ee*Ntok*4);
  int*            slot_list = (int*)alloc((size_t)Ee*Ntok*4);
  float*          wt_list   = (float*)alloc((size_t)Ee*Ntok*4);
  int*            ctok    = (int*)alloc((size_t)NPAD*4);
  int*            cslot   = (int*)alloc((size_t)NPAD*4);
  float*          cwt     = (float*)alloc((size_t)NPAD*4);
  __hip_bfloat16* egu_t   = (__hip_bfloat16*)alloc((size_t)Ee*2*Ii*HIDD*2);
  __hip_bfloat16* sgu_t   = (__hip_bfloat16*)alloc((size_t)2*ISs*HIDD*2);
  __hip_bfloat16* sd_t    = (__hip_bfloat16*)alloc((size_t)HIDD*ISs*2);
  __hip_bfloat16* act     = (__hip_bfloat16*)alloc((size_t)NPAD*Ii*2);
  __hip_bfloat16* sgu_raw = (__hip_bfloat16*)alloc((size_t)Ntok*2*ISs*2);
  __hip_bfloat16* sgb     = (__hip_bfloat16*)alloc((size_t)Ntok*ISs*2);
  __hip_bfloat16* routed  = (__hip_bfloat16*)alloc((size_t)Ntok*2*HIDD*2);
  float*          shout   = (float*)alloc((size_t)Ntok*HIDD*4);
  size_t xStart = (off + 255) & ~(size_t)255;
  off = xStart;
  __hip_bfloat16* Ae      = (__hip_bfloat16*)alloc((size_t)NPAD*HIDD*2);
  __hip_bfloat16* actg    = (__hip_bfloat16*)alloc((size_t)NPAD*2*Ii*2);
  off = xStart;
  __hip_bfloat16* ed_t    = (__hip_bfloat16*)alloc((size_t)Ee*HIDD*Ii*2);

  dim3 blk(256);
  const int nelem = Ntok*Pp;
  #define NO5 nullptr, nullptr, nullptr, nullptr, nullptr

  // ================= attention =================
  rms_split_kernel<<<Ntok, blk, 0, stream>>>(x, norm1_w, xn, xn_lo, 1e-5f);
  trans_split_kernel<<<dim3(32,32,1), blk, 0, stream>>>(wq, wqkv_t, wqkv_lo, HIDD, Pp);
  trans_split_kernel<<<dim3(32,32,1), blk, 0, stream>>>(wk, wqkv_t + (size_t)Pp*HIDD,
                                                        wqkv_lo + (size_t)Pp*HIDD, HIDD, Pp);
  trans_split_kernel<<<dim3(32,32,1), blk, 0, stream>>>(wv, wqkv_t + (size_t)2*Pp*HIDD,
                                                        wqkv_lo + (size_t)2*Pp*HIDD, HIDD, Pp);
  trans_split_kernel<<<dim3(32,32,1), blk, 0, stream>>>(wo, wo_t, wo_lo, Pp, HIDD);
  trans_kernel<<<dim3(2,32,1),  blk, 0, stream>>>(fa, fg_t, HIDD, Dd, 0, 0);
  trans_kernel<<<dim3(2,32,1),  blk, 0, stream>>>(ga, fg_t + (size_t)Dd*HIDD, HIDD, Dd, 0, 0);
  trans_kernel<<<dim3(32,2,1),  blk, 0, stream>>>(fb, fb_t, Dd, Pp, 0, 0);
  trans_kernel<<<dim3(32,2,1),  blk, 0, stream>>>(gb, gb_t, Dd, Pp, 0, 0);

  // QKV: one-dispatch 3-phase split GEMM
  gemm3_k<0><<<dim3(48,16,1), blk, 0, stream>>>(xn, xn_lo, wqkv_t, wqkv_lo, qkvlin,
                                                Ntok, 3*Pp, HIDD, nullptr);
  // fused conv + silu + l2norm
  conv_norm_kernel<<<dim3(Ntok,3,1), blk, 0, stream>>>(qkvlin, cq, ck, cv, qc, kc, vc);
  // decay + gate low-rank stage 1 (fa|ga merged, N=128)
  gemm_k<1,0><<<dim3(2,16,1), blk, 0, stream>>>(xn, fg_t, atmp12, Ntok, 2*Dd, HIDD, HIDD, NO5, nullptr);
  // stage 2: fb on first half of atmp12, gb on second half (lda=128)
  gemm_k<0,0><<<dim3(16,16,1), blk, 0, stream>>>(atmp12, fb_t, gbuf, Ntok, Pp, Dd, 2*Dd, NO5, nullptr);
  gemm_k<0,0><<<dim3(16,16,1), blk, 0, stream>>>(atmp12+Dd, gb_t, gatebuf, Ntok, Pp, Dd, 2*Dd, NO5, nullptr);
  g_kernel<<<(nelem+255)/256, blk, 0, stream>>>(gbuf, A_log, dt_bias);
  beta_kernel<<<Ntok, blk, 0, stream>>>(xn, bp, betab);
  scan_kernel<<<Bb*Hh*4, dim3(64), 0, stream>>>(qc, kc, vc, gbuf, betab, obuf);
  onorm_gate_split_kernel<<<(Ntok*Hh)/4, blk, 0, stream>>>(obuf, onorm_w, gatebuf, obuf_hi, obuf_lo);
  // wo: one-dispatch 3-phase split GEMM + residual
  gemm3_k<2><<<dim3(16,16,1), blk, 0, stream>>>(obuf_hi, obuf_lo, wo_t, wo_lo, hbuf,
                                                Ntok, HIDD, Pp, x);

  // ================= MoE =================
  rms_bf16_kernel<<<Ntok, blk, 0, stream>>>(hbuf, norm2_w, hn, 1e-5f);
  router_scores_kernel<<<Ntok, blk, 0, stream>>>(hbuf, norm2_w, gate_w, scores);
  hipMemsetAsync(counts, 0, Ee*sizeof(int), stream);
  router_kernel<<<(Ntok+255)/256, blk, 0, stream>>>(scores, gate_b, counts, tok_list, slot_list, wt_list);
  prefix_kernel<<<1, 64, 0, stream>>>(counts, prefix);
  compact_kernel<<<Ee, blk, 0, stream>>>(counts, prefix, tok_list, slot_list, wt_list, ctok, cslot, cwt);
  gather_kernel<<<NASSIGN, dim3(128), 0, stream>>>(hn, ctok, Ae);
  trans_kernel<<<dim3(24,32,Ee), blk, 0, stream>>>(wg_e, egu_t,
      HIDD, Ii, (long)HIDD*Ii, (long)2*Ii*HIDD);
  trans_kernel<<<dim3(24,32,Ee), blk, 0, stream>>>(wu_e, egu_t + (size_t)Ii*HIDD,
      HIDD, Ii, (long)HIDD*Ii, (long)2*Ii*HIDD);
  gemm_k<3,0><<<dim3(24,16,Ee), blk, 0, stream>>>(Ae, egu_t, actg, Ntok, 2*Ii, HIDD, HIDD,
                                                  nullptr, counts, prefix, nullptr, nullptr, nullptr);
  glu_kernel<<<(NASSIGN*Ii+255)/256, blk, 0, stream>>>(actg, act, NASSIGN);
  trans_kernel<<<dim3(32,24,Ee), blk, 0, stream>>>(wd_e, ed_t,
      Ii, HIDD, (long)Ii*HIDD, (long)HIDD*Ii);
  gemm_k<4,0><<<dim3(16,16,Ee), blk, 0, stream>>>(act, ed_t, routed, Ntok, HIDD, Ii, Ii,
                                                  nullptr, counts, prefix, ctok, cslot, cwt);
  trans_kernel<<<dim3(24,32,1), blk, 0, stream>>>(wg_s, sgu_t, HIDD, ISs, 0, 0);
  trans_kernel<<<dim3(24,32,1), blk, 0, stream>>>(wu_s, sgu_t + (size_t)ISs*HIDD, HIDD, ISs, 0, 0);
  trans_kernel<<<dim3(32,24,1), blk, 0, stream>>>(wd_s, sd_t, ISs, HIDD, 0, 0);
  gemm_k<1,0><<<dim3(24,16,1), blk, 0, stream>>>(hn, sgu_t, sgu_raw, Ntok, 2*ISs, HIDD, HIDD, NO5, nullptr);
  glu_kernel<<<(Ntok*ISs+255)/256, blk, 0, stream>>>(sgu_raw, sgb, Ntok);
  gemm_k<0,0><<<dim3(16,16,1), blk, 0, stream>>>(sgb, sd_t, shout, Ntok, HIDD, ISs, ISs, NO5, nullptr);

  final_kernel<<<(Ntok*HIDD+255)/256, blk, 0, stream>>>(hbuf, routed, shout, out);
}

// Round 6
// 413.869 us; speedup vs baseline: 8.4818x; 1.0366x over previous
//
#include <hip/hip_runtime.h>
#include <hip/hip_bf16.h>
#include <math.h>

#define Bb 2
#define Tt 512
#define HIDD 1024
#define Hh 16
#define Dd 64
#define Pp 1024
#define Kc 4
#define Ee 8
#define Ii 768
#define ISs 768
#define Ntok (Bb*Tt)   // 1024
#define NASSIGN (2*Ntok) // 2048 routed assignments
#define NPAD 2112
#define CH 16
#define NCH (Tt/CH)

typedef __attribute__((ext_vector_type(8))) short bf16x8;
typedef __attribute__((ext_vector_type(4))) float floatx4;

__device__ __forceinline__ float sigmoidf_(float x){ return 1.f/(1.f+expf(-x)); }
__device__ __forceinline__ float siluf_(float x){ return x/(1.f+expf(-x)); }
__device__ __forceinline__ float bf2f(__hip_bfloat16 b){ return __bfloat162float(b); }

__device__ __forceinline__ void async16(void* lds, const void* g) {
  __builtin_amdgcn_global_load_lds(
      (const __attribute__((address_space(1))) void*)g,
      (__attribute__((address_space(3))) void*)lds, 16, 0, 0);
}

// quad-perm DPP add: x + x[lane ^ (1 or 2)] (VALU pipe, no LDS)
template<int CTRL>
__device__ __forceinline__ float dpp_add(float x){
  int y = __builtin_amdgcn_update_dpp(0, __float_as_int(x), CTRL, 0xF, 0xF, true);
  return x + __int_as_float(y);
}
// xor1 = quad_perm[1,0,3,2] = 0xB1 ; xor2 = quad_perm[2,3,0,1] = 0x4E

// ================= RMS norm (fp32 in, bf16 out) =================
__global__ void rms_bf16_kernel(const float* __restrict__ x, const float* __restrict__ w,
                                __hip_bfloat16* __restrict__ out, float eps) {
  int row = blockIdx.x;
  const float* xr = x + (size_t)row*HIDD;
  float s = 0.f;
  for (int i = threadIdx.x; i < HIDD; i += 256){ float v = xr[i]; s += v*v; }
  #pragma unroll
  for (int off=32; off; off>>=1) s += __shfl_down(s, off, 64);
  __shared__ float red[4];
  if ((threadIdx.x & 63)==0) red[threadIdx.x>>6] = s;
  __syncthreads();
  float tot = red[0]+red[1]+red[2]+red[3];
  float sc = rsqrtf(tot/(float)HIDD + eps);
  for (int i = threadIdx.x; i < HIDD; i += 256)
    out[(size_t)row*HIDD+i] = __float2bfloat16(xr[i]*sc*w[i]);
}

// ================= RMS norm (fp32 in, split hi/lo bf16 out) =================
__global__ void rms_split_kernel(const float* __restrict__ x, const float* __restrict__ w,
                                 __hip_bfloat16* __restrict__ hi, __hip_bfloat16* __restrict__ lo,
                                 float eps) {
  int row = blockIdx.x;
  const float* xr = x + (size_t)row*HIDD;
  float s = 0.f;
  for (int i = threadIdx.x; i < HIDD; i += 256){ float v = xr[i]; s += v*v; }
  #pragma unroll
  for (int off=32; off; off>>=1) s += __shfl_down(s, off, 64);
  __shared__ float red[4];
  if ((threadIdx.x & 63)==0) red[threadIdx.x>>6] = s;
  __syncthreads();
  float tot = red[0]+red[1]+red[2]+red[3];
  float sc = rsqrtf(tot/(float)HIDD + eps);
  for (int i = threadIdx.x; i < HIDD; i += 256) {
    float v = xr[i]*sc*w[i];
    __hip_bfloat16 h = __float2bfloat16(v);
    hi[(size_t)row*HIDD+i] = h;
    lo[(size_t)row*HIDD+i] = __float2bfloat16(v - bf2f(h));
  }
}

// ================= transpose + f32->bf16: src[K][N] -> dst[N][K] =================
__global__ void trans_kernel(const float* __restrict__ src, __hip_bfloat16* __restrict__ dst,
                             int K, int N, long sbs, long dbs) {
  src += (size_t)blockIdx.z * sbs; dst += (size_t)blockIdx.z * dbs;
  __shared__ float tile[32][33];
  int n0 = blockIdx.x*32, k0 = blockIdx.y*32;
  int tx = threadIdx.x & 31, ty0 = threadIdx.x >> 5;
  #pragma unroll
  for (int j=0;j<4;j++){ int ty = ty0 + j*8; tile[ty][tx] = src[(size_t)(k0+ty)*N + n0+tx]; }
  __syncthreads();
  #pragma unroll
  for (int j=0;j<4;j++){ int ty = ty0 + j*8; dst[(size_t)(n0+ty)*K + k0+tx] = __float2bfloat16(tile[tx][ty]); }
}

// ================= transpose + split hi/lo: src[K][N] -> hi/lo[N][K] =================
__global__ void trans_split_kernel(const float* __restrict__ src, __hip_bfloat16* __restrict__ hi,
                                   __hip_bfloat16* __restrict__ lo, int K, int N) {
  __shared__ float tile[32][33];
  int n0 = blockIdx.x*32, k0 = blockIdx.y*32;
  int tx = threadIdx.x & 31, ty0 = threadIdx.x >> 5;
  #pragma unroll
  for (int j=0;j<4;j++){ int ty = ty0 + j*8; tile[ty][tx] = src[(size_t)(k0+ty)*N + n0+tx]; }
  __syncthreads();
  #pragma unroll
  for (int j=0;j<4;j++){
    int ty = ty0 + j*8;
    float v = tile[tx][ty];
    __hip_bfloat16 h = __float2bfloat16(v);
    hi[(size_t)(n0+ty)*K + k0+tx] = h;
    lo[(size_t)(n0+ty)*K + k0+tx] = __float2bfloat16(v - bf2f(h));
  }
}

// ================= MFMA GEMM core =================
__device__ __forceinline__ int lds_off(int row, int slot){
  return row*128 + (((slot ^ row)&7)<<4);
}

// MODE 0: f32 out. 1: bf16 out. 2: f32 out + resid. 3: expert compact bf16 out.
// 4: expert scatter f32->bf16 routed out with per-row weight.
template<int MODE, int ACC>
__global__ __launch_bounds__(256)
void gemm_k(const __hip_bfloat16* __restrict__ A, const __hip_bfloat16* __restrict__ BT,
            void* __restrict__ C, int M, int N, int K, int lda, const float* __restrict__ resid,
            const int* __restrict__ counts, const int* __restrict__ prefix,
            const int* __restrict__ ctok, const int* __restrict__ cslot,
            const float* __restrict__ cwt) {
  int Me = M;
  int moff = 0;
  if (MODE >= 3) {
    int e = blockIdx.z;
    Me = counts[e]; moff = prefix[e];
    A  += (size_t)moff * lda;
    BT += (size_t)e * (size_t)N * K;
  }
  int row0 = blockIdx.y * 64;
  if (row0 >= Me) return;
  int col0 = blockIdx.x * 64;

  __shared__ __attribute__((aligned(16))) short As[64*64];
  __shared__ __attribute__((aligned(16))) short Bs[64*64];
  const int lane = threadIdx.x & 63;
  const int w    = threadIdx.x >> 6;
  const int wr = w >> 1, wc = w & 1;
  const int srow = lane >> 3;
  const int sch  = (lane & 7) ^ (srow & 7);
  const int q = lane >> 4, r16 = lane & 15;

  const __hip_bfloat16* Ag = A  + (size_t)row0 * lda;
  const __hip_bfloat16* Bg = BT + (size_t)col0 * K;

  floatx4 acc[2][2] = {};

  for (int k0 = 0; k0 < K; k0 += 64) {
    #pragma unroll
    for (int ii = 0; ii < 2; ++ii) {
      const int inst = w + ii*4;
      const int r = inst*8 + srow;
      async16((char*)As + inst*1024, Ag + (size_t)r*lda + (size_t)(k0 + sch*8));
      async16((char*)Bs + inst*1024, Bg + (size_t)r*K   + (size_t)(k0 + sch*8));
    }
    __syncthreads();
    #pragma unroll
    for (int kk = 0; kk < 2; ++kk) {
      int slot = kk*4 + q;
      bf16x8 a0 = *(const bf16x8*)((const char*)As + lds_off(wr*32 +      r16, slot));
      bf16x8 a1 = *(const bf16x8*)((const char*)As + lds_off(wr*32 + 16 + r16, slot));
      bf16x8 b0 = *(const bf16x8*)((const char*)Bs + lds_off(wc*32 +      r16, slot));
      bf16x8 b1 = *(const bf16x8*)((const char*)Bs + lds_off(wc*32 + 16 + r16, slot));
      acc[0][0] = __builtin_amdgcn_mfma_f32_16x16x32_bf16(a0, b0, acc[0][0], 0, 0, 0);
      acc[0][1] = __builtin_amdgcn_mfma_f32_16x16x32_bf16(a0, b1, acc[0][1], 0, 0, 0);
      acc[1][0] = __builtin_amdgcn_mfma_f32_16x16x32_bf16(a1, b0, acc[1][0], 0, 0, 0);
      acc[1][1] = __builtin_amdgcn_mfma_f32_16x16x32_bf16(a1, b1, acc[1][1], 0, 0, 0);
    }
    __syncthreads();
  }

  #pragma unroll
  for (int mi = 0; mi < 2; ++mi) {
    #pragma unroll
    for (int r = 0; r < 4; ++r) {
      int grow = row0 + wr*32 + mi*16 + q*4 + r;
      if (grow >= Me) continue;
      #pragma unroll
      for (int ni = 0; ni < 2; ++ni) {
        int gcol = col0 + wc*32 + ni*16 + r16;
        float v = acc[mi][ni][r];
        if (MODE == 0) {
          float* Cp = (float*)C + (size_t)grow*N + gcol;
          if (ACC) v += *Cp;
          *Cp = v;
        } else if (MODE == 2) {
          float* Cp = (float*)C + (size_t)grow*N + gcol;
          if (ACC) v += *Cp;
          *Cp = v + resid[(size_t)grow*N + gcol];
        } else if (MODE == 1) {
          ((__hip_bfloat16*)C)[(size_t)grow*N + gcol] = __float2bfloat16(v);
        } else if (MODE == 3) {
          ((__hip_bfloat16*)C)[(size_t)(moff+grow)*N + gcol] = __float2bfloat16(v);
        } else { // 4
          int rc = moff + grow;
          int tok = ctok[rc], sl = cslot[rc];
          ((__hip_bfloat16*)C)[((size_t)tok*2 + sl)*N + gcol] = __float2bfloat16(cwt[rc]*v);
        }
      }
    }
  }
}

// 3-phase split-bf16 GEMM in one dispatch: C = Ahi·Bhi + Ahi·Blo + Alo·Bhi [+resid]
template<int MODE>  // 0: f32 out, 2: f32 out + resid
__global__ __launch_bounds__(256)
void gemm3_k(const __hip_bfloat16* __restrict__ Ahi, const __hip_bfloat16* __restrict__ Alo,
             const __hip_bfloat16* __restrict__ Bhi, const __hip_bfloat16* __restrict__ Blo,
             float* __restrict__ C, int M, int N, int K, const float* __restrict__ resid) {
  int row0 = blockIdx.y * 64;
  int col0 = blockIdx.x * 64;

  __shared__ __attribute__((aligned(16))) short As[64*64];
  __shared__ __attribute__((aligned(16))) short Bs[64*64];
  const int lane = threadIdx.x & 63;
  const int w    = threadIdx.x >> 6;
  const int wr = w >> 1, wc = w & 1;
  const int srow = lane >> 3;
  const int sch  = (lane & 7) ^ (srow & 7);
  const int q = lane >> 4, r16 = lane & 15;

  floatx4 acc[2][2] = {};

  for (int p = 0; p < 3; ++p) {
    const __hip_bfloat16* Ag = ((p==2)? Alo : Ahi) + (size_t)row0 * K;
    const __hip_bfloat16* Bg = ((p==1)? Blo : Bhi) + (size_t)col0 * K;
    for (int k0 = 0; k0 < K; k0 += 64) {
      #pragma unroll
      for (int ii = 0; ii < 2; ++ii) {
        const int inst = w + ii*4;
        const int r = inst*8 + srow;
        async16((char*)As + inst*1024, Ag + (size_t)r*K + (size_t)(k0 + sch*8));
        async16((char*)Bs + inst*1024, Bg + (size_t)r*K + (size_t)(k0 + sch*8));
      }
      __syncthreads();
      #pragma unroll
      for (int kk = 0; kk < 2; ++kk) {
        int slot = kk*4 + q;
        bf16x8 a0 = *(const bf16x8*)((const char*)As + lds_off(wr*32 +      r16, slot));
        bf16x8 a1 = *(const bf16x8*)((const char*)As + lds_off(wr*32 + 16 + r16, slot));
        bf16x8 b0 = *(const bf16x8*)((const char*)Bs + lds_off(wc*32 +      r16, slot));
        bf16x8 b1 = *(const bf16x8*)((const char*)Bs + lds_off(wc*32 + 16 + r16, slot));
        acc[0][0] = __builtin_amdgcn_mfma_f32_16x16x32_bf16(a0, b0, acc[0][0], 0, 0, 0);
        acc[0][1] = __builtin_amdgcn_mfma_f32_16x16x32_bf16(a0, b1, acc[0][1], 0, 0, 0);
        acc[1][0] = __builtin_amdgcn_mfma_f32_16x16x32_bf16(a1, b0, acc[1][0], 0, 0, 0);
        acc[1][1] = __builtin_amdgcn_mfma_f32_16x16x32_bf16(a1, b1, acc[1][1], 0, 0, 0);
      }
      __syncthreads();
    }
  }

  #pragma unroll
  for (int mi = 0; mi < 2; ++mi) {
    #pragma unroll
    for (int r = 0; r < 4; ++r) {
      int grow = row0 + wr*32 + mi*16 + q*4 + r;
      #pragma unroll
      for (int ni = 0; ni < 2; ++ni) {
        int gcol = col0 + wc*32 + ni*16 + r16;
        float v = acc[mi][ni][r];
        if (MODE == 2) v += resid[(size_t)grow*N + gcol];
        C[(size_t)grow*N + gcol] = v;
      }
    }
  }
}

// ================= fused causal dwconv(K=4) + SiLU + (L2 norm for q/k) =================
__global__ void conv_norm_kernel(const float* __restrict__ in,
                                 const float* __restrict__ cq, const float* __restrict__ ck,
                                 const float* __restrict__ cv,
                                 float* __restrict__ qc, float* __restrict__ kc,
                                 float* __restrict__ vc) {
  int tok = blockIdx.x;
  int mode = blockIdx.y;
  const float* w = (mode==0) ? cq : (mode==1) ? ck : cv;
  float* outp    = (mode==0) ? qc : (mode==1) ? kc : vc;
  int colOff = mode << 10;
  int t = threadIdx.x;
  int c0 = t*4;
  int tloc = tok & (Tt-1);

  float wv[4][4];
  #pragma unroll
  for (int i=0;i<4;i++){
    float4 w4 = ((const float4*)w)[c0+i];
    wv[i][0]=w4.x; wv[i][1]=w4.y; wv[i][2]=w4.z; wv[i][3]=w4.w;
  }
  float acc[4] = {0.f,0.f,0.f,0.f};
  #pragma unroll
  for (int j=0;j<Kc;j++){
    int tt = tloc - (Kc-1) + j;
    if (tt >= 0){
      float4 xv = *(const float4*)&in[(size_t)(tok-(Kc-1)+j)*3072 + colOff + c0];
      acc[0] += wv[0][j]*xv.x;
      acc[1] += wv[1][j]*xv.y;
      acc[2] += wv[2][j]*xv.z;
      acc[3] += wv[3][j]*xv.w;
    }
  }
  float val[4];
  #pragma unroll
  for (int i=0;i<4;i++) val[i] = siluf_(acc[i]);
  float scale = 1.f;
  if (mode < 2) {
    float ss = val[0]*val[0]+val[1]*val[1]+val[2]*val[2]+val[3]*val[3];
    ss += __shfl_xor(ss, 1, 64);
    ss += __shfl_xor(ss, 2, 64);
    ss += __shfl_xor(ss, 4, 64);
    ss += __shfl_xor(ss, 8, 64);
    scale = rsqrtf(ss/(float)Dd + 1e-6f) * ((mode==0) ? (1.f/64.f) : 0.125f);
  }
  float4 o4 = make_float4(val[0]*scale, val[1]*scale, val[2]*scale, val[3]*scale);
  *(float4*)&outp[(size_t)tok*Pp + c0] = o4;
}

// ================= g = exp(-exp(A_log)*softplus(a + dt_bias)) =================
__global__ void g_kernel(float* __restrict__ a, const float* __restrict__ A_log,
                         const float* __restrict__ dt_bias) {
  int idx = blockIdx.x*256 + threadIdx.x;
  if (idx >= Ntok*Pp) return;
  int d = idx & 63;
  int hh = (idx >> 6) & 15;
  float v = a[idx] + dt_bias[hh*Dd + d];
  float sp = (v > 20.f) ? v : log1pf(expf(v));
  a[idx] = expf(-expf(A_log[hh]) * sp);
}

// ================= beta = sigmoid(xn @ bp), N=16 =================
__global__ void beta_kernel(const __hip_bfloat16* __restrict__ xn, const float* __restrict__ bp,
                            float* __restrict__ betab) {
  int row = blockIdx.x;
  int t = threadIdx.x;
  int n = t & 15, ch = t >> 4;
  float s = 0.f;
  for (int k = ch*64; k < ch*64+64; ++k)
    s += bf2f(xn[(size_t)row*HIDD + k]) * bp[k*16 + n];
  __shared__ float red[256];
  red[t] = s; __syncthreads();
  if (t < 16) {
    float tot = 0.f;
    #pragma unroll
    for (int c2 = 0; c2 < 16; ++c2) tot += red[c2*16 + t];
    betab[(size_t)row*16 + t] = sigmoidf_(tot);
  }
}

// ================= router logits fp32 from hbuf (fused rms) =================
__global__ void router_scores_kernel(const float* __restrict__ h, const float* __restrict__ w2,
                                     const float* __restrict__ gw, float* __restrict__ scores) {
  int row = blockIdx.x;
  const float* hr = h + (size_t)row*HIDD;
  float s = 0.f;
  for (int i = threadIdx.x; i < HIDD; i += 256){ float v = hr[i]; s += v*v; }
  #pragma unroll
  for (int off=32; off; off>>=1) s += __shfl_down(s, off, 64);
  __shared__ float red[4];
  if ((threadIdx.x & 63)==0) red[threadIdx.x>>6] = s;
  __syncthreads();
  float sc = rsqrtf((red[0]+red[1]+red[2]+red[3])/(float)HIDD + 1e-5f);
  float acc[Ee] = {};
  for (int i = threadIdx.x; i < HIDD; i += 256){
    float xv = hr[i]*sc*w2[i];
    #pragma unroll
    for (int e=0;e<Ee;e++) acc[e] += xv*gw[i*Ee+e];
  }
  #pragma unroll
  for (int e=0;e<Ee;e++){
    #pragma unroll
    for (int off=32; off; off>>=1) acc[e] += __shfl_down(acc[e], off, 64);
  }
  __shared__ float red2[4][Ee];
  if ((threadIdx.x & 63)==0){
    #pragma unroll
    for (int e=0;e<Ee;e++) red2[threadIdx.x>>6][e] = acc[e];
  }
  __syncthreads();
  if (threadIdx.x < Ee)
    scores[(size_t)row*Ee + threadIdx.x] =
      red2[0][threadIdx.x]+red2[1][threadIdx.x]+red2[2][threadIdx.x]+red2[3][threadIdx.x];
}

// ================= delta-rule scan v4: register double-buffer prefetch =================
// block = (b, hh, vb). lane = vi*4 + kq.
__global__ __launch_bounds__(64)
void scan_kernel(const float* __restrict__ q, const float* __restrict__ k,
                 const float* __restrict__ v, const float* __restrict__ g,
                 const float* __restrict__ beta, float* __restrict__ o) {
  const int vb = blockIdx.x & 3;
  const int hh = (blockIdx.x >> 2) & 15;
  const int b  = blockIdx.x >> 6;
  const int lane = threadIdx.x;
  const int kq = lane & 3;
  const int vi = lane >> 2;
  const int v0 = vb*16;
  const int rb = b*Tt;

  __shared__ __attribute__((aligned(16))) float sq[2][CH][64];
  __shared__ __attribute__((aligned(16))) float sk[2][CH][64];
  __shared__ __attribute__((aligned(16))) float sg[2][CH][64];
  __shared__ __attribute__((aligned(16))) float sv[2][CH][16];
  __shared__ float sb[Tt];

  #pragma unroll
  for (int i=0;i<Tt/64;i++)
    sb[i*64+lane] = beta[(size_t)(rb + i*64 + lane)*Hh + hh];

  auto stage = [&](int t0, int pb) {
    const int srow = lane >> 4, sch4 = (lane & 15)*4;
    #pragma unroll
    for (int ii=0; ii<4; ++ii) {
      size_t gbase = (size_t)(rb + t0 + ii*4 + srow)*Pp + hh*64;
      async16(&sq[pb][ii*4][0], q + gbase + sch4);
      async16(&sk[pb][ii*4][0], k + gbase + sch4);
      async16(&sg[pb][ii*4][0], g + gbase + sch4);
    }
    size_t gv = (size_t)(rb + t0 + (lane>>2))*Pp + hh*64 + v0 + (lane&3)*4;
    async16(&sv[pb][0][0], v + gv);
  };

  // double-buffered per-step operand registers
  float4 K4[2][4], G4[2][4], Q4[2][4];
  float VV[2], BB[2];

  auto ldstep = [&](int pb, int i, int pr, int t){
    const float4* kp = (const float4*)&sk[pb][i][kq*16];
    const float4* gp = (const float4*)&sg[pb][i][kq*16];
    const float4* qp = (const float4*)&sq[pb][i][kq*16];
    #pragma unroll
    for (int jj=0;jj<4;jj++){ K4[pr][jj]=kp[jj]; G4[pr][jj]=gp[jj]; Q4[pr][jj]=qp[jj]; }
    VV[pr] = sv[pb][i][vi];
    BB[pr] = sb[t];
  };

  float S[16];
  #pragma unroll
  for (int j=0;j<16;j++) S[j]=0.f;

  stage(0, 0);
  asm volatile("s_waitcnt vmcnt(0)" ::: "memory");
  ldstep(0, 0, 0, 0);

  for (int c=0; c<NCH; ++c) {
    int pb = c & 1;
    if (c+1 < NCH) stage((c+1)*CH, pb^1);
    #pragma unroll
    for (int i=0;i<CH;i++){
      int t = c*CH + i;
      int cur = i & 1, nxt = cur ^ 1;
      // prefetch next step's operands (overlaps with compute below)
      if (i < CH-1) {
        ldstep(pb, i+1, nxt, t+1);
      } else if (c+1 < NCH) {
        asm volatile("s_waitcnt vmcnt(0)" ::: "memory");  // next chunk staged (13 loads, issued ~15 steps ago)
        ldstep(pb^1, 0, nxt, t+1);
      }
      // compute step t from [cur]
      float pr0=0.f, pr1=0.f, pr2=0.f, pr3=0.f;
      #pragma unroll
      for (int jj=0;jj<4;jj++){
        float4 gg = G4[cur][jj]; float4 kk = K4[cur][jj];
        float s0 = S[jj*4+0]*gg.x; S[jj*4+0]=s0; pr0 += kk.x*s0;
        float s1 = S[jj*4+1]*gg.y; S[jj*4+1]=s1; pr1 += kk.y*s1;
        float s2 = S[jj*4+2]*gg.z; S[jj*4+2]=s2; pr2 += kk.z*s2;
        float s3 = S[jj*4+3]*gg.w; S[jj*4+3]=s3; pr3 += kk.w*s3;
      }
      float pred = (pr0+pr1)+(pr2+pr3);
      pred = dpp_add<0xB1>(pred);      // + lane^1
      pred = dpp_add<0x4E>(pred);      // + lane^2
      float upd = (VV[cur] - pred) * BB[cur];
      float a0=0.f, a1=0.f, a2=0.f, a3=0.f;
      #pragma unroll
      for (int jj=0;jj<4;jj++){
        float4 kk = K4[cur][jj]; float4 qq = Q4[cur][jj];
        float s0 = S[jj*4+0]+kk.x*upd; S[jj*4+0]=s0; a0 += qq.x*s0;
        float s1 = S[jj*4+1]+kk.y*upd; S[jj*4+1]=s1; a1 += qq.y*s1;
        float s2 = S[jj*4+2]+kk.z*upd; S[jj*4+2]=s2; a2 += qq.z*s2;
        float s3 = S[jj*4+3]+kk.w*upd; S[jj*4+3]=s3; a3 += qq.w*s3;
      }
      float acc = (a0+a1)+(a2+a3);
      acc = dpp_add<0xB1>(acc);
      acc = dpp_add<0x4E>(acc);
      if (kq == 0) o[(size_t)(rb+t)*Pp + hh*64 + v0 + vi] = acc;
    }
  }
}

// ================= o = rms(o)*w*sigmoid(gate) -> split hi/lo bf16 =================
__global__ void onorm_gate_split_kernel(const float* __restrict__ o, const float* __restrict__ w,
                                        const float* __restrict__ gate,
                                        __hip_bfloat16* __restrict__ hi, __hip_bfloat16* __restrict__ lo) {
  int row = blockIdx.x*4 + (threadIdx.x>>6);
  int lane = threadIdx.x & 63;
  size_t idx = (size_t)row*Dd + lane;
  float v = o[idx];
  float s = v*v;
  #pragma unroll
  for (int off=32; off; off>>=1) s += __shfl_xor(s, off, 64);
  float r = v * rsqrtf(s/(float)Dd + 1e-5f) * w[lane] * sigmoidf_(gate[idx]);
  __hip_bfloat16 h = __float2bfloat16(r);
  hi[idx] = h;
  lo[idx] = __float2bfloat16(r - bf2f(h));
}

// ================= router top-2 =================
__global__ void router_kernel(const float* __restrict__ logits, const float* __restrict__ gate_b,
                              int* __restrict__ counts, int* __restrict__ tok_list,
                              int* __restrict__ slot_list, float* __restrict__ wt_list) {
  int n = blockIdx.x*256 + threadIdx.x;
  if (n >= Ntok) return;
  float sc[Ee], bi[Ee];
  #pragma unroll
  for (int e=0;e<Ee;e++){ float s = sigmoidf_(logits[n*Ee+e]); sc[e]=s; bi[e]=s+gate_b[e]; }
  int i0=0;
  #pragma unroll
  for (int e=1;e<Ee;e++) if (bi[e] > bi[i0]) i0=e;
  int i1=-1;
  #pragma unroll
  for (int e=0;e<Ee;e++){ if (e==i0) continue; if (i1<0 || bi[e] > bi[i1]) i1=e; }
  float w0=sc[i0], w1=sc[i1];
  float inv = 1.f/(w0+w1+1e-20f);
  w0*=inv; w1*=inv;
  int p0 = atomicAdd(&counts[i0],1);
  tok_list[i0*Ntok+p0]=n; slot_list[i0*Ntok+p0]=0; wt_list[i0*Ntok+p0]=w0;
  int p1 = atomicAdd(&counts[i1],1);
  tok_list[i1*Ntok+p1]=n; slot_list[i1*Ntok+p1]=1; wt_list[i1*Ntok+p1]=w1;
}

__global__ void prefix_kernel(const int* __restrict__ counts, int* __restrict__ prefix) {
  if (threadIdx.x==0 && blockIdx.x==0){ int s=0; for (int e=0;e<Ee;e++){ prefix[e]=s; s+=counts[e]; } }
}

__global__ void compact_kernel(const int* __restrict__ counts, const int* __restrict__ prefix,
                               const int* __restrict__ tok_list, const int* __restrict__ slot_list,
                               const float* __restrict__ wt_list,
                               int* __restrict__ ctok, int* __restrict__ cslot, float* __restrict__ cwt) {
  int e = blockIdx.x; int c = counts[e], p = prefix[e];
  for (int i = threadIdx.x; i < c; i += 256) {
    ctok[p+i]  = tok_list[e*Ntok+i];
    cslot[p+i] = slot_list[e*Ntok+i];
    cwt[p+i]   = wt_list[e*Ntok+i];
  }
}

__global__ void gather_kernel(const __hip_bfloat16* __restrict__ hn, const int* __restrict__ ctok,
                              __hip_bfloat16* __restrict__ Ae) {
  int r = blockIdx.x;
  int t = threadIdx.x; // 128
  ((int4*)(Ae + (size_t)r*HIDD))[t] = ((const int4*)(hn + (size_t)ctok[r]*HIDD))[t];
}

// ================= GLU: out = silu(gu[:, :768]) * gu[:, 768:] =================
__global__ void glu_kernel(const __hip_bfloat16* __restrict__ gu, __hip_bfloat16* __restrict__ outp,
                           int rows) {
  int idx = blockIdx.x*256 + threadIdx.x;
  if (idx >= rows*Ii) return;
  int r = idx / Ii, c2 = idx - r*Ii;
  float gv = bf2f(gu[(size_t)r*(2*Ii) + c2]);
  float uv = bf2f(gu[(size_t)r*(2*Ii) + Ii + c2]);
  outp[idx] = __float2bfloat16(siluf_(gv)*uv);
}

__global__ void final_kernel(const float* __restrict__ h, const __hip_bfloat16* __restrict__ routed,
                             const float* __restrict__ shr, float* __restrict__ out) {
  int idx = blockIdx.x*256 + threadIdx.x;
  if (idx >= Ntok*HIDD) return;
  int n = idx >> 10, c = idx & 1023;
  out[idx] = h[idx] + bf2f(routed[(size_t)n*2*HIDD + c]) + bf2f(routed[(size_t)n*2*HIDD + HIDD + c]) + shr[idx];
}

// ---------------------------------------------------------------------------
extern "C" void kernel_launch(void* const* d_in, const int* in_sizes, int n_in,
                              void* d_out, int out_size, void* d_ws, size_t ws_size,
                              hipStream_t stream) {
  (void)in_sizes; (void)n_in; (void)out_size; (void)ws_size;
  const float* x        = (const float*)d_in[0];
  const float* norm1_w  = (const float*)d_in[1];
  const float* wq       = (const float*)d_in[2];
  const float* wk       = (const float*)d_in[3];
  const float* wv       = (const float*)d_in[4];
  const float* cq       = (const float*)d_in[5];
  const float* ck       = (const float*)d_in[6];
  const float* cv       = (const float*)d_in[7];
  const float* fa       = (const float*)d_in[8];
  const float* fb       = (const float*)d_in[9];
  const float* bp       = (const float*)d_in[10];
  const float* ga       = (const float*)d_in[11];
  const float* gb       = (const float*)d_in[12];
  const float* A_log    = (const float*)d_in[13];
  const float* dt_bias  = (const float*)d_in[14];
  const float* onorm_w  = (const float*)d_in[15];
  const float* wo       = (const float*)d_in[16];
  const float* norm2_w  = (const float*)d_in[17];
  const float* gate_w   = (const float*)d_in[18];
  const float* gate_b   = (const float*)d_in[19];
  const float* wg_e     = (const float*)d_in[20];
  const float* wu_e     = (const float*)d_in[21];
  const float* wd_e     = (const float*)d_in[22];
  const float* wg_s     = (const float*)d_in[23];
  const float* wu_s     = (const float*)d_in[24];
  const float* wd_s     = (const float*)d_in[25];
  float* out = (float*)d_out;

  char* base = (char*)d_ws;
  size_t off = 0;
  auto alloc = [&](size_t bytes)->char* {
    off = (off + 255) & ~(size_t)255;
    char* p = base + off; off += bytes; return p;
  };
  float* hbuf = (float*)alloc((size_t)Ntok*HIDD*4);
  size_t uStart = (off + 255) & ~(size_t)255;

  // ---- attention view ----
  off = uStart;
  __hip_bfloat16* xn      = (__hip_bfloat16*)alloc((size_t)Ntok*HIDD*2);
  __hip_bfloat16* xn_lo   = (__hip_bfloat16*)alloc((size_t)Ntok*HIDD*2);
  __hip_bfloat16* wqkv_t  = (__hip_bfloat16*)alloc((size_t)3*Pp*HIDD*2);
  __hip_bfloat16* wqkv_lo = (__hip_bfloat16*)alloc((size_t)3*Pp*HIDD*2);
  float*          qkvlin  = (float*)alloc((size_t)Ntok*3*Pp*4);
  float*          qc      = (float*)alloc((size_t)Ntok*Pp*4);
  float*          kc      = (float*)alloc((size_t)Ntok*Pp*4);
  float*          vc      = (float*)alloc((size_t)Ntok*Pp*4);
  float*          gbuf    = (float*)alloc((size_t)Ntok*Pp*4);
  float*          gatebuf = (float*)alloc((size_t)Ntok*Pp*4);
  float*          obuf    = (float*)alloc((size_t)Ntok*Pp*4);
  __hip_bfloat16* atmp12  = (__hip_bfloat16*)alloc((size_t)Ntok*2*Dd*2);
  float*          betab   = (float*)alloc((size_t)Ntok*Hh*4);
  __hip_bfloat16* obuf_hi = (__hip_bfloat16*)alloc((size_t)Ntok*Pp*2);
  __hip_bfloat16* obuf_lo = (__hip_bfloat16*)alloc((size_t)Ntok*Pp*2);
  __hip_bfloat16* wo_t    = (__hip_bfloat16*)alloc((size_t)HIDD*Pp*2);
  __hip_bfloat16* wo_lo   = (__hip_bfloat16*)alloc((size_t)HIDD*Pp*2);
  __hip_bfloat16* fg_t    = (__hip_bfloat16*)alloc((size_t)2*Dd*HIDD*2);
  __hip_bfloat16* fb_t    = (__hip_bfloat16*)alloc((size_t)Pp*Dd*2);
  __hip_bfloat16* gb_t    = (__hip_bfloat16*)alloc((size_t)Pp*Dd*2);

  // ---- moe view (overlaps attention view) ----
  off = uStart;
  __hip_bfloat16* hn      = (__hip_bfloat16*)alloc((size_t)Ntok*HIDD*2);
  float*          scores  = (float*)alloc((size_t)Ntok*Ee*4);
  int*            counts  = (int*)alloc(64);
  int*            prefix  = (int*)alloc(64);
  int*            tok_list  = (int*)alloc((size_t)Ee*Ntok*4);
  int*            slot_list = (int*)alloc((size_t)Ee*Ntok*4);
  float*          wt_list   = (float*)alloc((size_t)Ee*Ntok*4);
  int*            ctok    = (int*)alloc((size_t)NPAD*4);
  int*            cslot   = (int*)alloc((size_t)NPAD*4);
  float*          cwt     = (float*)alloc((size_t)NPAD*4);
  __hip_bfloat16* egu_t   = (__hip_bfloat16*)alloc((size_t)Ee*2*Ii*HIDD*2);
  __hip_bfloat16* sgu_t   = (__hip_bfloat16*)alloc((size_t)2*ISs*HIDD*2);
  __hip_bfloat16* sd_t    = (__hip_bfloat16*)alloc((size_t)HIDD*ISs*2);
  __hip_bfloat16* act     = (__hip_bfloat16*)alloc((size_t)NPAD*Ii*2);
  __hip_bfloat16* sgu_raw = (__hip_bfloat16*)alloc((size_t)Ntok*2*ISs*2);
  __hip_bfloat16* sgb     = (__hip_bfloat16*)alloc((size_t)Ntok*ISs*2);
  __hip_bfloat16* routed  = (__hip_bfloat16*)alloc((size_t)Ntok*2*HIDD*2);
  float*          shout   = (float*)alloc((size_t)Ntok*HIDD*4);
  size_t xStart = (off + 255) & ~(size_t)255;
  off = xStart;
  __hip_bfloat16* Ae      = (__hip_bfloat16*)alloc((size_t)NPAD*HIDD*2);
  __hip_bfloat16* actg    = (__hip_bfloat16*)alloc((size_t)NPAD*2*Ii*2);
  off = xStart;
  __hip_bfloat16* ed_t    = (__hip_bfloat16*)alloc((size_t)Ee*HIDD*Ii*2);

  dim3 blk(256);
  const int nelem = Ntok*Pp;
  #define NO5 nullptr, nullptr, nullptr, nullptr, nullptr

  // ================= attention =================
  rms_split_kernel<<<Ntok, blk, 0, stream>>>(x, norm1_w, xn, xn_lo, 1e-5f);
  trans_split_kernel<<<dim3(32,32,1), blk, 0, stream>>>(wq, wqkv_t, wqkv_lo, HIDD, Pp);
  trans_split_kernel<<<dim3(32,32,1), blk, 0, stream>>>(wk, wqkv_t + (size_t)Pp*HIDD,
                                                        wqkv_lo + (size_t)Pp*HIDD, HIDD, Pp);
  trans_split_kernel<<<dim3(32,32,1), blk, 0, stream>>>(wv, wqkv_t + (size_t)2*Pp*HIDD,
                                                        wqkv_lo + (size_t)2*Pp*HIDD, HIDD, Pp);
  trans_split_kernel<<<dim3(32,32,1), blk, 0, stream>>>(wo, wo_t, wo_lo, Pp, HIDD);
  trans_kernel<<<dim3(2,32,1),  blk, 0, stream>>>(fa, fg_t, HIDD, Dd, 0, 0);
  trans_kernel<<<dim3(2,32,1),  blk, 0, stream>>>(ga, fg_t + (size_t)Dd*HIDD, HIDD, Dd, 0, 0);
  trans_kernel<<<dim3(32,2,1),  blk, 0, stream>>>(fb, fb_t, Dd, Pp, 0, 0);
  trans_kernel<<<dim3(32,2,1),  blk, 0, stream>>>(gb, gb_t, Dd, Pp, 0, 0);

  gemm3_k<0><<<dim3(48,16,1), blk, 0, stream>>>(xn, xn_lo, wqkv_t, wqkv_lo, qkvlin,
                                                Ntok, 3*Pp, HIDD, nullptr);
  conv_norm_kernel<<<dim3(Ntok,3,1), blk, 0, stream>>>(qkvlin, cq, ck, cv, qc, kc, vc);
  gemm_k<1,0><<<dim3(2,16,1), blk, 0, stream>>>(xn, fg_t, atmp12, Ntok, 2*Dd, HIDD, HIDD, NO5, nullptr);
  gemm_k<0,0><<<dim3(16,16,1), blk, 0, stream>>>(atmp12, fb_t, gbuf, Ntok, Pp, Dd, 2*Dd, NO5, nullptr);
  gemm_k<0,0><<<dim3(16,16,1), blk, 0, stream>>>(atmp12+Dd, gb_t, gatebuf, Ntok, Pp, Dd, 2*Dd, NO5, nullptr);
  g_kernel<<<(nelem+255)/256, blk, 0, stream>>>(gbuf, A_log, dt_bias);
  beta_kernel<<<Ntok, blk, 0, stream>>>(xn, bp, betab);
  scan_kernel<<<Bb*Hh*4, dim3(64), 0, stream>>>(qc, kc, vc, gbuf, betab, obuf);
  onorm_gate_split_kernel<<<(Ntok*Hh)/4, blk, 0, stream>>>(obuf, onorm_w, gatebuf, obuf_hi, obuf_lo);
  gemm3_k<2><<<dim3(16,16,1), blk, 0, stream>>>(obuf_hi, obuf_lo, wo_t, wo_lo, hbuf,
                                                Ntok, HIDD, Pp, x);

  // ================= MoE =================
  rms_bf16_kernel<<<Ntok, blk, 0, stream>>>(hbuf, norm2_w, hn, 1e-5f);
  router_scores_kernel<<<Ntok, blk, 0, stream>>>(hbuf, norm2_w, gate_w, scores);
  hipMemsetAsync(counts, 0, Ee*sizeof(int), stream);
  router_kernel<<<(Ntok+255)/256, blk, 0, stream>>>(scores, gate_b, counts, tok_list, slot_list, wt_list);
  prefix_kernel<<<1, 64, 0, stream>>>(counts, prefix);
  compact_kernel<<<Ee, blk, 0, stream>>>(counts, prefix, tok_list, slot_list, wt_list, ctok, cslot, cwt);
  gather_kernel<<<NASSIGN, dim3(128), 0, stream>>>(hn, ctok, Ae);
  trans_kernel<<<dim3(24,32,Ee), blk, 0, stream>>>(wg_e, egu_t,
      HIDD, Ii, (long)HIDD*Ii, (long)2*Ii*HIDD);
  trans_kernel<<<dim3(24,32,Ee), blk, 0, stream>>>(wu_e, egu_t + (size_t)Ii*HIDD,
      HIDD, Ii, (long)HIDD*Ii, (long)2*Ii*HIDD);
  gemm_k<3,0><<<dim3(24,16,Ee), blk, 0, stream>>>(Ae, egu_t, actg, Ntok, 2*Ii, HIDD, HIDD,
                                                  nullptr, counts, prefix, nullptr, nullptr, nullptr);
  glu_kernel<<<(NASSIGN*Ii+255)/256, blk, 0, stream>>>(actg, act, NASSIGN);
  trans_kernel<<<dim3(32,24,Ee), blk, 0, stream>>>(wd_e, ed_t,
      Ii, HIDD, (long)Ii*HIDD, (long)HIDD*Ii);
  gemm_k<4,0><<<dim3(16,16,Ee), blk, 0, stream>>>(act, ed_t, routed, Ntok, HIDD, Ii, Ii,
                                                  nullptr, counts, prefix, ctok, cslot, cwt);
  trans_kernel<<<dim3(24,32,1), blk, 0, stream>>>(wg_s, sgu_t, HIDD, ISs, 0, 0);
  trans_kernel<<<dim3(24,32,1), blk, 0, stream>>>(wu_s, sgu_t + (size_t)ISs*HIDD, HIDD, ISs, 0, 0);
  trans_kernel<<<dim3(32,24,1), blk, 0, stream>>>(wd_s, sd_t, ISs, HIDD, 0, 0);
  gemm_k<1,0><<<dim3(24,16,1), blk, 0, stream>>>(hn, sgu_t, sgu_raw, Ntok, 2*ISs, HIDD, HIDD, NO5, nullptr);
  glu_kernel<<<(Ntok*ISs+255)/256, blk, 0, stream>>>(sgu_raw, sgb, Ntok);
  gemm_k<0,0><<<dim3(16,16,1), blk, 0, stream>>>(sgb, sd_t, shout, Ntok, HIDD, ISs, ISs, NO5, nullptr);

  final_kernel<<<(Ntok*HIDD+255)/256, blk, 0, stream>>>(hbuf, routed, shout, out);
}

// Round 7
// 374.463 us; speedup vs baseline: 9.3743x; 1.1052x over previous
//
#include <hip/hip_runtime.h>
#include <hip/hip_bf16.h>
#include <math.h>

#define Bb 2
#define Tt 512
#define HIDD 1024
#define Hh 16
#define Dd 64
#define Pp 1024
#define Kc 4
#define Ee 8
#define Ii 768
#define ISs 768
#define Ntok (Bb*Tt)   // 1024
#define NASSIGN (2*Ntok) // 2048 routed assignments
#define NPAD 2112
#define CH 16
#define NCH (Tt/CH)

typedef __attribute__((ext_vector_type(8))) short bf16x8;
typedef __attribute__((ext_vector_type(4))) float floatx4;

__device__ __forceinline__ float sigmoidf_(float x){ return 1.f/(1.f+expf(-x)); }
__device__ __forceinline__ float siluf_(float x){ return x/(1.f+expf(-x)); }
__device__ __forceinline__ float bf2f(__hip_bfloat16 b){ return __bfloat162float(b); }

__device__ __forceinline__ void async16(void* lds, const void* g) {
  __builtin_amdgcn_global_load_lds(
      (const __attribute__((address_space(1))) void*)g,
      (__attribute__((address_space(3))) void*)lds, 16, 0, 0);
}

// DPP add: x + x[permuted lane] (VALU pipe, no LDS)
// 0xB1 quad_perm xor1, 0x4E quad_perm xor2, 0x141 row_half_mirror, 0x140 row_mirror
template<int CTRL>
__device__ __forceinline__ float dpp_add(float x){
  int y = __builtin_amdgcn_update_dpp(0, __float_as_int(x), CTRL, 0xF, 0xF, true);
  return x + __int_as_float(y);
}

// ================= RMS norm (fp32 in, bf16 out) =================
__global__ void rms_bf16_kernel(const float* __restrict__ x, const float* __restrict__ w,
                                __hip_bfloat16* __restrict__ out, float eps) {
  int row = blockIdx.x;
  const float* xr = x + (size_t)row*HIDD;
  float s = 0.f;
  for (int i = threadIdx.x; i < HIDD; i += 256){ float v = xr[i]; s += v*v; }
  #pragma unroll
  for (int off=32; off; off>>=1) s += __shfl_down(s, off, 64);
  __shared__ float red[4];
  if ((threadIdx.x & 63)==0) red[threadIdx.x>>6] = s;
  __syncthreads();
  float tot = red[0]+red[1]+red[2]+red[3];
  float sc = rsqrtf(tot/(float)HIDD + eps);
  for (int i = threadIdx.x; i < HIDD; i += 256)
    out[(size_t)row*HIDD+i] = __float2bfloat16(xr[i]*sc*w[i]);
}

// ================= RMS norm (fp32 in, split hi/lo bf16 out) =================
__global__ void rms_split_kernel(const float* __restrict__ x, const float* __restrict__ w,
                                 __hip_bfloat16* __restrict__ hi, __hip_bfloat16* __restrict__ lo,
                                 float eps) {
  int row = blockIdx.x;
  const float* xr = x + (size_t)row*HIDD;
  float s = 0.f;
  for (int i = threadIdx.x; i < HIDD; i += 256){ float v = xr[i]; s += v*v; }
  #pragma unroll
  for (int off=32; off; off>>=1) s += __shfl_down(s, off, 64);
  __shared__ float red[4];
  if ((threadIdx.x & 63)==0) red[threadIdx.x>>6] = s;
  __syncthreads();
  float tot = red[0]+red[1]+red[2]+red[3];
  float sc = rsqrtf(tot/(float)HIDD + eps);
  for (int i = threadIdx.x; i < HIDD; i += 256) {
    float v = xr[i]*sc*w[i];
    __hip_bfloat16 h = __float2bfloat16(v);
    hi[(size_t)row*HIDD+i] = h;
    lo[(size_t)row*HIDD+i] = __float2bfloat16(v - bf2f(h));
  }
}

// ================= transpose + f32->bf16: src[K][N] -> dst[N][K] =================
__global__ void trans_kernel(const float* __restrict__ src, __hip_bfloat16* __restrict__ dst,
                             int K, int N, long sbs, long dbs) {
  src += (size_t)blockIdx.z * sbs; dst += (size_t)blockIdx.z * dbs;
  __shared__ float tile[32][33];
  int n0 = blockIdx.x*32, k0 = blockIdx.y*32;
  int tx = threadIdx.x & 31, ty0 = threadIdx.x >> 5;
  #pragma unroll
  for (int j=0;j<4;j++){ int ty = ty0 + j*8; tile[ty][tx] = src[(size_t)(k0+ty)*N + n0+tx]; }
  __syncthreads();
  #pragma unroll
  for (int j=0;j<4;j++){ int ty = ty0 + j*8; dst[(size_t)(n0+ty)*K + k0+tx] = __float2bfloat16(tile[tx][ty]); }
}

// ================= transpose + split hi/lo: src[K][N] -> hi/lo[N][K] =================
__global__ void trans_split_kernel(const float* __restrict__ src, __hip_bfloat16* __restrict__ hi,
                                   __hip_bfloat16* __restrict__ lo, int K, int N) {
  __shared__ float tile[32][33];
  int n0 = blockIdx.x*32, k0 = blockIdx.y*32;
  int tx = threadIdx.x & 31, ty0 = threadIdx.x >> 5;
  #pragma unroll
  for (int j=0;j<4;j++){ int ty = ty0 + j*8; tile[ty][tx] = src[(size_t)(k0+ty)*N + n0+tx]; }
  __syncthreads();
  #pragma unroll
  for (int j=0;j<4;j++){
    int ty = ty0 + j*8;
    float v = tile[tx][ty];
    __hip_bfloat16 h = __float2bfloat16(v);
    hi[(size_t)(n0+ty)*K + k0+tx] = h;
    lo[(size_t)(n0+ty)*K + k0+tx] = __float2bfloat16(v - bf2f(h));
  }
}

// ================= MFMA GEMM core =================
__device__ __forceinline__ int lds_off(int row, int slot){
  return row*128 + (((slot ^ row)&7)<<4);
}

// MODE 0: f32 out. 1: bf16 out. 2: f32 out + resid. 3: expert compact bf16 out.
// 4: expert scatter f32->bf16 routed out with per-row weight.
template<int MODE, int ACC>
__global__ __launch_bounds__(256)
void gemm_k(const __hip_bfloat16* __restrict__ A, const __hip_bfloat16* __restrict__ BT,
            void* __restrict__ C, int M, int N, int K, int lda, const float* __restrict__ resid,
            const int* __restrict__ counts, const int* __restrict__ prefix,
            const int* __restrict__ ctok, const int* __restrict__ cslot,
            const float* __restrict__ cwt) {
  int Me = M;
  int moff = 0;
  if (MODE >= 3) {
    int e = blockIdx.z;
    Me = counts[e]; moff = prefix[e];
    A  += (size_t)moff * lda;
    BT += (size_t)e * (size_t)N * K;
  }
  int row0 = blockIdx.y * 64;
  if (row0 >= Me) return;
  int col0 = blockIdx.x * 64;

  __shared__ __attribute__((aligned(16))) short As[64*64];
  __shared__ __attribute__((aligned(16))) short Bs[64*64];
  const int lane = threadIdx.x & 63;
  const int w    = threadIdx.x >> 6;
  const int wr = w >> 1, wc = w & 1;
  const int srow = lane >> 3;
  const int sch  = (lane & 7) ^ (srow & 7);
  const int q = lane >> 4, r16 = lane & 15;

  const __hip_bfloat16* Ag = A  + (size_t)row0 * lda;
  const __hip_bfloat16* Bg = BT + (size_t)col0 * K;

  floatx4 acc[2][2] = {};

  for (int k0 = 0; k0 < K; k0 += 64) {
    #pragma unroll
    for (int ii = 0; ii < 2; ++ii) {
      const int inst = w + ii*4;
      const int r = inst*8 + srow;
      async16((char*)As + inst*1024, Ag + (size_t)r*lda + (size_t)(k0 + sch*8));
      async16((char*)Bs + inst*1024, Bg + (size_t)r*K   + (size_t)(k0 + sch*8));
    }
    __syncthreads();
    #pragma unroll
    for (int kk = 0; kk < 2; ++kk) {
      int slot = kk*4 + q;
      bf16x8 a0 = *(const bf16x8*)((const char*)As + lds_off(wr*32 +      r16, slot));
      bf16x8 a1 = *(const bf16x8*)((const char*)As + lds_off(wr*32 + 16 + r16, slot));
      bf16x8 b0 = *(const bf16x8*)((const char*)Bs + lds_off(wc*32 +      r16, slot));
      bf16x8 b1 = *(const bf16x8*)((const char*)Bs + lds_off(wc*32 + 16 + r16, slot));
      acc[0][0] = __builtin_amdgcn_mfma_f32_16x16x32_bf16(a0, b0, acc[0][0], 0, 0, 0);
      acc[0][1] = __builtin_amdgcn_mfma_f32_16x16x32_bf16(a0, b1, acc[0][1], 0, 0, 0);
      acc[1][0] = __builtin_amdgcn_mfma_f32_16x16x32_bf16(a1, b0, acc[1][0], 0, 0, 0);
      acc[1][1] = __builtin_amdgcn_mfma_f32_16x16x32_bf16(a1, b1, acc[1][1], 0, 0, 0);
    }
    __syncthreads();
  }

  #pragma unroll
  for (int mi = 0; mi < 2; ++mi) {
    #pragma unroll
    for (int r = 0; r < 4; ++r) {
      int grow = row0 + wr*32 + mi*16 + q*4 + r;
      if (grow >= Me) continue;
      #pragma unroll
      for (int ni = 0; ni < 2; ++ni) {
        int gcol = col0 + wc*32 + ni*16 + r16;
        float v = acc[mi][ni][r];
        if (MODE == 0) {
          float* Cp = (float*)C + (size_t)grow*N + gcol;
          if (ACC) v += *Cp;
          *Cp = v;
        } else if (MODE == 2) {
          float* Cp = (float*)C + (size_t)grow*N + gcol;
          if (ACC) v += *Cp;
          *Cp = v + resid[(size_t)grow*N + gcol];
        } else if (MODE == 1) {
          ((__hip_bfloat16*)C)[(size_t)grow*N + gcol] = __float2bfloat16(v);
        } else if (MODE == 3) {
          ((__hip_bfloat16*)C)[(size_t)(moff+grow)*N + gcol] = __float2bfloat16(v);
        } else { // 4
          int rc = moff + grow;
          int tok = ctok[rc], sl = cslot[rc];
          ((__hip_bfloat16*)C)[((size_t)tok*2 + sl)*N + gcol] = __float2bfloat16(cwt[rc]*v);
        }
      }
    }
  }
}

// 3-phase split-bf16 GEMM in one dispatch: C = Ahi·Bhi + Ahi·Blo + Alo·Bhi [+resid]
template<int MODE>  // 0: f32 out, 2: f32 out + resid
__global__ __launch_bounds__(256)
void gemm3_k(const __hip_bfloat16* __restrict__ Ahi, const __hip_bfloat16* __restrict__ Alo,
             const __hip_bfloat16* __restrict__ Bhi, const __hip_bfloat16* __restrict__ Blo,
             float* __restrict__ C, int M, int N, int K, const float* __restrict__ resid) {
  int row0 = blockIdx.y * 64;
  int col0 = blockIdx.x * 64;

  __shared__ __attribute__((aligned(16))) short As[64*64];
  __shared__ __attribute__((aligned(16))) short Bs[64*64];
  const int lane = threadIdx.x & 63;
  const int w    = threadIdx.x >> 6;
  const int wr = w >> 1, wc = w & 1;
  const int srow = lane >> 3;
  const int sch  = (lane & 7) ^ (srow & 7);
  const int q = lane >> 4, r16 = lane & 15;

  floatx4 acc[2][2] = {};

  for (int p = 0; p < 3; ++p) {
    const __hip_bfloat16* Ag = ((p==2)? Alo : Ahi) + (size_t)row0 * K;
    const __hip_bfloat16* Bg = ((p==1)? Blo : Bhi) + (size_t)col0 * K;
    for (int k0 = 0; k0 < K; k0 += 64) {
      #pragma unroll
      for (int ii = 0; ii < 2; ++ii) {
        const int inst = w + ii*4;
        const int r = inst*8 + srow;
        async16((char*)As + inst*1024, Ag + (size_t)r*K + (size_t)(k0 + sch*8));
        async16((char*)Bs + inst*1024, Bg + (size_t)r*K + (size_t)(k0 + sch*8));
      }
      __syncthreads();
      #pragma unroll
      for (int kk = 0; kk < 2; ++kk) {
        int slot = kk*4 + q;
        bf16x8 a0 = *(const bf16x8*)((const char*)As + lds_off(wr*32 +      r16, slot));
        bf16x8 a1 = *(const bf16x8*)((const char*)As + lds_off(wr*32 + 16 + r16, slot));
        bf16x8 b0 = *(const bf16x8*)((const char*)Bs + lds_off(wc*32 +      r16, slot));
        bf16x8 b1 = *(const bf16x8*)((const char*)Bs + lds_off(wc*32 + 16 + r16, slot));
        acc[0][0] = __builtin_amdgcn_mfma_f32_16x16x32_bf16(a0, b0, acc[0][0], 0, 0, 0);
        acc[0][1] = __builtin_amdgcn_mfma_f32_16x16x32_bf16(a0, b1, acc[0][1], 0, 0, 0);
        acc[1][0] = __builtin_amdgcn_mfma_f32_16x16x32_bf16(a1, b0, acc[1][0], 0, 0, 0);
        acc[1][1] = __builtin_amdgcn_mfma_f32_16x16x32_bf16(a1, b1, acc[1][1], 0, 0, 0);
      }
      __syncthreads();
    }
  }

  #pragma unroll
  for (int mi = 0; mi < 2; ++mi) {
    #pragma unroll
    for (int r = 0; r < 4; ++r) {
      int grow = row0 + wr*32 + mi*16 + q*4 + r;
      #pragma unroll
      for (int ni = 0; ni < 2; ++ni) {
        int gcol = col0 + wc*32 + ni*16 + r16;
        float v = acc[mi][ni][r];
        if (MODE == 2) v += resid[(size_t)grow*N + gcol];
        C[(size_t)grow*N + gcol] = v;
      }
    }
  }
}

// ================= fused causal dwconv(K=4) + SiLU + (L2 norm for q/k) =================
__global__ void conv_norm_kernel(const float* __restrict__ in,
                                 const float* __restrict__ cq, const float* __restrict__ ck,
                                 const float* __restrict__ cv,
                                 float* __restrict__ qc, float* __restrict__ kc,
                                 float* __restrict__ vc) {
  int tok = blockIdx.x;
  int mode = blockIdx.y;
  const float* w = (mode==0) ? cq : (mode==1) ? ck : cv;
  float* outp    = (mode==0) ? qc : (mode==1) ? kc : vc;
  int colOff = mode << 10;
  int t = threadIdx.x;
  int c0 = t*4;
  int tloc = tok & (Tt-1);

  float wv[4][4];
  #pragma unroll
  for (int i=0;i<4;i++){
    float4 w4 = ((const float4*)w)[c0+i];
    wv[i][0]=w4.x; wv[i][1]=w4.y; wv[i][2]=w4.z; wv[i][3]=w4.w;
  }
  float acc[4] = {0.f,0.f,0.f,0.f};
  #pragma unroll
  for (int j=0;j<Kc;j++){
    int tt = tloc - (Kc-1) + j;
    if (tt >= 0){
      float4 xv = *(const float4*)&in[(size_t)(tok-(Kc-1)+j)*3072 + colOff + c0];
      acc[0] += wv[0][j]*xv.x;
      acc[1] += wv[1][j]*xv.y;
      acc[2] += wv[2][j]*xv.z;
      acc[3] += wv[3][j]*xv.w;
    }
  }
  float val[4];
  #pragma unroll
  for (int i=0;i<4;i++) val[i] = siluf_(acc[i]);
  float scale = 1.f;
  if (mode < 2) {
    float ss = val[0]*val[0]+val[1]*val[1]+val[2]*val[2]+val[3]*val[3];
    ss += __shfl_xor(ss, 1, 64);
    ss += __shfl_xor(ss, 2, 64);
    ss += __shfl_xor(ss, 4, 64);
    ss += __shfl_xor(ss, 8, 64);
    scale = rsqrtf(ss/(float)Dd + 1e-6f) * ((mode==0) ? (1.f/64.f) : 0.125f);
  }
  float4 o4 = make_float4(val[0]*scale, val[1]*scale, val[2]*scale, val[3]*scale);
  *(float4*)&outp[(size_t)tok*Pp + c0] = o4;
}

// ================= g = exp(-exp(A_log)*softplus(a + dt_bias)) =================
__global__ void g_kernel(float* __restrict__ a, const float* __restrict__ A_log,
                         const float* __restrict__ dt_bias) {
  int idx = blockIdx.x*256 + threadIdx.x;
  if (idx >= Ntok*Pp) return;
  int d = idx & 63;
  int hh = (idx >> 6) & 15;
  float v = a[idx] + dt_bias[hh*Dd + d];
  float sp = (v > 20.f) ? v : log1pf(expf(v));
  a[idx] = expf(-expf(A_log[hh]) * sp);
}

// ================= beta = sigmoid(xn @ bp), N=16 =================
__global__ void beta_kernel(const __hip_bfloat16* __restrict__ xn, const float* __restrict__ bp,
                            float* __restrict__ betab) {
  int row = blockIdx.x;
  int t = threadIdx.x;
  int n = t & 15, ch = t >> 4;
  float s = 0.f;
  for (int k = ch*64; k < ch*64+64; ++k)
    s += bf2f(xn[(size_t)row*HIDD + k]) * bp[k*16 + n];
  __shared__ float red[256];
  red[t] = s; __syncthreads();
  if (t < 16) {
    float tot = 0.f;
    #pragma unroll
    for (int c2 = 0; c2 < 16; ++c2) tot += red[c2*16 + t];
    betab[(size_t)row*16 + t] = sigmoidf_(tot);
  }
}

// ================= router logits fp32 from hbuf (fused rms) =================
__global__ void router_scores_kernel(const float* __restrict__ h, const float* __restrict__ w2,
                                     const float* __restrict__ gw, float* __restrict__ scores) {
  int row = blockIdx.x;
  const float* hr = h + (size_t)row*HIDD;
  float s = 0.f;
  for (int i = threadIdx.x; i < HIDD; i += 256){ float v = hr[i]; s += v*v; }
  #pragma unroll
  for (int off=32; off; off>>=1) s += __shfl_down(s, off, 64);
  __shared__ float red[4];
  if ((threadIdx.x & 63)==0) red[threadIdx.x>>6] = s;
  __syncthreads();
  float sc = rsqrtf((red[0]+red[1]+red[2]+red[3])/(float)HIDD + 1e-5f);
  float acc[Ee] = {};
  for (int i = threadIdx.x; i < HIDD; i += 256){
    float xv = hr[i]*sc*w2[i];
    #pragma unroll
    for (int e=0;e<Ee;e++) acc[e] += xv*gw[i*Ee+e];
  }
  #pragma unroll
  for (int e=0;e<Ee;e++){
    #pragma unroll
    for (int off=32; off; off>>=1) acc[e] += __shfl_down(acc[e], off, 64);
  }
  __shared__ float red2[4][Ee];
  if ((threadIdx.x & 63)==0){
    #pragma unroll
    for (int e=0;e<Ee;e++) red2[threadIdx.x>>6][e] = acc[e];
  }
  __syncthreads();
  if (threadIdx.x < Ee)
    scores[(size_t)row*Ee + threadIdx.x] =
      red2[0][threadIdx.x]+red2[1][threadIdx.x]+red2[2][threadIdx.x]+red2[3][threadIdx.x];
}

// ================= delta-rule scan v5: vsplit=16, 512 blocks, S[4]/lane =================
// block = (b, hh, vb): v-cols [vb*4, vb*4+4). lane = vi*16 + kq: kq in [0,16) k-slice
// (k = kq*4+j), vi in [0,4) v col. Reduction over kq = 4 DPP adds (VALU pipe).
__global__ __launch_bounds__(64)
void scan_kernel(const float* __restrict__ q, const float* __restrict__ k,
                 const float* __restrict__ v, const float* __restrict__ g,
                 const float* __restrict__ beta, float* __restrict__ o) {
  const int vb = blockIdx.x & 15;
  const int hh = (blockIdx.x >> 4) & 15;
  const int b  = blockIdx.x >> 8;
  const int lane = threadIdx.x;
  const int kq = lane & 15;
  const int vi = lane >> 4;
  const int v0 = vb*4;
  const int rb = b*Tt;

  __shared__ __attribute__((aligned(16))) float sq[2][CH][64];
  __shared__ __attribute__((aligned(16))) float sk[2][CH][64];
  __shared__ __attribute__((aligned(16))) float sg[2][CH][64];
  __shared__ __attribute__((aligned(16))) float sbv[Tt][4];
  __shared__ float sb[Tt];

  // stage all v up front: sbv[t][0..4) <- v[rb+t][hh*64+v0 .. +4)  (8 async16)
  #pragma unroll
  for (int i=0;i<Tt/64;i++)
    async16(&sbv[i*64][0], v + (size_t)(rb + i*64 + lane)*Pp + hh*64 + v0);
  // beta for all steps
  #pragma unroll
  for (int i=0;i<Tt/64;i++)
    sb[i*64+lane] = beta[(size_t)(rb + i*64 + lane)*Hh + hh];

  auto stage = [&](int t0, int pb) {
    const int srow = lane >> 4, sch4 = (lane & 15)*4;
    #pragma unroll
    for (int ii=0; ii<4; ++ii) {
      size_t gbase = (size_t)(rb + t0 + ii*4 + srow)*Pp + hh*64;
      async16(&sq[pb][ii*4][0], q + gbase + sch4);
      async16(&sk[pb][ii*4][0], k + gbase + sch4);
      async16(&sg[pb][ii*4][0], g + gbase + sch4);
    }
  };

  float S0=0.f, S1=0.f, S2=0.f, S3=0.f;

  stage(0, 0);
  asm volatile("s_waitcnt vmcnt(0)" ::: "memory");

  for (int c=0; c<NCH; ++c) {
    int pb = c & 1;
    if (c+1 < NCH) {
      stage((c+1)*CH, pb^1);
      asm volatile("s_waitcnt vmcnt(12)" ::: "memory");   // stage(c) fully landed
    } else {
      asm volatile("s_waitcnt vmcnt(0)" ::: "memory");
    }
    __builtin_amdgcn_sched_barrier(0);
    #pragma unroll
    for (int i=0;i<CH;i++){
      int t = c*CH + i;
      float4 k4 = *(const float4*)&sk[pb][i][kq*4];
      float4 g4 = *(const float4*)&sg[pb][i][kq*4];
      float4 q4 = *(const float4*)&sq[pb][i][kq*4];
      float vv = sbv[t][vi];
      float bt = sb[t];
      S0 *= g4.x; S1 *= g4.y; S2 *= g4.z; S3 *= g4.w;
      float pred = S0*k4.x + S1*k4.y + S2*k4.z + S3*k4.w;
      pred = dpp_add<0xB1>(pred);       // + lane^1
      pred = dpp_add<0x4E>(pred);       // + lane^2
      pred = dpp_add<0x141>(pred);      // row_half_mirror: sum over 8
      pred = dpp_add<0x140>(pred);      // row_mirror: sum over 16
      float upd = (vv - pred) * bt;
      S0 += k4.x*upd; S1 += k4.y*upd; S2 += k4.z*upd; S3 += k4.w*upd;
      float acc = S0*q4.x + S1*q4.y + S2*q4.z + S3*q4.w;
      acc = dpp_add<0xB1>(acc);
      acc = dpp_add<0x4E>(acc);
      acc = dpp_add<0x141>(acc);
      acc = dpp_add<0x140>(acc);
      if (kq == 0) o[(size_t)(rb+t)*Pp + hh*64 + v0 + vi] = acc;
    }
  }
}

// ================= o = rms(o)*w*sigmoid(gate) -> split hi/lo bf16 =================
__global__ void onorm_gate_split_kernel(const float* __restrict__ o, const float* __restrict__ w,
                                        const float* __restrict__ gate,
                                        __hip_bfloat16* __restrict__ hi, __hip_bfloat16* __restrict__ lo) {
  int row = blockIdx.x*4 + (threadIdx.x>>6);
  int lane = threadIdx.x & 63;
  size_t idx = (size_t)row*Dd + lane;
  float v = o[idx];
  float s = v*v;
  #pragma unroll
  for (int off=32; off; off>>=1) s += __shfl_xor(s, off, 64);
  float r = v * rsqrtf(s/(float)Dd + 1e-5f) * w[lane] * sigmoidf_(gate[idx]);
  __hip_bfloat16 h = __float2bfloat16(r);
  hi[idx] = h;
  lo[idx] = __float2bfloat16(r - bf2f(h));
}

// ================= router top-2 =================
__global__ void router_kernel(const float* __restrict__ logits, const float* __restrict__ gate_b,
                              int* __restrict__ counts, int* __restrict__ tok_list,
                              int* __restrict__ slot_list, float* __restrict__ wt_list) {
  int n = blockIdx.x*256 + threadIdx.x;
  if (n >= Ntok) return;
  float sc[Ee], bi[Ee];
  #pragma unroll
  for (int e=0;e<Ee;e++){ float s = sigmoidf_(logits[n*Ee+e]); sc[e]=s; bi[e]=s+gate_b[e]; }
  int i0=0;
  #pragma unroll
  for (int e=1;e<Ee;e++) if (bi[e] > bi[i0]) i0=e;
  int i1=-1;
  #pragma unroll
  for (int e=0;e<Ee;e++){ if (e==i0) continue; if (i1<0 || bi[e] > bi[i1]) i1=e; }
  float w0=sc[i0], w1=sc[i1];
  float inv = 1.f/(w0+w1+1e-20f);
  w0*=inv; w1*=inv;
  int p0 = atomicAdd(&counts[i0],1);
  tok_list[i0*Ntok+p0]=n; slot_list[i0*Ntok+p0]=0; wt_list[i0*Ntok+p0]=w0;
  int p1 = atomicAdd(&counts[i1],1);
  tok_list[i1*Ntok+p1]=n; slot_list[i1*Ntok+p1]=1; wt_list[i1*Ntok+p1]=w1;
}

__global__ void prefix_kernel(const int* __restrict__ counts, int* __restrict__ prefix) {
  if (threadIdx.x==0 && blockIdx.x==0){ int s=0; for (int e=0;e<Ee;e++){ prefix[e]=s; s+=counts[e]; } }
}

__global__ void compact_kernel(const int* __restrict__ counts, const int* __restrict__ prefix,
                               const int* __restrict__ tok_list, const int* __restrict__ slot_list,
                               const float* __restrict__ wt_list,
                               int* __restrict__ ctok, int* __restrict__ cslot, float* __restrict__ cwt) {
  int e = blockIdx.x; int c = counts[e], p = prefix[e];
  for (int i = threadIdx.x; i < c; i += 256) {
    ctok[p+i]  = tok_list[e*Ntok+i];
    cslot[p+i] = slot_list[e*Ntok+i];
    cwt[p+i]   = wt_list[e*Ntok+i];
  }
}

__global__ void gather_kernel(const __hip_bfloat16* __restrict__ hn, const int* __restrict__ ctok,
                              __hip_bfloat16* __restrict__ Ae) {
  int r = blockIdx.x;
  int t = threadIdx.x; // 128
  ((int4*)(Ae + (size_t)r*HIDD))[t] = ((const int4*)(hn + (size_t)ctok[r]*HIDD))[t];
}

// ================= GLU: out = silu(gu[:, :768]) * gu[:, 768:] =================
__global__ void glu_kernel(const __hip_bfloat16* __restrict__ gu, __hip_bfloat16* __restrict__ outp,
                           int rows) {
  int idx = blockIdx.x*256 + threadIdx.x;
  if (idx >= rows*Ii) return;
  int r = idx / Ii, c2 = idx - r*Ii;
  float gv = bf2f(gu[(size_t)r*(2*Ii) + c2]);
  float uv = bf2f(gu[(size_t)r*(2*Ii) + Ii + c2]);
  outp[idx] = __float2bfloat16(siluf_(gv)*uv);
}

__global__ void final_kernel(const float* __restrict__ h, const __hip_bfloat16* __restrict__ routed,
                             const float* __restrict__ shr, float* __restrict__ out) {
  int idx = blockIdx.x*256 + threadIdx.x;
  if (idx >= Ntok*HIDD) return;
  int n = idx >> 10, c = idx & 1023;
  out[idx] = h[idx] + bf2f(routed[(size_t)n*2*HIDD + c]) + bf2f(routed[(size_t)n*2*HIDD + HIDD + c]) + shr[idx];
}

// ---------------------------------------------------------------------------
extern "C" void kernel_launch(void* const* d_in, const int* in_sizes, int n_in,
                              void* d_out, int out_size, void* d_ws, size_t ws_size,
                              hipStream_t stream) {
  (void)in_sizes; (void)n_in; (void)out_size; (void)ws_size;
  const float* x        = (const float*)d_in[0];
  const float* norm1_w  = (const float*)d_in[1];
  const float* wq       = (const float*)d_in[2];
  const float* wk       = (const float*)d_in[3];
  const float* wv       = (const float*)d_in[4];
  const float* cq       = (const float*)d_in[5];
  const float* ck       = (const float*)d_in[6];
  const float* cv       = (const float*)d_in[7];
  const float* fa       = (const float*)d_in[8];
  const float* fb       = (const float*)d_in[9];
  const float* bp       = (const float*)d_in[10];
  const float* ga       = (const float*)d_in[11];
  const float* gb       = (const float*)d_in[12];
  const float* A_log    = (const float*)d_in[13];
  const float* dt_bias  = (const float*)d_in[14];
  const float* onorm_w  = (const float*)d_in[15];
  const float* wo       = (const float*)d_in[16];
  const float* norm2_w  = (const float*)d_in[17];
  const float* gate_w   = (const float*)d_in[18];
  const float* gate_b   = (const float*)d_in[19];
  const float* wg_e     = (const float*)d_in[20];
  const float* wu_e     = (const float*)d_in[21];
  const float* wd_e     = (const float*)d_in[22];
  const float* wg_s     = (const float*)d_in[23];
  const float* wu_s     = (const float*)d_in[24];
  const float* wd_s     = (const float*)d_in[25];
  float* out = (float*)d_out;

  char* base = (char*)d_ws;
  size_t off = 0;
  auto alloc = [&](size_t bytes)->char* {
    off = (off + 255) & ~(size_t)255;
    char* p = base + off; off += bytes; return p;
  };
  float* hbuf = (float*)alloc((size_t)Ntok*HIDD*4);
  size_t uStart = (off + 255) & ~(size_t)255;

  // ---- attention view ----
  off = uStart;
  __hip_bfloat16* xn      = (__hip_bfloat16*)alloc((size_t)Ntok*HIDD*2);
  __hip_bfloat16* xn_lo   = (__hip_bfloat16*)alloc((size_t)Ntok*HIDD*2);
  __hip_bfloat16* wqkv_t  = (__hip_bfloat16*)alloc((size_t)3*Pp*HIDD*2);
  __hip_bfloat16* wqkv_lo = (__hip_bfloat16*)alloc((size_t)3*Pp*HIDD*2);
  float*          qkvlin  = (float*)alloc((size_t)Ntok*3*Pp*4);
  float*          qc      = (float*)alloc((size_t)Ntok*Pp*4);
  float*          kc      = (float*)alloc((size_t)Ntok*Pp*4);
  float*          vc      = (float*)alloc((size_t)Ntok*Pp*4);
  float*          gbuf    = (float*)alloc((size_t)Ntok*Pp*4);
  float*          gatebuf = (float*)alloc((size_t)Ntok*Pp*4);
  float*          obuf    = (float*)alloc((size_t)Ntok*Pp*4);
  __hip_bfloat16* atmp12  = (__hip_bfloat16*)alloc((size_t)Ntok*2*Dd*2);
  float*          betab   = (float*)alloc((size_t)Ntok*Hh*4);
  __hip_bfloat16* obuf_hi = (__hip_bfloat16*)alloc((size_t)Ntok*Pp*2);
  __hip_bfloat16* obuf_lo = (__hip_bfloat16*)alloc((size_t)Ntok*Pp*2);
  __hip_bfloat16* wo_t    = (__hip_bfloat16*)alloc((size_t)HIDD*Pp*2);
  __hip_bfloat16* wo_lo   = (__hip_bfloat16*)alloc((size_t)HIDD*Pp*2);
  __hip_bfloat16* fg_t    = (__hip_bfloat16*)alloc((size_t)2*Dd*HIDD*2);
  __hip_bfloat16* fb_t    = (__hip_bfloat16*)alloc((size_t)Pp*Dd*2);
  __hip_bfloat16* gb_t    = (__hip_bfloat16*)alloc((size_t)Pp*Dd*2);

  // ---- moe view (overlaps attention view) ----
  off = uStart;
  __hip_bfloat16* hn      = (__hip_bfloat16*)alloc((size_t)Ntok*HIDD*2);
  float*          scores  = (float*)alloc((size_t)Ntok*Ee*4);
  int*            counts  = (int*)alloc(64);
  int*            prefix  = (int*)alloc(64);
  int*            tok_list  = (int*)alloc((size_t)Ee*Ntok*4);
  int*            slot_list = (int*)alloc((size_t)Ee*Ntok*4);
  float*          wt_list   = (float*)alloc((size_t)Ee*Ntok*4);
  int*            ctok    = (int*)alloc((size_t)NPAD*4);
  int*            cslot   = (int*)alloc((size_t)NPAD*4);
  float*          cwt     = (float*)alloc((size_t)NPAD*4);
  __hip_bfloat16* egu_t   = (__hip_bfloat16*)alloc((size_t)Ee*2*Ii*HIDD*2);
  __hip_bfloat16* sgu_t   = (__hip_bfloat16*)alloc((size_t)2*ISs*HIDD*2);
  __hip_bfloat16* sd_t    = (__hip_bfloat16*)alloc((size_t)HIDD*ISs*2);
  __hip_bfloat16* act     = (__hip_bfloat16*)alloc((size_t)NPAD*Ii*2);
  __hip_bfloat16* sgu_raw = (__hip_bfloat16*)alloc((size_t)Ntok*2*ISs*2);
  __hip_bfloat16* sgb     = (__hip_bfloat16*)alloc((size_t)Ntok*ISs*2);
  __hip_bfloat16* routed  = (__hip_bfloat16*)alloc((size_t)Ntok*2*HIDD*2);
  float*          shout   = (float*)alloc((size_t)Ntok*HIDD*4);
  size_t xStart = (off + 255) & ~(size_t)255;
  off = xStart;
  __hip_bfloat16* Ae      = (__hip_bfloat16*)alloc((size_t)NPAD*HIDD*2);
  __hip_bfloat16* actg    = (__hip_bfloat16*)alloc((size_t)NPAD*2*Ii*2);
  off = xStart;
  __hip_bfloat16* ed_t    = (__hip_bfloat16*)alloc((size_t)Ee*HIDD*Ii*2);

  dim3 blk(256);
  const int nelem = Ntok*Pp;
  #define NO5 nullptr, nullptr, nullptr, nullptr, nullptr

  // ================= attention =================
  rms_split_kernel<<<Ntok, blk, 0, stream>>>(x, norm1_w, xn, xn_lo, 1e-5f);
  trans_split_kernel<<<dim3(32,32,1), blk, 0, stream>>>(wq, wqkv_t, wqkv_lo, HIDD, Pp);
  trans_split_kernel<<<dim3(32,32,1), blk, 0, stream>>>(wk, wqkv_t + (size_t)Pp*HIDD,
                                                        wqkv_lo + (size_t)Pp*HIDD, HIDD, Pp);
  trans_split_kernel<<<dim3(32,32,1), blk, 0, stream>>>(wv, wqkv_t + (size_t)2*Pp*HIDD,
                                                        wqkv_lo + (size_t)2*Pp*HIDD, HIDD, Pp);
  trans_split_kernel<<<dim3(32,32,1), blk, 0, stream>>>(wo, wo_t, wo_lo, Pp, HIDD);
  trans_kernel<<<dim3(2,32,1),  blk, 0, stream>>>(fa, fg_t, HIDD, Dd, 0, 0);
  trans_kernel<<<dim3(2,32,1),  blk, 0, stream>>>(ga, fg_t + (size_t)Dd*HIDD, HIDD, Dd, 0, 0);
  trans_kernel<<<dim3(32,2,1),  blk, 0, stream>>>(fb, fb_t, Dd, Pp, 0, 0);
  trans_kernel<<<dim3(32,2,1),  blk, 0, stream>>>(gb, gb_t, Dd, Pp, 0, 0);

  gemm3_k<0><<<dim3(48,16,1), blk, 0, stream>>>(xn, xn_lo, wqkv_t, wqkv_lo, qkvlin,
                                                Ntok, 3*Pp, HIDD, nullptr);
  conv_norm_kernel<<<dim3(Ntok,3,1), blk, 0, stream>>>(qkvlin, cq, ck, cv, qc, kc, vc);
  gemm_k<1,0><<<dim3(2,16,1), blk, 0, stream>>>(xn, fg_t, atmp12, Ntok, 2*Dd, HIDD, HIDD, NO5, nullptr);
  gemm_k<0,0><<<dim3(16,16,1), blk, 0, stream>>>(atmp12, fb_t, gbuf, Ntok, Pp, Dd, 2*Dd, NO5, nullptr);
  gemm_k<0,0><<<dim3(16,16,1), blk, 0, stream>>>(atmp12+Dd, gb_t, gatebuf, Ntok, Pp, Dd, 2*Dd, NO5, nullptr);
  g_kernel<<<(nelem+255)/256, blk, 0, stream>>>(gbuf, A_log, dt_bias);
  beta_kernel<<<Ntok, blk, 0, stream>>>(xn, bp, betab);
  scan_kernel<<<Bb*Hh*16, dim3(64), 0, stream>>>(qc, kc, vc, gbuf, betab, obuf);
  onorm_gate_split_kernel<<<(Ntok*Hh)/4, blk, 0, stream>>>(obuf, onorm_w, gatebuf, obuf_hi, obuf_lo);
  gemm3_k<2><<<dim3(16,16,1), blk, 0, stream>>>(obuf_hi, obuf_lo, wo_t, wo_lo, hbuf,
                                                Ntok, HIDD, Pp, x);

  // ================= MoE =================
  rms_bf16_kernel<<<Ntok, blk, 0, stream>>>(hbuf, norm2_w, hn, 1e-5f);
  router_scores_kernel<<<Ntok, blk, 0, stream>>>(hbuf, norm2_w, gate_w, scores);
  hipMemsetAsync(counts, 0, Ee*sizeof(int), stream);
  router_kernel<<<(Ntok+255)/256, blk, 0, stream>>>(scores, gate_b, counts, tok_list, slot_list, wt_list);
  prefix_kernel<<<1, 64, 0, stream>>>(counts, prefix);
  compact_kernel<<<Ee, blk, 0, stream>>>(counts, prefix, tok_list, slot_list, wt_list, ctok, cslot, cwt);
  gather_kernel<<<NASSIGN, dim3(128), 0, stream>>>(hn, ctok, Ae);
  trans_kernel<<<dim3(24,32,Ee), blk, 0, stream>>>(wg_e, egu_t,
      HIDD, Ii, (long)HIDD*Ii, (long)2*Ii*HIDD);
  trans_kernel<<<dim3(24,32,Ee), blk, 0, stream>>>(wu_e, egu_t + (size_t)Ii*HIDD,
      HIDD, Ii, (long)HIDD*Ii, (long)2*Ii*HIDD);
  gemm_k<3,0><<<dim3(24,16,Ee), blk, 0, stream>>>(Ae, egu_t, actg, Ntok, 2*Ii, HIDD, HIDD,
                                                  nullptr, counts, prefix, nullptr, nullptr, nullptr);
  glu_kernel<<<(NASSIGN*Ii+255)/256, blk, 0, stream>>>(actg, act, NASSIGN);
  trans_kernel<<<dim3(32,24,Ee), blk, 0, stream>>>(wd_e, ed_t,
      Ii, HIDD, (long)Ii*HIDD, (long)HIDD*Ii);
  gemm_k<4,0><<<dim3(16,16,Ee), blk, 0, stream>>>(act, ed_t, routed, Ntok, HIDD, Ii, Ii,
                                                  nullptr, counts, prefix, ctok, cslot, cwt);
  trans_kernel<<<dim3(24,32,1), blk, 0, stream>>>(wg_s, sgu_t, HIDD, ISs, 0, 0);
  trans_kernel<<<dim3(24,32,1), blk, 0, stream>>>(wu_s, sgu_t + (size_t)ISs*HIDD, HIDD, ISs, 0, 0);
  trans_kernel<<<dim3(32,24,1), blk, 0, stream>>>(wd_s, sd_t, ISs, HIDD, 0, 0);
  gemm_k<1,0><<<dim3(24,16,1), blk, 0, stream>>>(hn, sgu_t, sgu_raw, Ntok, 2*ISs, HIDD, HIDD, NO5, nullptr);
  glu_kernel<<<(Ntok*ISs+255)/256, blk, 0, stream>>>(sgu_raw, sgb, Ntok);
  gemm_k<0,0><<<dim3(16,16,1), blk, 0, stream>>>(sgb, sd_t, shout, Ntok, HIDD, ISs, ISs, NO5, nullptr);

  final_kernel<<<(Ntok*HIDD+255)/256, blk, 0, stream>>>(hbuf, routed, shout, out);
}

// Round 8
// 356.707 us; speedup vs baseline: 9.8410x; 1.0498x over previous
//
#include <hip/hip_runtime.h>
#include <hip/hip_bf16.h>
#include <math.h>

#define Bb 2
#define Tt 512
#define HIDD 1024
#define Hh 16
#define Dd 64
#define Pp 1024
#define Kc 4
#define Ee 8
#define Ii 768
#define ISs 768
#define Ntok (Bb*Tt)   // 1024
#define NASSIGN (2*Ntok)
#define NPAD 2112
#define CH 16
#define NCH (Tt/CH)

typedef __attribute__((ext_vector_type(8))) short bf16x8;
typedef __attribute__((ext_vector_type(4))) float floatx4;

__device__ __forceinline__ float sigmoidf_(float x){ return 1.f/(1.f+expf(-x)); }
__device__ __forceinline__ float siluf_(float x){ return x/(1.f+expf(-x)); }
__device__ __forceinline__ float bf2f(__hip_bfloat16 b){ return __bfloat162float(b); }

__device__ __forceinline__ void async16(void* lds, const void* g) {
  __builtin_amdgcn_global_load_lds(
      (const __attribute__((address_space(1))) void*)g,
      (__attribute__((address_space(3))) void*)lds, 16, 0, 0);
}

template<int CTRL>
__device__ __forceinline__ float dpp_add(float x){
  int y = __builtin_amdgcn_update_dpp(0, __float_as_int(x), CTRL, 0xF, 0xF, true);
  return x + __int_as_float(y);
}

// ================= RMS norm (fp32 in, split hi/lo bf16 out) =================
__global__ void rms_split_kernel(const float* __restrict__ x, const float* __restrict__ w,
                                 __hip_bfloat16* __restrict__ hi, __hip_bfloat16* __restrict__ lo,
                                 float eps) {
  int row = blockIdx.x;
  const float* xr = x + (size_t)row*HIDD;
  float s = 0.f;
  for (int i = threadIdx.x; i < HIDD; i += 256){ float v = xr[i]; s += v*v; }
  #pragma unroll
  for (int off=32; off; off>>=1) s += __shfl_down(s, off, 64);
  __shared__ float red[4];
  if ((threadIdx.x & 63)==0) red[threadIdx.x>>6] = s;
  __syncthreads();
  float tot = red[0]+red[1]+red[2]+red[3];
  float sc = rsqrtf(tot/(float)HIDD + eps);
  for (int i = threadIdx.x; i < HIDD; i += 256) {
    float v = xr[i]*sc*w[i];
    __hip_bfloat16 h = __float2bfloat16(v);
    hi[(size_t)row*HIDD+i] = h;
    lo[(size_t)row*HIDD+i] = __float2bfloat16(v - bf2f(h));
  }
}

// ================= batched split transpose: wq/wk/wv/wo in one dispatch =================
__global__ void trans_split4_kernel(const float* __restrict__ wq, const float* __restrict__ wk,
                                    const float* __restrict__ wv, const float* __restrict__ wo,
                                    __hip_bfloat16* __restrict__ qkv_hi, __hip_bfloat16* __restrict__ qkv_lo,
                                    __hip_bfloat16* __restrict__ wo_hi, __hip_bfloat16* __restrict__ wo_lo) {
  int z = blockIdx.z;
  const float* src = (z==0)?wq:(z==1)?wk:(z==2)?wv:wo;
  __hip_bfloat16* hi = (z<3) ? qkv_hi + (size_t)z*Pp*HIDD : wo_hi;
  __hip_bfloat16* lo = (z<3) ? qkv_lo + (size_t)z*Pp*HIDD : wo_lo;
  __shared__ float tile[32][33];
  int n0 = blockIdx.x*32, k0 = blockIdx.y*32;
  int tx = threadIdx.x & 31, ty0 = threadIdx.x >> 5;
  #pragma unroll
  for (int j=0;j<4;j++){ int ty = ty0 + j*8; tile[ty][tx] = src[(size_t)(k0+ty)*1024 + n0+tx]; }
  __syncthreads();
  #pragma unroll
  for (int j=0;j<4;j++){
    int ty = ty0 + j*8;
    float v = tile[tx][ty];
    __hip_bfloat16 h = __float2bfloat16(v);
    hi[(size_t)(n0+ty)*1024 + k0+tx] = h;
    lo[(size_t)(n0+ty)*1024 + k0+tx] = __float2bfloat16(v - bf2f(h));
  }
}

// ================= plain transpose (z-batched over experts) =================
__global__ void trans_kernel(const float* __restrict__ src, __hip_bfloat16* __restrict__ dst,
                             int K, int N, long sbs, long dbs) {
  src += (size_t)blockIdx.z * sbs; dst += (size_t)blockIdx.z * dbs;
  __shared__ float tile[32][33];
  int n0 = blockIdx.x*32, k0 = blockIdx.y*32;
  int tx = threadIdx.x & 31, ty0 = threadIdx.x >> 5;
  #pragma unroll
  for (int j=0;j<4;j++){ int ty = ty0 + j*8; tile[ty][tx] = src[(size_t)(k0+ty)*N + n0+tx]; }
  __syncthreads();
  #pragma unroll
  for (int j=0;j<4;j++){ int ty = ty0 + j*8; dst[(size_t)(n0+ty)*K + k0+tx] = __float2bfloat16(tile[tx][ty]); }
}

// ================= pair transpose: z picks (srcA->dstA) or (srcB->dstB) =================
__global__ void trans_pair_kernel(const float* __restrict__ a, const float* __restrict__ b2,
                                  __hip_bfloat16* __restrict__ da, __hip_bfloat16* __restrict__ db,
                                  int K, int N) {
  const float* src = blockIdx.z ? b2 : a;
  __hip_bfloat16* dst = blockIdx.z ? db : da;
  __shared__ float tile[32][33];
  int n0 = blockIdx.x*32, k0 = blockIdx.y*32;
  int tx = threadIdx.x & 31, ty0 = threadIdx.x >> 5;
  #pragma unroll
  for (int j=0;j<4;j++){ int ty = ty0 + j*8; tile[ty][tx] = src[(size_t)(k0+ty)*N + n0+tx]; }
  __syncthreads();
  #pragma unroll
  for (int j=0;j<4;j++){ int ty = ty0 + j*8; dst[(size_t)(n0+ty)*K + k0+tx] = __float2bfloat16(tile[tx][ty]); }
}

// ====== interleaved transpose: dst[(2n+phase)][k] <- src_phase[k][n]; z = e*2+phase ======
__global__ void trans_inter_kernel(const float* __restrict__ sa, const float* __restrict__ sb2,
                                   __hip_bfloat16* __restrict__ dst, int K, int N,
                                   long sbs, long dbs) {
  int e = blockIdx.z >> 1, phase = blockIdx.z & 1;
  const float* src = (phase ? sb2 : sa) + (size_t)e*sbs;
  dst += (size_t)e*dbs;
  __shared__ float tile[32][33];
  int n0 = blockIdx.x*32, k0 = blockIdx.y*32;
  int tx = threadIdx.x & 31, ty0 = threadIdx.x >> 5;
  #pragma unroll
  for (int j=0;j<4;j++){ int ty = ty0 + j*8; tile[ty][tx] = src[(size_t)(k0+ty)*N + n0+tx]; }
  __syncthreads();
  #pragma unroll
  for (int j=0;j<4;j++){
    int ty = ty0 + j*8;
    dst[(size_t)(2*(n0+ty)+phase)*K + k0+tx] = __float2bfloat16(tile[tx][ty]);
  }
}

// ================= MFMA GEMM core =================
__device__ __forceinline__ int lds_off(int row, int slot){
  return row*128 + (((slot ^ row)&7)<<4);
}

// MODE 0: f32 out. 1: bf16 out. 2: f32 + resid. 3: expert compact bf16.
// 4: expert scatter with weight. 5: f32 g-transform (resid=A_log, cwt=dt_bias).
// 6: expert compact GLU (interleaved pairs, out N/2 bf16). 7: plain GLU (out N/2 bf16).
template<int MODE, int ACC>
__global__ __launch_bounds__(256)
void gemm_k(const __hip_bfloat16* __restrict__ A, const __hip_bfloat16* __restrict__ BT,
            void* __restrict__ C, int M, int N, int K, int lda, const float* __restrict__ resid,
            const int* __restrict__ counts, const int* __restrict__ prefix,
            const int* __restrict__ ctok, const int* __restrict__ cslot,
            const float* __restrict__ cwt) {
  int Me = M;
  int moff = 0;
  if (MODE == 3 || MODE == 4 || MODE == 6) {
    int e = blockIdx.z;
    Me = counts[e]; moff = prefix[e];
    A  += (size_t)moff * lda;
    BT += (size_t)e * (size_t)N * K;
  }
  int row0 = blockIdx.y * 64;
  if (row0 >= Me) return;
  int col0 = blockIdx.x * 64;

  __shared__ __attribute__((aligned(16))) short As[64*64];
  __shared__ __attribute__((aligned(16))) short Bs[64*64];
  const int lane = threadIdx.x & 63;
  const int w    = threadIdx.x >> 6;
  const int wr = w >> 1, wc = w & 1;
  const int srow = lane >> 3;
  const int sch  = (lane & 7) ^ (srow & 7);
  const int q = lane >> 4, r16 = lane & 15;

  const __hip_bfloat16* Ag = A  + (size_t)row0 * lda;
  const __hip_bfloat16* Bg = BT + (size_t)col0 * K;

  floatx4 acc[2][2] = {};

  for (int k0 = 0; k0 < K; k0 += 64) {
    #pragma unroll
    for (int ii = 0; ii < 2; ++ii) {
      const int inst = w + ii*4;
      const int r = inst*8 + srow;
      async16((char*)As + inst*1024, Ag + (size_t)r*lda + (size_t)(k0 + sch*8));
      async16((char*)Bs + inst*1024, Bg + (size_t)r*K   + (size_t)(k0 + sch*8));
    }
    __syncthreads();
    #pragma unroll
    for (int kk = 0; kk < 2; ++kk) {
      int slot = kk*4 + q;
      bf16x8 a0 = *(const bf16x8*)((const char*)As + lds_off(wr*32 +      r16, slot));
      bf16x8 a1 = *(const bf16x8*)((const char*)As + lds_off(wr*32 + 16 + r16, slot));
      bf16x8 b0 = *(const bf16x8*)((const char*)Bs + lds_off(wc*32 +      r16, slot));
      bf16x8 b1 = *(const bf16x8*)((const char*)Bs + lds_off(wc*32 + 16 + r16, slot));
      acc[0][0] = __builtin_amdgcn_mfma_f32_16x16x32_bf16(a0, b0, acc[0][0], 0, 0, 0);
      acc[0][1] = __builtin_amdgcn_mfma_f32_16x16x32_bf16(a0, b1, acc[0][1], 0, 0, 0);
      acc[1][0] = __builtin_amdgcn_mfma_f32_16x16x32_bf16(a1, b0, acc[1][0], 0, 0, 0);
      acc[1][1] = __builtin_amdgcn_mfma_f32_16x16x32_bf16(a1, b1, acc[1][1], 0, 0, 0);
    }
    __syncthreads();
  }

  #pragma unroll
  for (int mi = 0; mi < 2; ++mi) {
    #pragma unroll
    for (int r = 0; r < 4; ++r) {
      int grow = row0 + wr*32 + mi*16 + q*4 + r;
      if (grow >= Me) continue;
      #pragma unroll
      for (int ni = 0; ni < 2; ++ni) {
        int gcol = col0 + wc*32 + ni*16 + r16;
        float v = acc[mi][ni][r];
        if (MODE == 0) {
          float* Cp = (float*)C + (size_t)grow*N + gcol;
          if (ACC) v += *Cp;
          *Cp = v;
        } else if (MODE == 2) {
          float* Cp = (float*)C + (size_t)grow*N + gcol;
          if (ACC) v += *Cp;
          *Cp = v + resid[(size_t)grow*N + gcol];
        } else if (MODE == 1) {
          ((__hip_bfloat16*)C)[(size_t)grow*N + gcol] = __float2bfloat16(v);
        } else if (MODE == 3) {
          ((__hip_bfloat16*)C)[(size_t)(moff+grow)*N + gcol] = __float2bfloat16(v);
        } else if (MODE == 4) {
          int rc = moff + grow;
          int tok = ctok[rc], sl = cslot[rc];
          ((__hip_bfloat16*)C)[((size_t)tok*2 + sl)*N + gcol] = __float2bfloat16(cwt[rc]*v);
        } else if (MODE == 5) {
          int hh2 = gcol >> 6, d2 = gcol & 63;
          float t2 = v + cwt[hh2*64 + d2];
          float sp = (t2 > 20.f) ? t2 : log1pf(expf(t2));
          ((float*)C)[(size_t)grow*N + gcol] = expf(-expf(resid[hh2]) * sp);
        } else { // 6 or 7: GLU over interleaved pairs
          float pv = __shfl_xor(v, 1, 64);
          if ((lane & 1) == 0) {
            float rglu = siluf_(v) * pv;
            int pcol = gcol >> 1;
            size_t orow = (MODE == 6) ? (size_t)(moff + grow) : (size_t)grow;
            ((__hip_bfloat16*)C)[orow*(N/2) + pcol] = __float2bfloat16(rglu);
          }
        }
      }
    }
  }
}

// 3-phase split-bf16 GEMM: C = Ahi·Bhi + Ahi·Blo + Alo·Bhi [+resid]
template<int MODE>  // 0: f32 out, 2: f32 out + resid
__global__ __launch_bounds__(256)
void gemm3_k(const __hip_bfloat16* __restrict__ Ahi, const __hip_bfloat16* __restrict__ Alo,
             const __hip_bfloat16* __restrict__ Bhi, const __hip_bfloat16* __restrict__ Blo,
             float* __restrict__ C, int M, int N, int K, const float* __restrict__ resid) {
  int row0 = blockIdx.y * 64;
  int col0 = blockIdx.x * 64;

  __shared__ __attribute__((aligned(16))) short As[64*64];
  __shared__ __attribute__((aligned(16))) short Bs[64*64];
  const int lane = threadIdx.x & 63;
  const int w    = threadIdx.x >> 6;
  const int wr = w >> 1, wc = w & 1;
  const int srow = lane >> 3;
  const int sch  = (lane & 7) ^ (srow & 7);
  const int q = lane >> 4, r16 = lane & 15;

  floatx4 acc[2][2] = {};

  for (int p = 0; p < 3; ++p) {
    const __hip_bfloat16* Ag = ((p==2)? Alo : Ahi) + (size_t)row0 * K;
    const __hip_bfloat16* Bg = ((p==1)? Blo : Bhi) + (size_t)col0 * K;
    for (int k0 = 0; k0 < K; k0 += 64) {
      #pragma unroll
      for (int ii = 0; ii < 2; ++ii) {
        const int inst = w + ii*4;
        const int r = inst*8 + srow;
        async16((char*)As + inst*1024, Ag + (size_t)r*K + (size_t)(k0 + sch*8));
        async16((char*)Bs + inst*1024, Bg + (size_t)r*K + (size_t)(k0 + sch*8));
      }
      __syncthreads();
      #pragma unroll
      for (int kk = 0; kk < 2; ++kk) {
        int slot = kk*4 + q;
        bf16x8 a0 = *(const bf16x8*)((const char*)As + lds_off(wr*32 +      r16, slot));
        bf16x8 a1 = *(const bf16x8*)((const char*)As + lds_off(wr*32 + 16 + r16, slot));
        bf16x8 b0 = *(const bf16x8*)((const char*)Bs + lds_off(wc*32 +      r16, slot));
        bf16x8 b1 = *(const bf16x8*)((const char*)Bs + lds_off(wc*32 + 16 + r16, slot));
        acc[0][0] = __builtin_amdgcn_mfma_f32_16x16x32_bf16(a0, b0, acc[0][0], 0, 0, 0);
        acc[0][1] = __builtin_amdgcn_mfma_f32_16x16x32_bf16(a0, b1, acc[0][1], 0, 0, 0);
        acc[1][0] = __builtin_amdgcn_mfma_f32_16x16x32_bf16(a1, b0, acc[1][0], 0, 0, 0);
        acc[1][1] = __builtin_amdgcn_mfma_f32_16x16x32_bf16(a1, b1, acc[1][1], 0, 0, 0);
      }
      __syncthreads();
    }
  }

  #pragma unroll
  for (int mi = 0; mi < 2; ++mi) {
    #pragma unroll
    for (int r = 0; r < 4; ++r) {
      int grow = row0 + wr*32 + mi*16 + q*4 + r;
      #pragma unroll
      for (int ni = 0; ni < 2; ++ni) {
        int gcol = col0 + wc*32 + ni*16 + r16;
        float v = acc[mi][ni][r];
        if (MODE == 2) v += resid[(size_t)grow*N + gcol];
        C[(size_t)grow*N + gcol] = v;
      }
    }
  }
}

// ================= fused causal dwconv(K=4) + SiLU + (L2 norm for q/k) =================
__global__ void conv_norm_kernel(const float* __restrict__ in,
                                 const float* __restrict__ cq, const float* __restrict__ ck,
                                 const float* __restrict__ cv,
                                 float* __restrict__ qc, float* __restrict__ kc,
                                 float* __restrict__ vc) {
  int tok = blockIdx.x;
  int mode = blockIdx.y;
  const float* w = (mode==0) ? cq : (mode==1) ? ck : cv;
  float* outp    = (mode==0) ? qc : (mode==1) ? kc : vc;
  int colOff = mode << 10;
  int t = threadIdx.x;
  int c0 = t*4;
  int tloc = tok & (Tt-1);

  float wv[4][4];
  #pragma unroll
  for (int i=0;i<4;i++){
    float4 w4 = ((const float4*)w)[c0+i];
    wv[i][0]=w4.x; wv[i][1]=w4.y; wv[i][2]=w4.z; wv[i][3]=w4.w;
  }
  float acc[4] = {0.f,0.f,0.f,0.f};
  #pragma unroll
  for (int j=0;j<Kc;j++){
    int tt = tloc - (Kc-1) + j;
    if (tt >= 0){
      float4 xv = *(const float4*)&in[(size_t)(tok-(Kc-1)+j)*3072 + colOff + c0];
      acc[0] += wv[0][j]*xv.x;
      acc[1] += wv[1][j]*xv.y;
      acc[2] += wv[2][j]*xv.z;
      acc[3] += wv[3][j]*xv.w;
    }
  }
  float val[4];
  #pragma unroll
  for (int i=0;i<4;i++) val[i] = siluf_(acc[i]);
  float scale = 1.f;
  if (mode < 2) {
    float ss = val[0]*val[0]+val[1]*val[1]+val[2]*val[2]+val[3]*val[3];
    ss += __shfl_xor(ss, 1, 64);
    ss += __shfl_xor(ss, 2, 64);
    ss += __shfl_xor(ss, 4, 64);
    ss += __shfl_xor(ss, 8, 64);
    scale = rsqrtf(ss/(float)Dd + 1e-6f) * ((mode==0) ? (1.f/64.f) : 0.125f);
  }
  float4 o4 = make_float4(val[0]*scale, val[1]*scale, val[2]*scale, val[3]*scale);
  *(float4*)&outp[(size_t)tok*Pp + c0] = o4;
}

// ================= beta = sigmoid(xn @ bp), N=16 =================
__global__ void beta_kernel(const __hip_bfloat16* __restrict__ xn, const float* __restrict__ bp,
                            float* __restrict__ betab) {
  int row = blockIdx.x;
  int t = threadIdx.x;
  int n = t & 15, ch = t >> 4;
  float s = 0.f;
  for (int k = ch*64; k < ch*64+64; ++k)
    s += bf2f(xn[(size_t)row*HIDD + k]) * bp[k*16 + n];
  __shared__ float red[256];
  red[t] = s; __syncthreads();
  if (t < 16) {
    float tot = 0.f;
    #pragma unroll
    for (int c2 = 0; c2 < 16; ++c2) tot += red[c2*16 + t];
    betab[(size_t)row*16 + t] = sigmoidf_(tot);
  }
}

// ===== fused: hn = rms(h)*w2 (bf16) AND router logits (fp32) in one pass =====
__global__ void moe_rms_scores_kernel(const float* __restrict__ h, const float* __restrict__ w2,
                                      const float* __restrict__ gw,
                                      __hip_bfloat16* __restrict__ hn, float* __restrict__ scores) {
  int row = blockIdx.x;
  const float* hr = h + (size_t)row*HIDD;
  float s = 0.f;
  for (int i = threadIdx.x; i < HIDD; i += 256){ float v = hr[i]; s += v*v; }
  #pragma unroll
  for (int off=32; off; off>>=1) s += __shfl_down(s, off, 64);
  __shared__ float red[4];
  if ((threadIdx.x & 63)==0) red[threadIdx.x>>6] = s;
  __syncthreads();
  float sc = rsqrtf((red[0]+red[1]+red[2]+red[3])/(float)HIDD + 1e-5f);
  float acc[Ee] = {};
  for (int i = threadIdx.x; i < HIDD; i += 256){
    float xv = hr[i]*sc*w2[i];
    hn[(size_t)row*HIDD + i] = __float2bfloat16(xv);
    #pragma unroll
    for (int e=0;e<Ee;e++) acc[e] += xv*gw[i*Ee+e];
  }
  #pragma unroll
  for (int e=0;e<Ee;e++){
    #pragma unroll
    for (int off=32; off; off>>=1) acc[e] += __shfl_down(acc[e], off, 64);
  }
  __shared__ float red2[4][Ee];
  if ((threadIdx.x & 63)==0){
    #pragma unroll
    for (int e=0;e<Ee;e++) red2[threadIdx.x>>6][e] = acc[e];
  }
  __syncthreads();
  if (threadIdx.x < Ee)
    scores[(size_t)row*Ee + threadIdx.x] =
      red2[0][threadIdx.x]+red2[1][threadIdx.x]+red2[2][threadIdx.x]+red2[3][threadIdx.x];
}

// ================= delta-rule scan v5 (unchanged from R7) =================
__global__ __launch_bounds__(64)
void scan_kernel(const float* __restrict__ q, const float* __restrict__ k,
                 const float* __restrict__ v, const float* __restrict__ g,
                 const float* __restrict__ beta, float* __restrict__ o) {
  const int vb = blockIdx.x & 15;
  const int hh = (blockIdx.x >> 4) & 15;
  const int b  = blockIdx.x >> 8;
  const int lane = threadIdx.x;
  const int kq = lane & 15;
  const int vi = lane >> 4;
  const int v0 = vb*4;
  const int rb = b*Tt;

  __shared__ __attribute__((aligned(16))) float sq[2][CH][64];
  __shared__ __attribute__((aligned(16))) float sk[2][CH][64];
  __shared__ __attribute__((aligned(16))) float sg[2][CH][64];
  __shared__ __attribute__((aligned(16))) float sbv[Tt][4];
  __shared__ float sb[Tt];

  #pragma unroll
  for (int i=0;i<Tt/64;i++)
    async16(&sbv[i*64][0], v + (size_t)(rb + i*64 + lane)*Pp + hh*64 + v0);
  #pragma unroll
  for (int i=0;i<Tt/64;i++)
    sb[i*64+lane] = beta[(size_t)(rb + i*64 + lane)*Hh + hh];

  auto stage = [&](int t0, int pb) {
    const int srow = lane >> 4, sch4 = (lane & 15)*4;
    #pragma unroll
    for (int ii=0; ii<4; ++ii) {
      size_t gbase = (size_t)(rb + t0 + ii*4 + srow)*Pp + hh*64;
      async16(&sq[pb][ii*4][0], q + gbase + sch4);
      async16(&sk[pb][ii*4][0], k + gbase + sch4);
      async16(&sg[pb][ii*4][0], g + gbase + sch4);
    }
  };

  float S0=0.f, S1=0.f, S2=0.f, S3=0.f;

  stage(0, 0);
  asm volatile("s_waitcnt vmcnt(0)" ::: "memory");

  for (int c=0; c<NCH; ++c) {
    int pb = c & 1;
    if (c+1 < NCH) {
      stage((c+1)*CH, pb^1);
      asm volatile("s_waitcnt vmcnt(12)" ::: "memory");
    } else {
      asm volatile("s_waitcnt vmcnt(0)" ::: "memory");
    }
    __builtin_amdgcn_sched_barrier(0);
    #pragma unroll
    for (int i=0;i<CH;i++){
      int t = c*CH + i;
      float4 k4 = *(const float4*)&sk[pb][i][kq*4];
      float4 g4 = *(const float4*)&sg[pb][i][kq*4];
      float4 q4 = *(const float4*)&sq[pb][i][kq*4];
      float vv = sbv[t][vi];
      float bt = sb[t];
      S0 *= g4.x; S1 *= g4.y; S2 *= g4.z; S3 *= g4.w;
      float pred = S0*k4.x + S1*k4.y + S2*k4.z + S3*k4.w;
      pred = dpp_add<0xB1>(pred);
      pred = dpp_add<0x4E>(pred);
      pred = dpp_add<0x141>(pred);
      pred = dpp_add<0x140>(pred);
      float upd = (vv - pred) * bt;
      S0 += k4.x*upd; S1 += k4.y*upd; S2 += k4.z*upd; S3 += k4.w*upd;
      float acc = S0*q4.x + S1*q4.y + S2*q4.z + S3*q4.w;
      acc = dpp_add<0xB1>(acc);
      acc = dpp_add<0x4E>(acc);
      acc = dpp_add<0x141>(acc);
      acc = dpp_add<0x140>(acc);
      if (kq == 0) o[(size_t)(rb+t)*Pp + hh*64 + v0 + vi] = acc;
    }
  }
}

// ================= o = rms(o)*w*sigmoid(gate) -> split hi/lo bf16 =================
__global__ void onorm_gate_split_kernel(const float* __restrict__ o, const float* __restrict__ w,
                                        const float* __restrict__ gate,
                                        __hip_bfloat16* __restrict__ hi, __hip_bfloat16* __restrict__ lo) {
  int row = blockIdx.x*4 + (threadIdx.x>>6);
  int lane = threadIdx.x & 63;
  size_t idx = (size_t)row*Dd + lane;
  float v = o[idx];
  float s = v*v;
  #pragma unroll
  for (int off=32; off; off>>=1) s += __shfl_xor(s, off, 64);
  float r = v * rsqrtf(s/(float)Dd + 1e-5f) * w[lane] * sigmoidf_(gate[idx]);
  __hip_bfloat16 h = __float2bfloat16(r);
  hi[idx] = h;
  lo[idx] = __float2bfloat16(r - bf2f(h));
}

// ================= router top-2 =================
__global__ void router_kernel(const float* __restrict__ logits, const float* __restrict__ gate_b,
                              int* __restrict__ counts, int* __restrict__ tok_list,
                              int* __restrict__ slot_list, float* __restrict__ wt_list) {
  int n = blockIdx.x*256 + threadIdx.x;
  if (n >= Ntok) return;
  float sc[Ee], bi[Ee];
  #pragma unroll
  for (int e=0;e<Ee;e++){ float s = sigmoidf_(logits[n*Ee+e]); sc[e]=s; bi[e]=s+gate_b[e]; }
  int i0=0;
  #pragma unroll
  for (int e=1;e<Ee;e++) if (bi[e] > bi[i0]) i0=e;
  int i1=-1;
  #pragma unroll
  for (int e=0;e<Ee;e++){ if (e==i0) continue; if (i1<0 || bi[e] > bi[i1]) i1=e; }
  float w0=sc[i0], w1=sc[i1];
  float inv = 1.f/(w0+w1+1e-20f);
  w0*=inv; w1*=inv;
  int p0 = atomicAdd(&counts[i0],1);
  tok_list[i0*Ntok+p0]=n; slot_list[i0*Ntok+p0]=0; wt_list[i0*Ntok+p0]=w0;
  int p1 = atomicAdd(&counts[i1],1);
  tok_list[i1*Ntok+p1]=n; slot_list[i1*Ntok+p1]=1; wt_list[i1*Ntok+p1]=w1;
}

__global__ void prefix_kernel(const int* __restrict__ counts, int* __restrict__ prefix) {
  if (threadIdx.x==0 && blockIdx.x==0){ int s=0; for (int e=0;e<Ee;e++){ prefix[e]=s; s+=counts[e]; } }
}

__global__ void compact_kernel(const int* __restrict__ counts, const int* __restrict__ prefix,
                               const int* __restrict__ tok_list, const int* __restrict__ slot_list,
                               const float* __restrict__ wt_list,
                               int* __restrict__ ctok, int* __restrict__ cslot, float* __restrict__ cwt) {
  int e = blockIdx.x; int c = counts[e], p = prefix[e];
  for (int i = threadIdx.x; i < c; i += 256) {
    ctok[p+i]  = tok_list[e*Ntok+i];
    cslot[p+i] = slot_list[e*Ntok+i];
    cwt[p+i]   = wt_list[e*Ntok+i];
  }
}

__global__ void gather_kernel(const __hip_bfloat16* __restrict__ hn, const int* __restrict__ ctok,
                              __hip_bfloat16* __restrict__ Ae) {
  int r = blockIdx.x;
  int t = threadIdx.x; // 128
  ((int4*)(Ae + (size_t)r*HIDD))[t] = ((const int4*)(hn + (size_t)ctok[r]*HIDD))[t];
}

__global__ void final_kernel(const float* __restrict__ h, const __hip_bfloat16* __restrict__ routed,
                             const float* __restrict__ shr, float* __restrict__ out) {
  int idx = blockIdx.x*256 + threadIdx.x;
  if (idx >= Ntok*HIDD) return;
  int n = idx >> 10, c = idx & 1023;
  out[idx] = h[idx] + bf2f(routed[(size_t)n*2*HIDD + c]) + bf2f(routed[(size_t)n*2*HIDD + HIDD + c]) + shr[idx];
}

// ---------------------------------------------------------------------------
extern "C" void kernel_launch(void* const* d_in, const int* in_sizes, int n_in,
                              void* d_out, int out_size, void* d_ws, size_t ws_size,
                              hipStream_t stream) {
  (void)in_sizes; (void)n_in; (void)out_size; (void)ws_size;
  const float* x        = (const float*)d_in[0];
  const float* norm1_w  = (const float*)d_in[1];
  const float* wq       = (const float*)d_in[2];
  const float* wk       = (const float*)d_in[3];
  const float* wv       = (const float*)d_in[4];
  const float* cq       = (const float*)d_in[5];
  const float* ck       = (const float*)d_in[6];
  const float* cv       = (const float*)d_in[7];
  const float* fa       = (const float*)d_in[8];
  const float* fb       = (const float*)d_in[9];
  const float* bp       = (const float*)d_in[10];
  const float* ga       = (const float*)d_in[11];
  const float* gb       = (const float*)d_in[12];
  const float* A_log    = (const float*)d_in[13];
  const float* dt_bias  = (const float*)d_in[14];
  const float* onorm_w  = (const float*)d_in[15];
  const float* wo       = (const float*)d_in[16];
  const float* norm2_w  = (const float*)d_in[17];
  const float* gate_w   = (const float*)d_in[18];
  const float* gate_b   = (const float*)d_in[19];
  const float* wg_e     = (const float*)d_in[20];
  const float* wu_e     = (const float*)d_in[21];
  const float* wd_e     = (const float*)d_in[22];
  const float* wg_s     = (const float*)d_in[23];
  const float* wu_s     = (const float*)d_in[24];
  const float* wd_s     = (const float*)d_in[25];
  float* out = (float*)d_out;

  char* base = (char*)d_ws;
  size_t off = 0;
  auto alloc = [&](size_t bytes)->char* {
    off = (off + 255) & ~(size_t)255;
    char* p = base + off; off += bytes; return p;
  };
  float* hbuf = (float*)alloc((size_t)Ntok*HIDD*4);
  size_t uStart = (off + 255) & ~(size_t)255;

  // ---- attention view ----
  off = uStart;
  __hip_bfloat16* xn      = (__hip_bfloat16*)alloc((size_t)Ntok*HIDD*2);
  __hip_bfloat16* xn_lo   = (__hip_bfloat16*)alloc((size_t)Ntok*HIDD*2);
  __hip_bfloat16* wqkv_t  = (__hip_bfloat16*)alloc((size_t)3*Pp*HIDD*2);
  __hip_bfloat16* wqkv_lo = (__hip_bfloat16*)alloc((size_t)3*Pp*HIDD*2);
  float*          qkvlin  = (float*)alloc((size_t)Ntok*3*Pp*4);
  float*          qc      = (float*)alloc((size_t)Ntok*Pp*4);
  float*          kc      = (float*)alloc((size_t)Ntok*Pp*4);
  float*          vc      = (float*)alloc((size_t)Ntok*Pp*4);
  float*          gbuf    = (float*)alloc((size_t)Ntok*Pp*4);
  float*          gatebuf = (float*)alloc((size_t)Ntok*Pp*4);
  float*          obuf    = (float*)alloc((size_t)Ntok*Pp*4);
  __hip_bfloat16* atmp12  = (__hip_bfloat16*)alloc((size_t)Ntok*2*Dd*2);
  float*          betab   = (float*)alloc((size_t)Ntok*Hh*4);
  __hip_bfloat16* obuf_hi = (__hip_bfloat16*)alloc((size_t)Ntok*Pp*2);
  __hip_bfloat16* obuf_lo = (__hip_bfloat16*)alloc((size_t)Ntok*Pp*2);
  __hip_bfloat16* wo_t    = (__hip_bfloat16*)alloc((size_t)HIDD*Pp*2);
  __hip_bfloat16* wo_lo   = (__hip_bfloat16*)alloc((size_t)HIDD*Pp*2);
  __hip_bfloat16* fg_t    = (__hip_bfloat16*)alloc((size_t)2*Dd*HIDD*2);
  __hip_bfloat16* fb_t    = (__hip_bfloat16*)alloc((size_t)Pp*Dd*2);
  __hip_bfloat16* gb_t    = (__hip_bfloat16*)alloc((size_t)Pp*Dd*2);

  // ---- moe view (overlaps attention view) ----
  off = uStart;
  __hip_bfloat16* hn      = (__hip_bfloat16*)alloc((size_t)Ntok*HIDD*2);
  float*          scores  = (float*)alloc((size_t)Ntok*Ee*4);
  int*            counts  = (int*)alloc(64);
  int*            prefix  = (int*)alloc(64);
  int*            tok_list  = (int*)alloc((size_t)Ee*Ntok*4);
  int*            slot_list = (int*)alloc((size_t)Ee*Ntok*4);
  float*          wt_list   = (float*)alloc((size_t)Ee*Ntok*4);
  int*            ctok    = (int*)alloc((size_t)NPAD*4);
  int*            cslot   = (int*)alloc((size_t)NPAD*4);
  float*          cwt     = (float*)alloc((size_t)NPAD*4);
  __hip_bfloat16* egu_t   = (__hip_bfloat16*)alloc((size_t)Ee*2*Ii*HIDD*2);
  __hip_bfloat16* sgu_t   = (__hip_bfloat16*)alloc((size_t)2*ISs*HIDD*2);
  __hip_bfloat16* sd_t    = (__hip_bfloat16*)alloc((size_t)HIDD*ISs*2);
  __hip_bfloat16* act     = (__hip_bfloat16*)alloc((size_t)NPAD*Ii*2);
  __hip_bfloat16* sgb     = (__hip_bfloat16*)alloc((size_t)Ntok*ISs*2);
  __hip_bfloat16* routed  = (__hip_bfloat16*)alloc((size_t)Ntok*2*HIDD*2);
  float*          shout   = (float*)alloc((size_t)Ntok*HIDD*4);
  __hip_bfloat16* Ae      = (__hip_bfloat16*)alloc((size_t)NPAD*HIDD*2);
  __hip_bfloat16* ed_t    = (__hip_bfloat16*)alloc((size_t)Ee*HIDD*Ii*2);

  dim3 blk(256);
  #define NO5 nullptr, nullptr, nullptr, nullptr, nullptr

  // ================= attention =================
  rms_split_kernel<<<Ntok, blk, 0, stream>>>(x, norm1_w, xn, xn_lo, 1e-5f);
  trans_split4_kernel<<<dim3(32,32,4), blk, 0, stream>>>(wq, wk, wv, wo,
                                                         wqkv_t, wqkv_lo, wo_t, wo_lo);
  trans_pair_kernel<<<dim3(2,32,2), blk, 0, stream>>>(fa, ga, fg_t, fg_t + (size_t)Dd*HIDD, HIDD, Dd);
  trans_pair_kernel<<<dim3(32,2,2), blk, 0, stream>>>(fb, gb, fb_t, gb_t, Dd, Pp);

  gemm3_k<0><<<dim3(48,16,1), blk, 0, stream>>>(xn, xn_lo, wqkv_t, wqkv_lo, qkvlin,
                                                Ntok, 3*Pp, HIDD, nullptr);
  conv_norm_kernel<<<dim3(Ntok,3,1), blk, 0, stream>>>(qkvlin, cq, ck, cv, qc, kc, vc);
  gemm_k<1,0><<<dim3(2,16,1), blk, 0, stream>>>(xn, fg_t, atmp12, Ntok, 2*Dd, HIDD, HIDD, NO5, nullptr);
  // fb-GEMM with fused g-transform epilogue (resid=A_log, cwt=dt_bias)
  gemm_k<5,0><<<dim3(16,16,1), blk, 0, stream>>>(atmp12, fb_t, gbuf, Ntok, Pp, Dd, 2*Dd,
                                                 A_log, nullptr, nullptr, nullptr, nullptr, dt_bias);
  gemm_k<0,0><<<dim3(16,16,1), blk, 0, stream>>>(atmp12+Dd, gb_t, gatebuf, Ntok, Pp, Dd, 2*Dd, NO5, nullptr);
  beta_kernel<<<Ntok, blk, 0, stream>>>(xn, bp, betab);
  scan_kernel<<<Bb*Hh*16, dim3(64), 0, stream>>>(qc, kc, vc, gbuf, betab, obuf);
  onorm_gate_split_kernel<<<(Ntok*Hh)/4, blk, 0, stream>>>(obuf, onorm_w, gatebuf, obuf_hi, obuf_lo);
  gemm3_k<2><<<dim3(16,16,1), blk, 0, stream>>>(obuf_hi, obuf_lo, wo_t, wo_lo, hbuf,
                                                Ntok, HIDD, Pp, x);

  // ================= MoE =================
  moe_rms_scores_kernel<<<Ntok, blk, 0, stream>>>(hbuf, norm2_w, gate_w, hn, scores);
  hipMemsetAsync(counts, 0, Ee*sizeof(int), stream);
  router_kernel<<<(Ntok+255)/256, blk, 0, stream>>>(scores, gate_b, counts, tok_list, slot_list, wt_list);
  prefix_kernel<<<1, 64, 0, stream>>>(counts, prefix);
  compact_kernel<<<Ee, blk, 0, stream>>>(counts, prefix, tok_list, slot_list, wt_list, ctok, cslot, cwt);
  gather_kernel<<<NASSIGN, dim3(128), 0, stream>>>(hn, ctok, Ae);
  // interleaved (wg,wu) pair transpose: col 2j <- wg col j, col 2j+1 <- wu col j
  trans_inter_kernel<<<dim3(24,32,2*Ee), blk, 0, stream>>>(wg_e, wu_e, egu_t,
      HIDD, Ii, (long)HIDD*Ii, (long)2*Ii*HIDD);
  // expert up-GEMM with fused GLU epilogue -> act (compact rows, 768 cols)
  gemm_k<6,0><<<dim3(24,16,Ee), blk, 0, stream>>>(Ae, egu_t, act, Ntok, 2*Ii, HIDD, HIDD,
                                                  nullptr, counts, prefix, nullptr, nullptr, nullptr);
  trans_kernel<<<dim3(32,24,Ee), blk, 0, stream>>>(wd_e, ed_t,
      Ii, HIDD, (long)Ii*HIDD, (long)HIDD*Ii);
  gemm_k<4,0><<<dim3(16,16,Ee), blk, 0, stream>>>(act, ed_t, routed, Ntok, HIDD, Ii, Ii,
                                                  nullptr, counts, prefix, ctok, cslot, cwt);
  // shared expert: interleaved up-weights + fused GLU
  trans_inter_kernel<<<dim3(24,32,2), blk, 0, stream>>>(wg_s, wu_s, sgu_t, HIDD, ISs, 0, 0);
  trans_kernel<<<dim3(32,24,1), blk, 0, stream>>>(wd_s, sd_t, ISs, HIDD, 0, 0);
  gemm_k<7,0><<<dim3(24,16,1), blk, 0, stream>>>(hn, sgu_t, sgb, Ntok, 2*ISs, HIDD, HIDD, NO5, nullptr);
  gemm_k<0,0><<<dim3(16,16,1), blk, 0, stream>>>(sgb, sd_t, shout, Ntok, HIDD, ISs, ISs, NO5, nullptr);

  final_kernel<<<(Ntok*HIDD+255)/256, blk, 0, stream>>>(hbuf, routed, shout, out);
}